// Round 12
// baseline (4355.970 us; speedup 1.0000x reference)
//
#include <hip/hip_runtime.h>
#include <math.h>

#define HID  128
#define EDIM 4

typedef unsigned short u16;
typedef u16    us8   __attribute__((ext_vector_type(8)));
typedef __bf16 bf16x8 __attribute__((ext_vector_type(8)));
typedef float  f32x4 __attribute__((ext_vector_type(4)));

// silu via hw rcp: v_rcp_f32 (~1 ulp) instead of IEEE div (10+ inst w/o fast-math)
__device__ __forceinline__ float silu_f(float v) {
    return v * __builtin_amdgcn_rcpf(1.0f + __expf(-v));
}
__device__ __forceinline__ u16 f2bf(float f) {   // RNE fp32->bf16 (cold paths)
    unsigned u = __float_as_uint(f);
    unsigned r = u + 0x7fffu + ((u >> 16) & 1u);
    return (u16)(r >> 16);
}
__device__ __forceinline__ u16 f2bf_fast(float f) {  // round-half-up, 2 ops (hot)
    return (u16)((__float_as_uint(f) + 0x8000u) >> 16);
}
// pack two fp32 -> one u32 of 2 bf16 (round-half-up)
__device__ __forceinline__ unsigned pack_bf2(float a, float b) {
    return ((__float_as_uint(a) + 0x8000u) >> 16) |
           ((__float_as_uint(b) + 0x8000u) & 0xffff0000u);
}
__device__ __forceinline__ float bf2f(u16 s) {
    return __uint_as_float(((unsigned)s) << 16);
}
__device__ __forceinline__ bf16x8 as_bf(us8 v) {
    return __builtin_bit_cast(bf16x8, v);
}
__device__ __forceinline__ f32x4 bf4f(ushort4 v) {
    f32x4 r;
    r[0] = bf2f(v.x); r[1] = bf2f(v.y); r[2] = bf2f(v.z); r[3] = bf2f(v.w);
    return r;
}

// ---------------- fused setup: weight swizzle + zero-fills ------------------
// Generalized fragment swizzler: logical k -> source row = k + (k>=split ?
// jump : 0); valid iff row < Kdata. Layer stride Kstride rows.
__device__ __forceinline__ void wfrag_gen(const float* __restrict__ w,
        u16* __restrict__ out, int KT, int Kdata, int Kstride,
        int split, int jump, int idx) {
    int lane = idx & 63;
    int f    = (idx >> 6) % (KT * 8);
    int l    = idx / (64 * KT * 8);
    int kt = f >> 3, nt = f & 7;
    int n  = nt * 16 + (lane & 15);
    int k0 = kt * 32 + ((lane >> 4) * 8);
    us8 v;
    #pragma unroll
    for (int j = 0; j < 8; ++j) {
        int k = k0 + j;
        int row = k + (k >= split ? jump : 0);
        v[j] = (row < Kdata) ? f2bf(w[((size_t)l * Kstride + row) * HID + n]) : (u16)0;
    }
    *(us8*)&out[((size_t)(l * KT * 8 + f) * 64 + lane) * 8] = v;
}

// R22 split of W1 [260x128]: w1s (src rows 0..127, KT=4), w1b (dst rows
// 128..255, KT=4), w1t (attr rows 256..259 zero-padded to K=32, KT=1).
#define T1S (4 * 4 * 8 * 64)
#define T1T (4 * 1 * 8 * 64)
#define T1B (4 * 4 * 8 * 64)
#define T2  (4 * 4 * 8 * 64)
#define T3  (4 * 8 * 8 * 64)

__global__ __launch_bounds__(256) void setup_kernel(
        const float* __restrict__ ew1, const float* __restrict__ ew2,
        const float* __restrict__ nw,
        u16* __restrict__ w1sf, u16* __restrict__ w1tf,
        u16* __restrict__ w1bf,
        u16* __restrict__ w2f, u16* __restrict__ nwf,
        int* __restrict__ cnt, int* __restrict__ cursor,
        float* __restrict__ sums, float* __restrict__ cnts_g, int N, int G) {
    const int BIG = 1 << 30;
    int idx = blockIdx.x * 256 + threadIdx.x;
    if (idx < T1S) { wfrag_gen(ew1, w1sf, 4, 128, 260, BIG, 0, idx); return; }
    idx -= T1S;
    if (idx < T1T) { wfrag_gen(ew1, w1tf, 1, 260, 260, 0, 256, idx); return; }
    idx -= T1T;
    if (idx < T1B) { wfrag_gen(ew1, w1bf, 4, 260, 260, 0, 128, idx); return; }
    idx -= T1B;
    if (idx < T2) { wfrag_gen(ew2, w2f, 4, 128, 128, BIG, 0, idx); return; }
    idx -= T2;
    if (idx < T3) { wfrag_gen(nw, nwf, 8, 256, 256, BIG, 0, idx); return; }
    idx -= T3;
    if (idx < N) { cnt[idx] = 0; return; }
    idx -= N;
    if (idx < N) { cursor[idx] = 0; return; }
    idx -= N;
    if (idx < G * HID) { sums[idx] = 0.f; return; }
    idx -= G * HID;
    if (idx < G) { cnts_g[idx] = 0.f; return; }
}

// ---------------- CSR build: hist -> scan -> scatter ------------------------
__global__ __launch_bounds__(256) void hist_kernel(const int* __restrict__ dst,
        int* __restrict__ cnt, int E) {
    int e = blockIdx.x * 256 + threadIdx.x;
    if (e < E) atomicAdd(&cnt[dst[e]], 1);
}

// scan + per-layer node-group tile counters (cntg4: 4 copies, one consumed
// per fused layer dispatch; re-initialized on every graph replay since this
// kernel is part of the captured graph).
__global__ __launch_bounds__(1024) void scan_kernel(const int* __restrict__ cnt,
        int* __restrict__ rowptr, int* __restrict__ cntg4, int nG, int n) {
    __shared__ int s[1024];
    const int t = threadIdx.x;
    const int chunk = (n + 1023) >> 10;
    int lo = t * chunk, hi = lo + chunk;
    if (lo > n) lo = n;
    if (hi > n) hi = n;
    int sum = 0;
    for (int i = lo; i < hi; ++i) sum += cnt[i];
    s[t] = sum;
    __syncthreads();
    for (int off = 1; off < 1024; off <<= 1) {
        int v = (t >= off) ? s[t - off] : 0;
        __syncthreads();
        s[t] += v;
        __syncthreads();
    }
    int run = s[t] - sum;
    for (int i = lo; i < hi; ++i) { rowptr[i] = run; run += cnt[i]; }
    if (t == 1023) rowptr[n] = run;
    __syncthreads();
    for (int g = t; g < nG; g += 1024) {
        int a = rowptr[g * 32];
        int bhi = g * 32 + 32; if (bhi > n) bhi = n;
        int b = rowptr[bhi];
        int c = (a < b) ? (((b - 1) >> 6) - (a >> 6) + 1) : 0;
        cntg4[0 * nG + g] = c;
        cntg4[1 * nG + g] = c;
        cntg4[2 * nG + g] = c;
        cntg4[3 * nG + g] = c;
    }
}

__global__ __launch_bounds__(256) void scatter_kernel(const int* __restrict__ src,
        const int* __restrict__ dst, const float* __restrict__ ea,
        const int* __restrict__ rowptr, int* __restrict__ cursor,
        int* __restrict__ srcS, int* __restrict__ dstS, u16* __restrict__ eaS, int E) {
    int e = blockIdx.x * 256 + threadIdx.x;
    if (e >= E) return;
    int d = dst[e];
    int p = rowptr[d] + atomicAdd(&cursor[d], 1);
    srcS[p] = src[e];
    dstS[p] = d;
    const float* q = &ea[(size_t)e * EDIM];
    ushort4 v;
    v.x = f2bf(q[0]); v.y = f2bf(q[1]); v.z = f2bf(q[2]); v.w = f2bf(q[3]);
    *(ushort4*)&eaS[(size_t)p * 4] = v;
}

// ---------------- shared dual-projection tail -------------------------------
// Ys = x@W1s, Y = b1 + x@W1b from the block's own 32 xb rows; OUTPUT bf16.
// Caller must __syncthreads() after writing those xb rows. 256-thread
// geometry (t in [0,256)).
__device__ __forceinline__ void dual_proj(
        const u16* __restrict__ xb,
        const u16* __restrict__ w1sf, const u16* __restrict__ w1bf,
        const float* __restrict__ b1n,
        u16* __restrict__ Ys, u16* __restrict__ Y,
        int i0, int n, int t) {
    const int wv   = t >> 6, lane = t & 63;
    const int lrow = lane & 15;
    const int kq   = lane >> 4;
    const int kq8  = kq * 8;

    int iN[2];
    #pragma unroll
    for (int mt = 0; mt < 2; ++mt) {
        int i = i0 + mt * 16 + lrow; if (i >= n) i = n - 1;
        iN[mt] = i;
    }
    f32x4 aS[2][2], aB[2][2];
    #pragma unroll
    for (int mt = 0; mt < 2; ++mt)
        #pragma unroll
        for (int nt = 0; nt < 2; ++nt) {
            aS[mt][nt] = (f32x4){0.f, 0.f, 0.f, 0.f};
            aB[mt][nt] = *(const f32x4*)&b1n[(wv * 2 + nt) * 16 + kq * 4];
        }

    #pragma unroll
    for (int kt = 0; kt < 4; ++kt) {
        bf16x8 ws0 = *(const bf16x8*)&w1sf[((size_t)(kt * 8 + wv * 2 + 0) * 64 + lane) * 8];
        bf16x8 ws1 = *(const bf16x8*)&w1sf[((size_t)(kt * 8 + wv * 2 + 1) * 64 + lane) * 8];
        bf16x8 wb0 = *(const bf16x8*)&w1bf[((size_t)(kt * 8 + wv * 2 + 0) * 64 + lane) * 8];
        bf16x8 wb1 = *(const bf16x8*)&w1bf[((size_t)(kt * 8 + wv * 2 + 1) * 64 + lane) * 8];
        #pragma unroll
        for (int mt = 0; mt < 2; ++mt) {
            bf16x8 a = as_bf(*(const us8*)&xb[(size_t)iN[mt] * HID + kt * 32 + kq8]);
            aS[mt][0] = __builtin_amdgcn_mfma_f32_16x16x32_bf16(ws0, a, aS[mt][0], 0, 0, 0);
            aS[mt][1] = __builtin_amdgcn_mfma_f32_16x16x32_bf16(ws1, a, aS[mt][1], 0, 0, 0);
            aB[mt][0] = __builtin_amdgcn_mfma_f32_16x16x32_bf16(wb0, a, aB[mt][0], 0, 0, 0);
            aB[mt][1] = __builtin_amdgcn_mfma_f32_16x16x32_bf16(wb1, a, aB[mt][1], 0, 0, 0);
        }
    }
    #pragma unroll
    for (int mt = 0; mt < 2; ++mt) {
        int node = i0 + mt * 16 + lrow;
        if (node < n) {
            #pragma unroll
            for (int nt = 0; nt < 2; ++nt) {
                uint2 sv, bv;
                sv.x = pack_bf2(aS[mt][nt][0], aS[mt][nt][1]);
                sv.y = pack_bf2(aS[mt][nt][2], aS[mt][nt][3]);
                bv.x = pack_bf2(aB[mt][nt][0], aB[mt][nt][1]);
                bv.y = pack_bf2(aB[mt][nt][2], aB[mt][nt][3]);
                *(uint2*)&Ys[(size_t)node * HID + (wv * 2 + nt) * 16 + kq * 4] = sv;
                *(uint2*)&Y [(size_t)node * HID + (wv * 2 + nt) * 16 + kq * 4] = bv;
            }
        }
    }
}

// ---------------- embed + zero agg + counts + layer-0 projections -----------
__global__ __launch_bounds__(256) void embed_ys_kernel(
        const int* __restrict__ z, const float* __restrict__ emb,
        u16* __restrict__ xb, float* __restrict__ agg,
        const int* __restrict__ batch, float* __restrict__ counts,
        const u16* __restrict__ w1sf, const u16* __restrict__ w1bf,
        const float* __restrict__ b1n,
        u16* __restrict__ Ys, u16* __restrict__ Y, int n) {
    const int t  = threadIdx.x;
    const int i0 = blockIdx.x * 32;
    #pragma unroll
    for (int j = 0; j < 16; ++j) {
        int idx = j * 256 + t;                 // 4096 slots = 32 nodes x 128
        int node = i0 + (idx >> 7), col = idx & 127;
        if (node < n) {
            xb[(size_t)node * HID + col] = f2bf(emb[(size_t)z[node] * HID + col]);
            agg[(size_t)node * HID + col] = 0.f;
        }
    }
    if (t < 32 && i0 + t < n)
        unsafeAtomicAdd(&counts[batch[i0 + t]], 1.0f);
    __syncthreads();   // xb stores drained -> visible block-wide
    dual_proj(xb, w1sf, w1bf, b1n, Ys, Y, i0, n, t);
}

// ---------------- node-group worker (R8-proven node body, 256 active) -------
// Runs inside the fused kernel by the block that completes group g. agg is
// read via RELAXED device-scope ATOMIC loads (per-load cache bypass: other
// blocks' agg atomics live at the coherence point; no acquire fence -> no
// L2-invalidate storms, the R10 killer). xb/weights are normal loads
// (written in prior dispatches -> dispatch-boundary coherent). Barriers
// unconditional (all 512 threads participate; waves 4-7 idle).
__device__ __forceinline__ void node_group(int g,
        u16* __restrict__ xb, float* __restrict__ agg,
        const u16* __restrict__ nwf, const float* __restrict__ nb,
        const int* __restrict__ batch, float* __restrict__ sums,
        const u16* __restrict__ w1sf_nxt, const u16* __restrict__ w1bf_nxt,
        const float* __restrict__ b1_nxt,
        u16* __restrict__ Ys_out, u16* __restrict__ Y_out,
        int last, int N, int t512) {
    const bool act = (t512 < 256);
    const int t    = t512 & 255;
    const int i0   = g * 32;
    const int wv   = t >> 6, lane = t & 63;
    const int lrow = lane & 15;
    const int kq   = lane >> 4;
    const int kq8  = kq * 8;
    const int rq   = kq * 4;

    int iN[2];
    #pragma unroll
    for (int mt = 0; mt < 2; ++mt) {
        int i = i0 + mt * 16 + lrow; if (i >= N) i = N - 1;
        iN[mt] = i;
    }

    f32x4 acc[2][2];
    if (act) {
        float bias0 = nb[wv * 32 + lrow], bias1 = nb[wv * 32 + 16 + lrow];
        #pragma unroll
        for (int mt = 0; mt < 2; ++mt)
            #pragma unroll
            for (int r = 0; r < 4; ++r) {
                acc[mt][0][r] = bias0; acc[mt][1][r] = bias1;
            }
        #pragma unroll
        for (int kt = 0; kt < 4; ++kt) {     // x part (k 0..127)
            bf16x8 w0 = *(const bf16x8*)&nwf[((size_t)(kt * 8 + wv * 2 + 0) * 64 + lane) * 8];
            bf16x8 w1 = *(const bf16x8*)&nwf[((size_t)(kt * 8 + wv * 2 + 1) * 64 + lane) * 8];
            #pragma unroll
            for (int mt = 0; mt < 2; ++mt) {
                bf16x8 a = as_bf(*(const us8*)&xb[(size_t)iN[mt] * HID + kt * 32 + kq8]);
                acc[mt][0] = __builtin_amdgcn_mfma_f32_16x16x32_bf16(a, w0, acc[mt][0], 0, 0, 0);
                acc[mt][1] = __builtin_amdgcn_mfma_f32_16x16x32_bf16(a, w1, acc[mt][1], 0, 0, 0);
            }
        }
        #pragma unroll
        for (int kt = 4; kt < 8; ++kt) {     // agg part: relaxed atomic loads
            bf16x8 w0 = *(const bf16x8*)&nwf[((size_t)(kt * 8 + wv * 2 + 0) * 64 + lane) * 8];
            bf16x8 w1 = *(const bf16x8*)&nwf[((size_t)(kt * 8 + wv * 2 + 1) * 64 + lane) * 8];
            #pragma unroll
            for (int mt = 0; mt < 2; ++mt) {
                float* pa = &agg[(size_t)iN[mt] * HID + (kt - 4) * 32 + kq8];
                us8 av;
                #pragma unroll
                for (int j = 0; j < 8; ++j) {
                    float fv = __hip_atomic_load(&pa[j], __ATOMIC_RELAXED,
                                                 __HIP_MEMORY_SCOPE_AGENT);
                    av[j] = f2bf_fast(fv);
                }
                bf16x8 a = as_bf(av);
                acc[mt][0] = __builtin_amdgcn_mfma_f32_16x16x32_bf16(a, w0, acc[mt][0], 0, 0, 0);
                acc[mt][1] = __builtin_amdgcn_mfma_f32_16x16x32_bf16(a, w1, acc[mt][1], 0, 0, 0);
            }
        }
    }

    if (!last) {
        __syncthreads();   // all xb/agg reads for this group complete
        if (act) {
            const float4 z4 = make_float4(0.f, 0.f, 0.f, 0.f);
            #pragma unroll
            for (int kt = 0; kt < 4; ++kt)
                #pragma unroll
                for (int mt = 0; mt < 2; ++mt) {
                    float* pa = &agg[(size_t)iN[mt] * HID + kt * 32 + kq8];
                    *(float4*)pa = z4; *(float4*)(pa + 4) = z4;
                }
            #pragma unroll
            for (int mt = 0; mt < 2; ++mt)
                #pragma unroll
                for (int nt2 = 0; nt2 < 2; ++nt2)
                    #pragma unroll
                    for (int r = 0; r < 4; ++r) {
                        int i = i0 + mt * 16 + rq + r;
                        if (i < N)
                            xb[(size_t)i * HID + wv * 32 + nt2 * 16 + lrow] =
                                f2bf_fast(silu_f(acc[mt][nt2][r]));
                    }
        }
        __syncthreads();   // xb stores drained -> visible block-wide
        if (act)
            dual_proj(xb, w1sf_nxt, w1bf_nxt, b1_nxt, Ys_out, Y_out, i0, N, t);
    } else {
        if (act) {
            #pragma unroll
            for (int mt = 0; mt < 2; ++mt)
                #pragma unroll
                for (int nt2 = 0; nt2 < 2; ++nt2)
                    #pragma unroll
                    for (int r = 0; r < 4; ++r) {
                        int i = i0 + mt * 16 + rq + r;
                        if (i < N) {
                            int b = batch[i];
                            unsafeAtomicAdd(&sums[(size_t)b * HID + wv * 32 + nt2 * 16 + lrow],
                                            silu_f(acc[mt][nt2][r]));
                        }
                    }
        }
    }
}

// ---------------- fused edge+node layer kernel ------------------------------
// R27: edge body byte-identical to R11 (proven 136 us). After the scan, each
// block decrements the tile-counters of the node-groups whose edges it
// processed (the post-scan __syncthreads drains vmcnt for ALL waves -> this
// block's device-scope agg atomics are complete & visible BEFORE the relaxed
// decrement; no fences needed). The block whose decrement hits zero runs the
// node body for that group. Empty groups (no edges; ~impossible for this
// input but handled) are claimed by the tile containing CSR position
// rowptr[32g]. Ys/Y are ping-ponged per layer (edge reads in-buffers all
// dispatch long; winners write out-buffers). NO grid barrier, NO spinning,
// NO fences -> avoids R9 (coop dropped under capture) and R10 (fence
// invalidate storm) mechanisms entirely.
// FAILED variants (do not reintroduce): R9 XOR-swizzle, R13 2x2 wave tiling,
// R16 occupancy 2x, R18 VGPR-persistent weights (spill), R19 node-centric
// fusion (L2 thrash), R5 LDS-transpose node tail, R6 H-split, R9 cooperative
// launch, R10 persistent manual-barrier kernel.
__global__ __launch_bounds__(512, 6) void edge_node_mfma(
        const int* __restrict__ srcS, const int* __restrict__ dstS,
        const u16* __restrict__ eaS, const int* __restrict__ rowptr,
        int* __restrict__ cntg,
        const u16* __restrict__ w1tf,
        const u16* __restrict__ w2f, const float* __restrict__ b2,
        const u16* __restrict__ Ys, const u16* __restrict__ Y,
        u16* __restrict__ xb, float* __restrict__ agg,
        const u16* __restrict__ nwf, const float* __restrict__ nb,
        const int* __restrict__ batch, float* __restrict__ sums,
        const u16* __restrict__ w1sf_nxt, const u16* __restrict__ w1bf_nxt,
        const float* __restrict__ b1_nxt,
        u16* __restrict__ Ys_out, u16* __restrict__ Y_out,
        int last, int nE, int N, int nG) {
    // A: u16 [64][40] | H: u16 [64][136] (aliases A) | M: f32 [64][132]
    __shared__ __align__(16) char smem[64 * 132 * 4];
    __shared__ __align__(16) int dsh[64];
    __shared__ __align__(16) int ssh[64];
    __shared__ int wincnt;
    __shared__ int winlist[128];
    u16*   A = (u16*)smem;
    u16*   H = (u16*)smem;
    float* M = (float*)smem;

    const int t    = threadIdx.x;
    const int e0   = blockIdx.x * 64;
    const int wv   = t >> 6, lane = t & 63;
    const int lrow = lane & 15;
    const int kq   = lane >> 4;
    const int kq8  = kq * 8;
    const int rq   = kq * 4;
    const int h    = wv >> 2;     // edge-half this wave owns (0/1)
    const int p    = wv & 3;      // col-pair this wave owns (0..3)

    // ---- stage: dsh/ssh + attr rows (64 x 32 bf16, rows padded to 40) ----
    if (t < 64) {
        int e = e0 + t;
        bool valid = e < nE; if (!valid) e = nE - 1;
        dsh[t] = valid ? dstS[e] : -1;
        ssh[t] = srcS[e];
        ushort4 q = *(const ushort4*)&eaS[(size_t)e * 4];
        int base = t * 40;
        us8 z8 = (us8){0, 0, 0, 0, 0, 0, 0, 0};
        *(us8*)&A[base + 8]  = z8;         // K-pad cols 8..31 zero
        *(us8*)&A[base + 16] = z8;
        *(us8*)&A[base + 24] = z8;
        A[base + 0] = q.x; A[base + 1] = q.y; A[base + 2] = q.z; A[base + 3] = q.w;
        A[base + 4] = 0;   A[base + 5] = 0;   A[base + 6] = 0;   A[base + 7] = 0;
    }
    if (t == 64 + 0) wincnt = 0;           // init alongside stage
    __syncthreads();

    // ---- GEMM1: attr-only K=32. acc init = cvt(Ys[src]) + cvt(Y[dst]).
    f32x4 acc[2][2];
    #pragma unroll
    for (int mt = 0; mt < 2; ++mt) {
        int edge = (h * 2 + mt) * 16 + lrow;
        int d = dsh[edge]; if (d < 0) d = 0;   // tail-safe (unused result)
        int s = ssh[edge];
        #pragma unroll
        for (int nt = 0; nt < 2; ++nt) {
            ushort4 yv = *(const ushort4*)&Y [(size_t)d * HID + (p * 2 + nt) * 16 + rq];
            ushort4 sv = *(const ushort4*)&Ys[(size_t)s * HID + (p * 2 + nt) * 16 + rq];
            acc[mt][nt] = bf4f(yv) + bf4f(sv);
        }
    }
    {
        bf16x8 w0 = *(const bf16x8*)&w1tf[((size_t)(p * 2 + 0) * 64 + lane) * 8];
        bf16x8 w1 = *(const bf16x8*)&w1tf[((size_t)(p * 2 + 1) * 64 + lane) * 8];
        #pragma unroll
        for (int mt = 0; mt < 2; ++mt) {
            bf16x8 a = *(const bf16x8*)&A[((h * 2 + mt) * 16 + lrow) * 40 + kq8];
            acc[mt][0] = __builtin_amdgcn_mfma_f32_16x16x32_bf16(w0, a, acc[mt][0], 0, 0, 0);
            acc[mt][1] = __builtin_amdgcn_mfma_f32_16x16x32_bf16(w1, a, acc[mt][1], 0, 0, 0);
        }
    }
    __syncthreads();   // all A reads done; region reused as H

    // silu -> H
    #pragma unroll
    for (int mt = 0; mt < 2; ++mt)
        #pragma unroll
        for (int nt = 0; nt < 2; ++nt) {
            uint2 hv;
            hv.x = pack_bf2(silu_f(acc[mt][nt][0]), silu_f(acc[mt][nt][1]));
            hv.y = pack_bf2(silu_f(acc[mt][nt][2]), silu_f(acc[mt][nt][3]));
            int edge = (h * 2 + mt) * 16 + lrow;
            *(uint2*)&H[edge * 136 + (p * 2 + nt) * 16 + rq] = hv;
        }
    __syncthreads();

    // ---- GEMM2: [64 x 128] @ [128 x 128], swapped operands ----
    f32x4 acc2[2][2];
    #pragma unroll
    for (int nt = 0; nt < 2; ++nt) {
        f32x4 bv = *(const f32x4*)&b2[(p * 2 + nt) * 16 + rq];
        acc2[0][nt] = bv; acc2[1][nt] = bv;
    }
    #pragma unroll
    for (int kt = 0; kt < 4; ++kt) {
        bf16x8 w0 = *(const bf16x8*)&w2f[((size_t)(kt * 8 + p * 2 + 0) * 64 + lane) * 8];
        bf16x8 w1 = *(const bf16x8*)&w2f[((size_t)(kt * 8 + p * 2 + 1) * 64 + lane) * 8];
        #pragma unroll
        for (int mt = 0; mt < 2; ++mt) {
            bf16x8 a = *(const bf16x8*)&H[((h * 2 + mt) * 16 + lrow) * 136 + kt * 32 + kq8];
            acc2[mt][0] = __builtin_amdgcn_mfma_f32_16x16x32_bf16(w0, a, acc2[mt][0], 0, 0, 0);
            acc2[mt][1] = __builtin_amdgcn_mfma_f32_16x16x32_bf16(w1, a, acc2[mt][1], 0, 0, 0);
        }
    }
    __syncthreads();   // all H reads complete before M overwrites (aliased WAR)

    // silu -> M
    #pragma unroll
    for (int mt = 0; mt < 2; ++mt)
        #pragma unroll
        for (int nt = 0; nt < 2; ++nt) {
            f32x4 mv;
            #pragma unroll
            for (int r = 0; r < 4; ++r) mv[r] = silu_f(acc2[mt][nt][r]);
            int edge = (h * 2 + mt) * 16 + lrow;
            *(f32x4*)&M[edge * 132 + (p * 2 + nt) * 16 + rq] = mv;
        }

    // ---- wave-local segmented reduction into agg (no barrier) ----
    {
        int col = p * 32 + (lane & 31);
        int r0  = h * 32 + (lane >> 5) * 16;   // rows r0..r0+15
        int4 da = *(const int4*)&dsh[r0];
        int4 db = *(const int4*)&dsh[r0 + 4];
        int4 dc = *(const int4*)&dsh[r0 + 8];
        int4 dd = *(const int4*)&dsh[r0 + 12];
        int ds_[16] = {da.x, da.y, da.z, da.w, db.x, db.y, db.z, db.w,
                       dc.x, dc.y, dc.z, dc.w, dd.x, dd.y, dd.z, dd.w};
        float run = 0.f;
        int   cur = ds_[0];
        #pragma unroll
        for (int i = 0; i < 16; ++i) {
            run += M[(r0 + i) * 132 + col];
            int nxt = (i == 15) ? -2 : ds_[i + 1];
            if (cur != nxt) {             // uniform within 32-lane half
                if (cur >= 0)
                    unsafeAtomicAdd(&agg[(size_t)cur * HID + col], run);
                run = 0.f; cur = nxt;
            }
        }
    }

    // ================= completion accounting + fused node work =============
    const int nvalid = (nE - e0 < 64) ? (nE - e0) : 64;
    __syncthreads();   // compiler emits vmcnt(0) per wave before s_barrier ->
                       // ALL this block's agg atomics are complete & visible
    const int glo = dsh[0] >> 5;
    const int ghi = dsh[nvalid - 1] >> 5;
    {
        int nc = ghi - glo + 1;            // <= 64
        if (t < nc) {
            int gg = glo + t;
            int r32 = gg * 32 + 32; if (r32 > N) r32 = N;
            int lo = rowptr[gg * 32];
            int hi = rowptr[r32];
            if (lo < hi) {                 // non-empty -> this tile has its edges
                int old = __hip_atomic_fetch_add(&cntg[gg], -1,
                        __ATOMIC_RELAXED, __HIP_MEMORY_SCOPE_AGENT);
                if (old == 1) {            // we completed group gg
                    int idx = atomicAdd(&wincnt, 1);
                    winlist[idx] = gg;
                }
            }
        }
    }
    __syncthreads();
    if (t == 0) {
        // claim EMPTY groups whose CSR position falls in this tile (robustness;
        // ~never fires for this input). Capped list; cap unreachable here.
        int gp = (e0 > 0) ? (dstS[e0 - 1] >> 5) : -1;
        int ge = (blockIdx.x == gridDim.x - 1) ? (nG - 1) : ghi;
        for (int gg = gp + 1; gg <= ge; ++gg) {
            int r32 = gg * 32 + 32; if (r32 > N) r32 = N;
            int lo = rowptr[gg * 32];
            int hi = rowptr[r32];
            if (lo == hi) {
                bool claim = (lo >= e0 && lo < e0 + 64) ||
                             (lo >= nE && blockIdx.x == gridDim.x - 1);
                if (claim && wincnt < 128) winlist[wincnt++] = gg;
            }
        }
    }
    __syncthreads();
    const int nwin = wincnt;               // block-uniform
    for (int i = 0; i < nwin; ++i)
        node_group(winlist[i], xb, agg, nwf, nb, batch, sums,
                   w1sf_nxt, w1bf_nxt, b1_nxt, Ys_out, Y_out, last, N, t);
}

// ---------------- readout ---------------------------------------------------
__global__ __launch_bounds__(HID) void readout_kernel(
        const float* __restrict__ sums, const float* __restrict__ counts,
        const float* __restrict__ rw1, const float* __restrict__ rb1,
        const float* __restrict__ rw2, const float* __restrict__ rb2,
        float* __restrict__ pred) {
    __shared__ float gv[HID];
    __shared__ float hv[HID];
    const int g = blockIdx.x;
    const int t = threadIdx.x;
    float c = counts[g];
    if (c < 1.0f) c = 1.0f;
    gv[t] = sums[(size_t)g * HID + t] / c;   // cold path: keep exact division
    __syncthreads();
    float acc = rb1[t];
    for (int k4 = 0; k4 < 32; ++k4) {
        float4 mv = *(const float4*)&gv[k4 * 4];
        #pragma unroll
        for (int j = 0; j < 4; ++j)
            acc += ((const float*)&mv)[j] * rw1[(size_t)(k4 * 4 + j) * HID + t];
    }
    hv[t] = silu_f(acc) * rw2[t];
    __syncthreads();
    for (int s = HID / 2; s > 0; s >>= 1) {
        if (t < s) hv[t] += hv[t + s];
        __syncthreads();
    }
    if (t == 0) pred[g] = hv[0] + rb2[0];
}

extern "C" void kernel_launch(void* const* d_in, const int* in_sizes, int n_in,
                              void* d_out, int out_size, void* d_ws, size_t ws_size,
                              hipStream_t stream) {
    const int*   z          = (const int*)d_in[0];
    const int*   edge_index = (const int*)d_in[1];
    const float* edge_attr  = (const float*)d_in[2];
    const int*   batch      = (const int*)d_in[3];
    const float* emb        = (const float*)d_in[4];
    const float* ew1        = (const float*)d_in[5];
    const float* eb1        = (const float*)d_in[6];
    const float* ew2        = (const float*)d_in[7];
    const float* eb2        = (const float*)d_in[8];
    const float* nw         = (const float*)d_in[9];
    const float* nb         = (const float*)d_in[10];
    const float* rw1        = (const float*)d_in[11];
    const float* rb1        = (const float*)d_in[12];
    const float* rw2        = (const float*)d_in[13];
    const float* rb2        = (const float*)d_in[14];
    float* pred = (float*)d_out;

    const int N = in_sizes[0];
    const int E = in_sizes[1] / 2;
    const int G = out_size;
    const int* srcI = edge_index;
    const int* dstI = edge_index + E;
    const int nG = (N + 31) / 32;
    const int nTiles = (E + 63) / 64;

    char* base = (char*)d_ws;
    size_t off = 0;
    auto carve = [&](size_t bytes) -> char* {
        char* p = base + off;
        off = (off + bytes + 255) & ~(size_t)255;
        return p;
    };
    float* agg    = (float*)carve((size_t)N * HID * sizeof(float));
    float* sums   = (float*)carve((size_t)G * HID * sizeof(float));
    float* cnts_g = (float*)carve((size_t)G * sizeof(float));
    u16*   xb     = (u16*)carve((size_t)N * HID * sizeof(u16));
    u16*   Y0     = (u16*)carve((size_t)N * HID * sizeof(u16));   // dst-proj ping
    u16*   Ys0    = (u16*)carve((size_t)N * HID * sizeof(u16));   // src-proj ping
    u16*   Y1     = (u16*)carve((size_t)N * HID * sizeof(u16));   // dst-proj pong
    u16*   Ys1    = (u16*)carve((size_t)N * HID * sizeof(u16));   // src-proj pong
    int*   srcS   = (int*)carve((size_t)(E + 64) * sizeof(int));
    int*   dstS   = (int*)carve((size_t)(E + 64) * sizeof(int));
    u16*   eaS    = (u16*)carve((size_t)(E + 64) * 4 * sizeof(u16));
    int*   rowptr = (int*)carve((size_t)(N + 1) * sizeof(int));
    int*   cursor = (int*)carve((size_t)N * sizeof(int));
    int*   cnt    = (int*)carve((size_t)N * sizeof(int));
    int*   cntg4  = (int*)carve((size_t)4 * nG * sizeof(int));
    u16*   w1sf   = (u16*)carve((size_t)4 * 32 * 512 * sizeof(u16)); // KT=4 src
    u16*   w1tf   = (u16*)carve((size_t)4 * 8 * 512 * sizeof(u16));  // KT=1 attr
    u16*   w1bf   = (u16*)carve((size_t)4 * 32 * 512 * sizeof(u16)); // KT=4 dst
    u16*   w2f    = (u16*)carve((size_t)4 * 32 * 512 * sizeof(u16)); // KT=4
    u16*   nwf    = (u16*)carve((size_t)4 * 64 * 512 * sizeof(u16)); // KT=8

    // ---- fused setup: weight swizzle + zero cnt/cursor/sums/counts ----
    {
        long long total = (long long)T1S + T1T + T1B + T2 + T3
                        + 2LL * N + (long long)G * HID + G;
        int blocks = (int)((total + 255) / 256);
        setup_kernel<<<blocks, 256, 0, stream>>>(ew1, ew2, nw, w1sf, w1tf, w1bf,
                                                 w2f, nwf, cnt, cursor,
                                                 sums, cnts_g, N, G);
    }

    // ---- CSR build (dst-sorted edges) + per-layer group tile counters ----
    hist_kernel<<<(E + 255) / 256, 256, 0, stream>>>(dstI, cnt, E);
    scan_kernel<<<1, 1024, 0, stream>>>(cnt, rowptr, cntg4, nG, N);
    scatter_kernel<<<(E + 255) / 256, 256, 0, stream>>>(
        srcI, dstI, edge_attr, rowptr, cursor, srcS, dstS, eaS, E);

    // embed + zero agg + counts + layer-0 projections
    embed_ys_kernel<<<(N + 31) / 32, 256, 0, stream>>>(
        z, emb, xb, agg, batch, cnts_g, w1sf, w1bf, eb1, Ys0, Y0, N);

    for (int l = 0; l < 4; ++l) {
        int lnxt = (l + 1) & 3;            // l==3: tail skipped (last), unused
        u16* YsIn  = (l & 1) ? Ys1 : Ys0;
        u16* YIn   = (l & 1) ? Y1  : Y0;
        u16* YsOut = (l & 1) ? Ys0 : Ys1;
        u16* YOut  = (l & 1) ? Y0  : Y1;
        edge_node_mfma<<<nTiles, 512, 0, stream>>>(
            srcS, dstS, eaS, rowptr, cntg4 + (size_t)l * nG,
            w1tf + (size_t)l * 8 * 512,
            w2f + (size_t)l * 32 * 512, eb2 + (size_t)l * HID,
            YsIn, YIn,
            xb, agg, nwf + (size_t)l * 64 * 512, nb + (size_t)l * HID,
            batch, sums,
            w1sf + (size_t)lnxt * 32 * 512, w1bf + (size_t)lnxt * 32 * 512,
            eb1 + (size_t)lnxt * HID,
            YsOut, YOut,
            (l == 3) ? 1 : 0, E, N, nG);
    }

    readout_kernel<<<G, HID, 0, stream>>>(sums, cnts_g, rw1, rb1, rw2, rb2, pred);
}

// Round 13
// 1059.026 us; speedup vs baseline: 4.1132x; 4.1132x over previous
//
#include <hip/hip_runtime.h>
#include <math.h>

#define HID  128
#define EDIM 4

typedef unsigned short u16;
typedef u16    us8   __attribute__((ext_vector_type(8)));
typedef __bf16 bf16x8 __attribute__((ext_vector_type(8)));
typedef float  f32x4 __attribute__((ext_vector_type(4)));

// silu via hw rcp: v_rcp_f32 (~1 ulp) instead of IEEE div (10+ inst w/o fast-math)
__device__ __forceinline__ float silu_f(float v) {
    return v * __builtin_amdgcn_rcpf(1.0f + __expf(-v));
}
__device__ __forceinline__ u16 f2bf(float f) {   // RNE fp32->bf16 (cold paths)
    unsigned u = __float_as_uint(f);
    unsigned r = u + 0x7fffu + ((u >> 16) & 1u);
    return (u16)(r >> 16);
}
__device__ __forceinline__ u16 f2bf_fast(float f) {  // round-half-up, 2 ops (hot)
    return (u16)((__float_as_uint(f) + 0x8000u) >> 16);
}
// pack two fp32 -> one u32 of 2 bf16 (round-half-up)
__device__ __forceinline__ unsigned pack_bf2(float a, float b) {
    return ((__float_as_uint(a) + 0x8000u) >> 16) |
           ((__float_as_uint(b) + 0x8000u) & 0xffff0000u);
}
__device__ __forceinline__ float bf2f(u16 s) {
    return __uint_as_float(((unsigned)s) << 16);
}
__device__ __forceinline__ bf16x8 as_bf(us8 v) {
    return __builtin_bit_cast(bf16x8, v);
}
__device__ __forceinline__ f32x4 bf4f(ushort4 v) {
    f32x4 r;
    r[0] = bf2f(v.x); r[1] = bf2f(v.y); r[2] = bf2f(v.z); r[3] = bf2f(v.w);
    return r;
}

// ---------------- fused setup: weight swizzle + zero-fills ------------------
// Generalized fragment swizzler: logical k -> source row = k + (k>=split ?
// jump : 0); valid iff row < Kdata. Layer stride Kstride rows.
__device__ __forceinline__ void wfrag_gen(const float* __restrict__ w,
        u16* __restrict__ out, int KT, int Kdata, int Kstride,
        int split, int jump, int idx) {
    int lane = idx & 63;
    int f    = (idx >> 6) % (KT * 8);
    int l    = idx / (64 * KT * 8);
    int kt = f >> 3, nt = f & 7;
    int n  = nt * 16 + (lane & 15);
    int k0 = kt * 32 + ((lane >> 4) * 8);
    us8 v;
    #pragma unroll
    for (int j = 0; j < 8; ++j) {
        int k = k0 + j;
        int row = k + (k >= split ? jump : 0);
        v[j] = (row < Kdata) ? f2bf(w[((size_t)l * Kstride + row) * HID + n]) : (u16)0;
    }
    *(us8*)&out[((size_t)(l * KT * 8 + f) * 64 + lane) * 8] = v;
}

// R22 split of W1 [260x128]: w1s (src rows 0..127, KT=4), w1b (dst rows
// 128..255, KT=4), w1t (attr rows 256..259 zero-padded to K=32, KT=1).
#define T1S (4 * 4 * 8 * 64)
#define T1T (4 * 1 * 8 * 64)
#define T1B (4 * 4 * 8 * 64)
#define T2  (4 * 4 * 8 * 64)
#define T3  (4 * 8 * 8 * 64)

__global__ __launch_bounds__(256) void setup_kernel(
        const float* __restrict__ ew1, const float* __restrict__ ew2,
        const float* __restrict__ nw,
        u16* __restrict__ w1sf, u16* __restrict__ w1tf,
        u16* __restrict__ w1bf,
        u16* __restrict__ w2f, u16* __restrict__ nwf,
        int* __restrict__ cnt, int* __restrict__ cursor,
        float* __restrict__ sums, float* __restrict__ cnts_g, int N, int G) {
    const int BIG = 1 << 30;
    int idx = blockIdx.x * 256 + threadIdx.x;
    if (idx < T1S) { wfrag_gen(ew1, w1sf, 4, 128, 260, BIG, 0, idx); return; }
    idx -= T1S;
    if (idx < T1T) { wfrag_gen(ew1, w1tf, 1, 260, 260, 0, 256, idx); return; }
    idx -= T1T;
    if (idx < T1B) { wfrag_gen(ew1, w1bf, 4, 260, 260, 0, 128, idx); return; }
    idx -= T1B;
    if (idx < T2) { wfrag_gen(ew2, w2f, 4, 128, 128, BIG, 0, idx); return; }
    idx -= T2;
    if (idx < T3) { wfrag_gen(nw, nwf, 8, 256, 256, BIG, 0, idx); return; }
    idx -= T3;
    if (idx < N) { cnt[idx] = 0; return; }
    idx -= N;
    if (idx < N) { cursor[idx] = 0; return; }
    idx -= N;
    if (idx < G * HID) { sums[idx] = 0.f; return; }
    idx -= G * HID;
    if (idx < G) { cnts_g[idx] = 0.f; return; }
}

// ---------------- CSR build: hist -> scan ------------------------------------
__global__ __launch_bounds__(256) void hist_kernel(const int* __restrict__ dst,
        int* __restrict__ cnt, int E) {
    int e = blockIdx.x * 256 + threadIdx.x;
    if (e < E) atomicAdd(&cnt[dst[e]], 1);
}

__global__ __launch_bounds__(1024) void scan_kernel(const int* __restrict__ cnt,
        int* __restrict__ rowptr, int n) {
    __shared__ int s[1024];
    const int t = threadIdx.x;
    const int chunk = (n + 1023) >> 10;
    int lo = t * chunk, hi = lo + chunk;
    if (lo > n) lo = n;
    if (hi > n) hi = n;
    int sum = 0;
    for (int i = lo; i < hi; ++i) sum += cnt[i];
    s[t] = sum;
    __syncthreads();
    for (int off = 1; off < 1024; off <<= 1) {
        int v = (t >= off) ? s[t - off] : 0;
        __syncthreads();
        s[t] += v;
        __syncthreads();
    }
    int run = s[t] - sum;
    for (int i = lo; i < hi; ++i) { rowptr[i] = run; run += cnt[i]; }
    if (t == 1023) rowptr[n] = run;
}

// ---------------- shared dual-projection tail -------------------------------
// Ys = x@W1s, Y = b1 + x@W1b from the block's own 32 xb rows; OUTPUT bf16
// (halves edge gather traffic; b1 folded -> edge acc-init is cvt+cvt+add).
// Caller must __syncthreads() after writing those xb rows. 256-thread
// geometry (t in [0,256)).
__device__ __forceinline__ void dual_proj(
        const u16* __restrict__ xb,
        const u16* __restrict__ w1sf, const u16* __restrict__ w1bf,
        const float* __restrict__ b1n,
        u16* __restrict__ Ys, u16* __restrict__ Y,
        int i0, int n, int t) {
    const int wv   = t >> 6, lane = t & 63;
    const int lrow = lane & 15;
    const int kq   = lane >> 4;
    const int kq8  = kq * 8;

    int iN[2];
    #pragma unroll
    for (int mt = 0; mt < 2; ++mt) {
        int i = i0 + mt * 16 + lrow; if (i >= n) i = n - 1;
        iN[mt] = i;
    }
    f32x4 aS[2][2], aB[2][2];
    #pragma unroll
    for (int mt = 0; mt < 2; ++mt)
        #pragma unroll
        for (int nt = 0; nt < 2; ++nt) {
            aS[mt][nt] = (f32x4){0.f, 0.f, 0.f, 0.f};
            aB[mt][nt] = *(const f32x4*)&b1n[(wv * 2 + nt) * 16 + kq * 4];
        }

    #pragma unroll
    for (int kt = 0; kt < 4; ++kt) {
        bf16x8 ws0 = *(const bf16x8*)&w1sf[((size_t)(kt * 8 + wv * 2 + 0) * 64 + lane) * 8];
        bf16x8 ws1 = *(const bf16x8*)&w1sf[((size_t)(kt * 8 + wv * 2 + 1) * 64 + lane) * 8];
        bf16x8 wb0 = *(const bf16x8*)&w1bf[((size_t)(kt * 8 + wv * 2 + 0) * 64 + lane) * 8];
        bf16x8 wb1 = *(const bf16x8*)&w1bf[((size_t)(kt * 8 + wv * 2 + 1) * 64 + lane) * 8];
        #pragma unroll
        for (int mt = 0; mt < 2; ++mt) {
            bf16x8 a = as_bf(*(const us8*)&xb[(size_t)iN[mt] * HID + kt * 32 + kq8]);
            aS[mt][0] = __builtin_amdgcn_mfma_f32_16x16x32_bf16(ws0, a, aS[mt][0], 0, 0, 0);
            aS[mt][1] = __builtin_amdgcn_mfma_f32_16x16x32_bf16(ws1, a, aS[mt][1], 0, 0, 0);
            aB[mt][0] = __builtin_amdgcn_mfma_f32_16x16x32_bf16(wb0, a, aB[mt][0], 0, 0, 0);
            aB[mt][1] = __builtin_amdgcn_mfma_f32_16x16x32_bf16(wb1, a, aB[mt][1], 0, 0, 0);
        }
    }
    #pragma unroll
    for (int mt = 0; mt < 2; ++mt) {
        int node = i0 + mt * 16 + lrow;
        if (node < n) {
            #pragma unroll
            for (int nt = 0; nt < 2; ++nt) {
                uint2 sv, bv;
                sv.x = pack_bf2(aS[mt][nt][0], aS[mt][nt][1]);
                sv.y = pack_bf2(aS[mt][nt][2], aS[mt][nt][3]);
                bv.x = pack_bf2(aB[mt][nt][0], aB[mt][nt][1]);
                bv.y = pack_bf2(aB[mt][nt][2], aB[mt][nt][3]);
                *(uint2*)&Ys[(size_t)node * HID + (wv * 2 + nt) * 16 + kq * 4] = sv;
                *(uint2*)&Y [(size_t)node * HID + (wv * 2 + nt) * 16 + kq * 4] = bv;
            }
        }
    }
}

// ---------------- merged scatter + embed + layer-0 projections ---------------
// R28: scatter_kernel and embed_ys_kernel are INDEPENDENT (scatter writes
// srcS/dstS/eaS from the CSR; embed writes xb/agg/Ys/Y from emb/z) — merged
// into one dispatch with disjoint block ranges to remove one launch boundary.
// Each half is byte-identical to its proven original.
__global__ __launch_bounds__(256) void scatter_embed_kernel(
        const int* __restrict__ src, const int* __restrict__ dst,
        const float* __restrict__ ea, const int* __restrict__ rowptr,
        int* __restrict__ cursor,
        int* __restrict__ srcS, int* __restrict__ dstS, u16* __restrict__ eaS,
        const int* __restrict__ z, const float* __restrict__ emb,
        u16* __restrict__ xb, float* __restrict__ agg,
        const int* __restrict__ batch, float* __restrict__ counts,
        const u16* __restrict__ w1sf, const u16* __restrict__ w1bf,
        const float* __restrict__ b1n,
        u16* __restrict__ Ys, u16* __restrict__ Y,
        int E, int n, int SB) {
    const int t = threadIdx.x;
    if ((int)blockIdx.x < SB) {
        // -------- scatter half (blocks [0, SB)) --------
        int e = blockIdx.x * 256 + t;
        if (e >= E) return;
        int d = dst[e];
        int p = rowptr[d] + atomicAdd(&cursor[d], 1);
        srcS[p] = src[e];
        dstS[p] = d;
        const float* q = &ea[(size_t)e * EDIM];
        ushort4 v;
        v.x = f2bf(q[0]); v.y = f2bf(q[1]); v.z = f2bf(q[2]); v.w = f2bf(q[3]);
        *(ushort4*)&eaS[(size_t)p * 4] = v;
    } else {
        // -------- embed half (blocks [SB, SB+EB)) --------
        const int i0 = (blockIdx.x - SB) * 32;
        #pragma unroll
        for (int j = 0; j < 16; ++j) {
            int idx = j * 256 + t;             // 4096 slots = 32 nodes x 128
            int node = i0 + (idx >> 7), col = idx & 127;
            if (node < n) {
                xb[(size_t)node * HID + col] = f2bf(emb[(size_t)z[node] * HID + col]);
                agg[(size_t)node * HID + col] = 0.f;
            }
        }
        if (t < 32 && i0 + t < n)
            unsafeAtomicAdd(&counts[batch[i0 + t]], 1.0f);
        __syncthreads();   // xb stores drained -> visible block-wide
        dual_proj(xb, w1sf, w1bf, b1n, Ys, Y, i0, n, t);
    }
}

// ---------------- edge MLP: 64 dst-sorted edges/block, 8 waves --------------
// R12 core + R15 wave-local scan + R16 (8 waves, swapped MFMA operands) +
// R17 (dst-dedup) + R22 (src-hoist: GEMM1 attr-only K=32) + R26 (bf16 Ys/Y
// gathers, b1 pre-folded into Y). BYTE-IDENTICAL to R11 (135.5 us measured).
// FAILED variants (do not reintroduce): R9 XOR-swizzle, R13 2x2 wave tiling,
// R16 occupancy 2x, R18 VGPR-persistent weights (spill), R19 node-centric
// fusion (L2 thrash), R5 LDS-transpose node tail, R6 H-split, R9 cooperative
// launch (dropped under graph capture), R10 persistent manual-barrier kernel
// (fence invalidate storm), R12 dataflow-fused edge+node (uncached agg
// coherence reads serialize the tail; occupancy 13%, 1135 us).
__global__ __launch_bounds__(512, 8) void edge_mfma(
        const int* __restrict__ srcS, const int* __restrict__ dstS,
        const u16* __restrict__ eaS,
        const u16* __restrict__ w1tf,
        const u16* __restrict__ w2f, const float* __restrict__ b2,
        const u16* __restrict__ Ys, const u16* __restrict__ Y,
        float* __restrict__ agg, int nE) {
    // A: u16 [64][40] = 5120 B (attr only; dead after GEMM1)
    // H: u16 [64][136] = 17408 B (aliases A; dead after GEMM2)
    // M: f32 [64][132] = 33792 B (aliases A/H; sized to M)
    __shared__ __align__(16) char smem[64 * 132 * 4];
    __shared__ __align__(16) int dsh[64];
    __shared__ __align__(16) int ssh[64];
    u16*   A = (u16*)smem;
    u16*   H = (u16*)smem;
    float* M = (float*)smem;

    const int t    = threadIdx.x;
    const int e0   = blockIdx.x * 64;
    const int wv   = t >> 6, lane = t & 63;
    const int lrow = lane & 15;
    const int kq   = lane >> 4;
    const int kq8  = kq * 8;
    const int rq   = kq * 4;
    const int h    = wv >> 2;     // edge-half this wave owns (0/1)
    const int p    = wv & 3;      // col-pair this wave owns (0..3)

    // ---- stage: dsh/ssh + attr rows (64 x 32 bf16, rows padded to 40) ----
    if (t < 64) {
        int e = e0 + t;
        bool valid = e < nE; if (!valid) e = nE - 1;
        dsh[t] = valid ? dstS[e] : -1;
        ssh[t] = srcS[e];
        ushort4 q = *(const ushort4*)&eaS[(size_t)e * 4];
        int base = t * 40;
        us8 z8 = (us8){0, 0, 0, 0, 0, 0, 0, 0};
        *(us8*)&A[base + 8]  = z8;         // K-pad cols 8..31 zero
        *(us8*)&A[base + 16] = z8;
        *(us8*)&A[base + 24] = z8;
        A[base + 0] = q.x; A[base + 1] = q.y; A[base + 2] = q.z; A[base + 3] = q.w;
        A[base + 4] = 0;   A[base + 5] = 0;   A[base + 6] = 0;   A[base + 7] = 0;
    }
    __syncthreads();

    // ---- GEMM1: attr-only K=32. acc init = cvt(Ys[src]) + cvt(Y[dst])
    //      (b1 already folded into Y). Lane (lrow,kq) holds
    //      n = (p*2+nt)*16 + rq + r, edge = (h*2+mt)*16+lrow.
    f32x4 acc[2][2];
    #pragma unroll
    for (int mt = 0; mt < 2; ++mt) {
        int edge = (h * 2 + mt) * 16 + lrow;
        int d = dsh[edge]; if (d < 0) d = 0;   // tail-safe (unused result)
        int s = ssh[edge];
        #pragma unroll
        for (int nt = 0; nt < 2; ++nt) {
            ushort4 yv = *(const ushort4*)&Y [(size_t)d * HID + (p * 2 + nt) * 16 + rq];
            ushort4 sv = *(const ushort4*)&Ys[(size_t)s * HID + (p * 2 + nt) * 16 + rq];
            acc[mt][nt] = bf4f(yv) + bf4f(sv);
        }
    }
    {
        bf16x8 w0 = *(const bf16x8*)&w1tf[((size_t)(p * 2 + 0) * 64 + lane) * 8];
        bf16x8 w1 = *(const bf16x8*)&w1tf[((size_t)(p * 2 + 1) * 64 + lane) * 8];
        #pragma unroll
        for (int mt = 0; mt < 2; ++mt) {
            bf16x8 a = *(const bf16x8*)&A[((h * 2 + mt) * 16 + lrow) * 40 + kq8];
            acc[mt][0] = __builtin_amdgcn_mfma_f32_16x16x32_bf16(w0, a, acc[mt][0], 0, 0, 0);
            acc[mt][1] = __builtin_amdgcn_mfma_f32_16x16x32_bf16(w1, a, acc[mt][1], 0, 0, 0);
        }
    }
    __syncthreads();   // all A reads done; region reused as H

    // silu -> H: 4 consecutive n per lane -> one packed b64 per (mt,nt)
    #pragma unroll
    for (int mt = 0; mt < 2; ++mt)
        #pragma unroll
        for (int nt = 0; nt < 2; ++nt) {
            uint2 hv;
            hv.x = pack_bf2(silu_f(acc[mt][nt][0]), silu_f(acc[mt][nt][1]));
            hv.y = pack_bf2(silu_f(acc[mt][nt][2]), silu_f(acc[mt][nt][3]));
            int edge = (h * 2 + mt) * 16 + lrow;
            *(uint2*)&H[edge * 136 + (p * 2 + nt) * 16 + rq] = hv;
        }
    __syncthreads();

    // ---- GEMM2: [64 x 128] @ [128 x 128], swapped operands ----
    f32x4 acc2[2][2];
    #pragma unroll
    for (int nt = 0; nt < 2; ++nt) {
        f32x4 bv = *(const f32x4*)&b2[(p * 2 + nt) * 16 + rq];
        acc2[0][nt] = bv; acc2[1][nt] = bv;
    }
    #pragma unroll
    for (int kt = 0; kt < 4; ++kt) {
        bf16x8 w0 = *(const bf16x8*)&w2f[((size_t)(kt * 8 + p * 2 + 0) * 64 + lane) * 8];
        bf16x8 w1 = *(const bf16x8*)&w2f[((size_t)(kt * 8 + p * 2 + 1) * 64 + lane) * 8];
        #pragma unroll
        for (int mt = 0; mt < 2; ++mt) {
            bf16x8 a = *(const bf16x8*)&H[((h * 2 + mt) * 16 + lrow) * 136 + kt * 32 + kq8];
            acc2[mt][0] = __builtin_amdgcn_mfma_f32_16x16x32_bf16(w0, a, acc2[mt][0], 0, 0, 0);
            acc2[mt][1] = __builtin_amdgcn_mfma_f32_16x16x32_bf16(w1, a, acc2[mt][1], 0, 0, 0);
        }
    }
    __syncthreads();   // all H reads complete before M overwrites (aliased WAR)

    // silu -> M: fp32 messages, one float4 store per (mt,nt)
    #pragma unroll
    for (int mt = 0; mt < 2; ++mt)
        #pragma unroll
        for (int nt = 0; nt < 2; ++nt) {
            f32x4 mv;
            #pragma unroll
            for (int r = 0; r < 4; ++r) mv[r] = silu_f(acc2[mt][nt][r]);
            int edge = (h * 2 + mt) * 16 + lrow;
            *(f32x4*)&M[edge * 132 + (p * 2 + nt) * 16 + rq] = mv;
        }

    // ---- wave-local segmented reduction: wave (h,p) scans exactly the
    // 32-row x 32-col M region it wrote (NO barrier; intra-wave DS program
    // order + compiler lgkmcnt waits guarantee visibility). dsh preloaded
    // as 4x ds_read_b128.
    {
        int col = p * 32 + (lane & 31);
        int r0  = h * 32 + (lane >> 5) * 16;   // rows r0..r0+15
        int4 da = *(const int4*)&dsh[r0];
        int4 db = *(const int4*)&dsh[r0 + 4];
        int4 dc = *(const int4*)&dsh[r0 + 8];
        int4 dd = *(const int4*)&dsh[r0 + 12];
        int ds_[16] = {da.x, da.y, da.z, da.w, db.x, db.y, db.z, db.w,
                       dc.x, dc.y, dc.z, dc.w, dd.x, dd.y, dd.z, dd.w};
        float run = 0.f;
        int   cur = ds_[0];
        #pragma unroll
        for (int i = 0; i < 16; ++i) {
            run += M[(r0 + i) * 132 + col];
            int nxt = (i == 15) ? -2 : ds_[i + 1];
            if (cur != nxt) {             // uniform within 32-lane half
                if (cur >= 0)
                    unsafeAtomicAdd(&agg[(size_t)cur * HID + col], run);
                run = 0.f; cur = nxt;
            }
        }
    }
}

// ---------------- node MLP: 32 nodes/block + fused next-layer projections ---
// R2-exact core (non-swapped mfma, scalar xb stores). R23 tail (last==0):
// after xb stores + barrier (vmcnt drain -> L2 visibility), dual_proj on the
// block's own 32 fresh xb rows (bf16 out, b1_nxt folded). Proven R8 pattern.
__global__ __launch_bounds__(256) void node_mfma(
        u16* __restrict__ xb, float* __restrict__ agg,
        const u16* __restrict__ nwf, const float* __restrict__ nb,
        const int* __restrict__ batch, float* __restrict__ sums,
        const u16* __restrict__ w1sf_nxt, const u16* __restrict__ w1bf_nxt,
        const float* __restrict__ b1_nxt,
        u16* __restrict__ Ys, u16* __restrict__ Y,
        int last, int n) {
    const int t    = threadIdx.x;
    const int i0   = blockIdx.x * 32;
    const int wv   = t >> 6, lane = t & 63;
    const int lrow = lane & 15;
    const int kq   = lane >> 4;
    const int kq8  = kq * 8;
    const int rq   = kq * 4;

    int iN[2];
    #pragma unroll
    for (int mt = 0; mt < 2; ++mt) {
        int i = i0 + mt * 16 + lrow; if (i >= n) i = n - 1;
        iN[mt] = i;
    }

    f32x4 acc[2][2];
    {
        float bias0 = nb[wv * 32 + lrow], bias1 = nb[wv * 32 + 16 + lrow];
        #pragma unroll
        for (int mt = 0; mt < 2; ++mt)
            #pragma unroll
            for (int r = 0; r < 4; ++r) {
                acc[mt][0][r] = bias0; acc[mt][1][r] = bias1;
            }
    }
    #pragma unroll
    for (int kt = 0; kt < 4; ++kt) {     // x part (k 0..127)
        bf16x8 w0 = *(const bf16x8*)&nwf[((size_t)(kt * 8 + wv * 2 + 0) * 64 + lane) * 8];
        bf16x8 w1 = *(const bf16x8*)&nwf[((size_t)(kt * 8 + wv * 2 + 1) * 64 + lane) * 8];
        #pragma unroll
        for (int mt = 0; mt < 2; ++mt) {
            bf16x8 a = as_bf(*(const us8*)&xb[(size_t)iN[mt] * HID + kt * 32 + kq8]);
            acc[mt][0] = __builtin_amdgcn_mfma_f32_16x16x32_bf16(a, w0, acc[mt][0], 0, 0, 0);
            acc[mt][1] = __builtin_amdgcn_mfma_f32_16x16x32_bf16(a, w1, acc[mt][1], 0, 0, 0);
        }
    }
    #pragma unroll
    for (int kt = 4; kt < 8; ++kt) {     // agg part (k 128..255), fp32 -> bf16
        bf16x8 w0 = *(const bf16x8*)&nwf[((size_t)(kt * 8 + wv * 2 + 0) * 64 + lane) * 8];
        bf16x8 w1 = *(const bf16x8*)&nwf[((size_t)(kt * 8 + wv * 2 + 1) * 64 + lane) * 8];
        #pragma unroll
        for (int mt = 0; mt < 2; ++mt) {
            const float* pa = &agg[(size_t)iN[mt] * HID + (kt - 4) * 32 + kq8];
            float4 f0 = *(const float4*)pa;
            float4 f1 = *(const float4*)(pa + 4);
            us8 av;
            av[0] = f2bf_fast(f0.x); av[1] = f2bf_fast(f0.y);
            av[2] = f2bf_fast(f0.z); av[3] = f2bf_fast(f0.w);
            av[4] = f2bf_fast(f1.x); av[5] = f2bf_fast(f1.y);
            av[6] = f2bf_fast(f1.z); av[7] = f2bf_fast(f1.w);
            bf16x8 a = as_bf(av);
            acc[mt][0] = __builtin_amdgcn_mfma_f32_16x16x32_bf16(a, w0, acc[mt][0], 0, 0, 0);
            acc[mt][1] = __builtin_amdgcn_mfma_f32_16x16x32_bf16(a, w1, acc[mt][1], 0, 0, 0);
        }
    }

    if (!last) {
        __syncthreads();   // all xb/agg reads in block complete before overwrite
        const float4 z4 = make_float4(0.f, 0.f, 0.f, 0.f);
        #pragma unroll
        for (int kt = 0; kt < 4; ++kt)
            #pragma unroll
            for (int mt = 0; mt < 2; ++mt) {
                float* pa = &agg[(size_t)iN[mt] * HID + kt * 32 + kq8];
                *(float4*)pa = z4; *(float4*)(pa + 4) = z4;
            }
        #pragma unroll
        for (int mt = 0; mt < 2; ++mt)
            #pragma unroll
            for (int nt2 = 0; nt2 < 2; ++nt2)
                #pragma unroll
                for (int r = 0; r < 4; ++r) {
                    int i = i0 + mt * 16 + rq + r;
                    if (i < n)
                        xb[(size_t)i * HID + wv * 32 + nt2 * 16 + lrow] =
                            f2bf_fast(silu_f(acc[mt][nt2][r]));
                }
        __syncthreads();   // xb stores drained (vmcnt0 at barrier) -> visible
        dual_proj(xb, w1sf_nxt, w1bf_nxt, b1_nxt, Ys, Y, i0, n, t);
    } else {
        // final layer: scatter straight into per-graph sums
        #pragma unroll
        for (int mt = 0; mt < 2; ++mt)
            #pragma unroll
            for (int nt2 = 0; nt2 < 2; ++nt2)
                #pragma unroll
                for (int r = 0; r < 4; ++r) {
                    int i = i0 + mt * 16 + rq + r;
                    if (i < n) {
                        int b = batch[i];
                        unsafeAtomicAdd(&sums[(size_t)b * HID + wv * 32 + nt2 * 16 + lrow],
                                        silu_f(acc[mt][nt2][r]));
                    }
                }
    }
}

// ---------------- readout ---------------------------------------------------
__global__ __launch_bounds__(HID) void readout_kernel(
        const float* __restrict__ sums, const float* __restrict__ counts,
        const float* __restrict__ rw1, const float* __restrict__ rb1,
        const float* __restrict__ rw2, const float* __restrict__ rb2,
        float* __restrict__ pred) {
    __shared__ float gv[HID];
    __shared__ float hv[HID];
    const int g = blockIdx.x;
    const int t = threadIdx.x;
    float c = counts[g];
    if (c < 1.0f) c = 1.0f;
    gv[t] = sums[(size_t)g * HID + t] / c;   // cold path: keep exact division
    __syncthreads();
    float acc = rb1[t];
    for (int k4 = 0; k4 < 32; ++k4) {
        float4 mv = *(const float4*)&gv[k4 * 4];
        #pragma unroll
        for (int j = 0; j < 4; ++j)
            acc += ((const float*)&mv)[j] * rw1[(size_t)(k4 * 4 + j) * HID + t];
    }
    hv[t] = silu_f(acc) * rw2[t];
    __syncthreads();
    for (int s = HID / 2; s > 0; s >>= 1) {
        if (t < s) hv[t] += hv[t + s];
        __syncthreads();
    }
    if (t == 0) pred[g] = hv[0] + rb2[0];
}

extern "C" void kernel_launch(void* const* d_in, const int* in_sizes, int n_in,
                              void* d_out, int out_size, void* d_ws, size_t ws_size,
                              hipStream_t stream) {
    const int*   z          = (const int*)d_in[0];
    const int*   edge_index = (const int*)d_in[1];
    const float* edge_attr  = (const float*)d_in[2];
    const int*   batch      = (const int*)d_in[3];
    const float* emb        = (const float*)d_in[4];
    const float* ew1        = (const float*)d_in[5];
    const float* eb1        = (const float*)d_in[6];
    const float* ew2        = (const float*)d_in[7];
    const float* eb2        = (const float*)d_in[8];
    const float* nw         = (const float*)d_in[9];
    const float* nb         = (const float*)d_in[10];
    const float* rw1        = (const float*)d_in[11];
    const float* rb1        = (const float*)d_in[12];
    const float* rw2        = (const float*)d_in[13];
    const float* rb2        = (const float*)d_in[14];
    float* pred = (float*)d_out;

    const int N = in_sizes[0];
    const int E = in_sizes[1] / 2;
    const int G = out_size;
    const int* srcI = edge_index;
    const int* dstI = edge_index + E;

    char* base = (char*)d_ws;
    size_t off = 0;
    auto carve = [&](size_t bytes) -> char* {
        char* p = base + off;
        off = (off + bytes + 255) & ~(size_t)255;
        return p;
    };
    float* agg    = (float*)carve((size_t)N * HID * sizeof(float));
    float* sums   = (float*)carve((size_t)G * HID * sizeof(float));
    float* cnts_g = (float*)carve((size_t)G * sizeof(float));
    u16*   xb     = (u16*)carve((size_t)N * HID * sizeof(u16));
    u16*   Y      = (u16*)carve((size_t)N * HID * sizeof(u16));   // dst-proj (bf16, b1 folded)
    u16*   Ys     = (u16*)carve((size_t)N * HID * sizeof(u16));   // src-proj (bf16)
    int*   srcS   = (int*)carve((size_t)(E + 64) * sizeof(int));
    int*   dstS   = (int*)carve((size_t)(E + 64) * sizeof(int));
    u16*   eaS    = (u16*)carve((size_t)(E + 64) * 4 * sizeof(u16));
    int*   rowptr = (int*)carve((size_t)(N + 1) * sizeof(int));
    int*   cursor = (int*)carve((size_t)N * sizeof(int));
    int*   cnt    = (int*)carve((size_t)N * sizeof(int));
    u16*   w1sf   = (u16*)carve((size_t)4 * 32 * 512 * sizeof(u16)); // KT=4 src
    u16*   w1tf   = (u16*)carve((size_t)4 * 8 * 512 * sizeof(u16));  // KT=1 attr
    u16*   w1bf   = (u16*)carve((size_t)4 * 32 * 512 * sizeof(u16)); // KT=4 dst
    u16*   w2f    = (u16*)carve((size_t)4 * 32 * 512 * sizeof(u16)); // KT=4
    u16*   nwf    = (u16*)carve((size_t)4 * 64 * 512 * sizeof(u16)); // KT=8

    // ---- fused setup: weight swizzle + zero cnt/cursor/sums/counts ----
    {
        long long total = (long long)T1S + T1T + T1B + T2 + T3
                        + 2LL * N + (long long)G * HID + G;
        int blocks = (int)((total + 255) / 256);
        setup_kernel<<<blocks, 256, 0, stream>>>(ew1, ew2, nw, w1sf, w1tf, w1bf,
                                                 w2f, nwf, cnt, cursor,
                                                 sums, cnts_g, N, G);
    }

    // ---- CSR build (dst-sorted edges) ----
    hist_kernel<<<(E + 255) / 256, 256, 0, stream>>>(dstI, cnt, E);
    scan_kernel<<<1, 1024, 0, stream>>>(cnt, rowptr, N);

    // ---- merged scatter + embed + layer-0 projections (independent halves) ----
    {
        const int SB = (E + 255) / 256;
        const int EB = (N + 31) / 32;
        scatter_embed_kernel<<<SB + EB, 256, 0, stream>>>(
            srcI, dstI, edge_attr, rowptr, cursor, srcS, dstS, eaS,
            z, emb, xb, agg, batch, cnts_g, w1sf, w1bf, eb1, Ys, Y, E, N, SB);
    }

    for (int l = 0; l < 4; ++l) {
        edge_mfma<<<(E + 63) / 64, 512, 0, stream>>>(
            srcS, dstS, eaS,
            w1tf + (size_t)l * 8 * 512,
            w2f + (size_t)l * 32 * 512, eb2 + (size_t)l * HID,
            Ys, Y, agg, E);
        int lnxt = (l + 1) & 3;   // l==3: tail skipped (last=1), args unused
        node_mfma<<<(N + 31) / 32, 256, 0, stream>>>(
            xb, agg, nwf + (size_t)l * 64 * 512, nb + (size_t)l * HID,
            batch, sums,
            w1sf + (size_t)lnxt * 32 * 512, w1bf + (size_t)lnxt * 32 * 512,
            eb1 + (size_t)lnxt * HID,
            Ys, Y, (l == 3) ? 1 : 0, N);
    }

    readout_kernel<<<G, HID, 0, stream>>>(sums, cnts_g, rw1, rb1, rw2, rb2, pred);
}

// Round 14
// 1040.786 us; speedup vs baseline: 4.1853x; 1.0175x over previous
//
#include <hip/hip_runtime.h>
#include <math.h>

#define HID  128
#define EDIM 4

typedef unsigned short u16;
typedef u16    us8   __attribute__((ext_vector_type(8)));
typedef __bf16 bf16x8 __attribute__((ext_vector_type(8)));
typedef float  f32x4 __attribute__((ext_vector_type(4)));

// silu via hw rcp: v_rcp_f32 (~1 ulp) instead of IEEE div (10+ inst w/o fast-math)
__device__ __forceinline__ float silu_f(float v) {
    return v * __builtin_amdgcn_rcpf(1.0f + __expf(-v));
}
__device__ __forceinline__ u16 f2bf(float f) {   // RNE fp32->bf16 (cold paths)
    unsigned u = __float_as_uint(f);
    unsigned r = u + 0x7fffu + ((u >> 16) & 1u);
    return (u16)(r >> 16);
}
__device__ __forceinline__ u16 f2bf_fast(float f) {  // round-half-up, 2 ops (hot)
    return (u16)((__float_as_uint(f) + 0x8000u) >> 16);
}
// pack two fp32 -> one u32 of 2 bf16 (round-half-up)
__device__ __forceinline__ unsigned pack_bf2(float a, float b) {
    return ((__float_as_uint(a) + 0x8000u) >> 16) |
           ((__float_as_uint(b) + 0x8000u) & 0xffff0000u);
}
__device__ __forceinline__ float bf2f(u16 s) {
    return __uint_as_float(((unsigned)s) << 16);
}
__device__ __forceinline__ bf16x8 as_bf(us8 v) {
    return __builtin_bit_cast(bf16x8, v);
}
__device__ __forceinline__ f32x4 bf4f(ushort4 v) {
    f32x4 r;
    r[0] = bf2f(v.x); r[1] = bf2f(v.y); r[2] = bf2f(v.z); r[3] = bf2f(v.w);
    return r;
}

// ---------------- fused setup: weight swizzle + zero-fills ------------------
// Generalized fragment swizzler: logical k -> source row = k + (k>=split ?
// jump : 0); valid iff row < Kdata. Layer stride Kstride rows.
__device__ __forceinline__ void wfrag_gen(const float* __restrict__ w,
        u16* __restrict__ out, int KT, int Kdata, int Kstride,
        int split, int jump, int idx) {
    int lane = idx & 63;
    int f    = (idx >> 6) % (KT * 8);
    int l    = idx / (64 * KT * 8);
    int kt = f >> 3, nt = f & 7;
    int n  = nt * 16 + (lane & 15);
    int k0 = kt * 32 + ((lane >> 4) * 8);
    us8 v;
    #pragma unroll
    for (int j = 0; j < 8; ++j) {
        int k = k0 + j;
        int row = k + (k >= split ? jump : 0);
        v[j] = (row < Kdata) ? f2bf(w[((size_t)l * Kstride + row) * HID + n]) : (u16)0;
    }
    *(us8*)&out[((size_t)(l * KT * 8 + f) * 64 + lane) * 8] = v;
}

// R22 split of W1 [260x128]: w1s (src rows 0..127, KT=4), w1b (dst rows
// 128..255, KT=4), w1t (attr rows 256..259 zero-padded to K=32, KT=1).
#define T1S (4 * 4 * 8 * 64)
#define T1T (4 * 1 * 8 * 64)
#define T1B (4 * 4 * 8 * 64)
#define T2  (4 * 4 * 8 * 64)
#define T3  (4 * 8 * 8 * 64)

__global__ __launch_bounds__(256) void setup_kernel(
        const float* __restrict__ ew1, const float* __restrict__ ew2,
        const float* __restrict__ nw,
        u16* __restrict__ w1sf, u16* __restrict__ w1tf,
        u16* __restrict__ w1bf,
        u16* __restrict__ w2f, u16* __restrict__ nwf,
        int* __restrict__ cnt, int* __restrict__ cursor,
        float* __restrict__ sums, float* __restrict__ cnts_g, int N, int G) {
    const int BIG = 1 << 30;
    int idx = blockIdx.x * 256 + threadIdx.x;
    if (idx < T1S) { wfrag_gen(ew1, w1sf, 4, 128, 260, BIG, 0, idx); return; }
    idx -= T1S;
    if (idx < T1T) { wfrag_gen(ew1, w1tf, 1, 260, 260, 0, 256, idx); return; }
    idx -= T1T;
    if (idx < T1B) { wfrag_gen(ew1, w1bf, 4, 260, 260, 0, 128, idx); return; }
    idx -= T1B;
    if (idx < T2) { wfrag_gen(ew2, w2f, 4, 128, 128, BIG, 0, idx); return; }
    idx -= T2;
    if (idx < T3) { wfrag_gen(nw, nwf, 8, 256, 256, BIG, 0, idx); return; }
    idx -= T3;
    if (idx < N) { cnt[idx] = 0; return; }
    idx -= N;
    if (idx < N) { cursor[idx] = 0; return; }
    idx -= N;
    if (idx < G * HID) { sums[idx] = 0.f; return; }
    idx -= G * HID;
    if (idx < G) { cnts_g[idx] = 0.f; return; }
}

// ---------------- CSR build: hist -> scan ------------------------------------
__global__ __launch_bounds__(256) void hist_kernel(const int* __restrict__ dst,
        int* __restrict__ cnt, int E) {
    int e = blockIdx.x * 256 + threadIdx.x;
    if (e < E) atomicAdd(&cnt[dst[e]], 1);
}

__global__ __launch_bounds__(1024) void scan_kernel(const int* __restrict__ cnt,
        int* __restrict__ rowptr, int n) {
    __shared__ int s[1024];
    const int t = threadIdx.x;
    const int chunk = (n + 1023) >> 10;
    int lo = t * chunk, hi = lo + chunk;
    if (lo > n) lo = n;
    if (hi > n) hi = n;
    int sum = 0;
    for (int i = lo; i < hi; ++i) sum += cnt[i];
    s[t] = sum;
    __syncthreads();
    for (int off = 1; off < 1024; off <<= 1) {
        int v = (t >= off) ? s[t - off] : 0;
        __syncthreads();
        s[t] += v;
        __syncthreads();
    }
    int run = s[t] - sum;
    for (int i = lo; i < hi; ++i) { rowptr[i] = run; run += cnt[i]; }
    if (t == 1023) rowptr[n] = run;
}

// ---------------- shared dual-projection tail -------------------------------
// Ys = x@W1s, Y = b1 + x@W1b from the block's own 32 xb rows; OUTPUT bf16
// (halves edge gather traffic; b1 folded -> edge acc-init is cvt+cvt+add).
// Caller must __syncthreads() after writing those xb rows. 256-thread
// geometry (t in [0,256)).
__device__ __forceinline__ void dual_proj(
        const u16* __restrict__ xb,
        const u16* __restrict__ w1sf, const u16* __restrict__ w1bf,
        const float* __restrict__ b1n,
        u16* __restrict__ Ys, u16* __restrict__ Y,
        int i0, int n, int t) {
    const int wv   = t >> 6, lane = t & 63;
    const int lrow = lane & 15;
    const int kq   = lane >> 4;
    const int kq8  = kq * 8;

    int iN[2];
    #pragma unroll
    for (int mt = 0; mt < 2; ++mt) {
        int i = i0 + mt * 16 + lrow; if (i >= n) i = n - 1;
        iN[mt] = i;
    }
    f32x4 aS[2][2], aB[2][2];
    #pragma unroll
    for (int mt = 0; mt < 2; ++mt)
        #pragma unroll
        for (int nt = 0; nt < 2; ++nt) {
            aS[mt][nt] = (f32x4){0.f, 0.f, 0.f, 0.f};
            aB[mt][nt] = *(const f32x4*)&b1n[(wv * 2 + nt) * 16 + kq * 4];
        }

    #pragma unroll
    for (int kt = 0; kt < 4; ++kt) {
        bf16x8 ws0 = *(const bf16x8*)&w1sf[((size_t)(kt * 8 + wv * 2 + 0) * 64 + lane) * 8];
        bf16x8 ws1 = *(const bf16x8*)&w1sf[((size_t)(kt * 8 + wv * 2 + 1) * 64 + lane) * 8];
        bf16x8 wb0 = *(const bf16x8*)&w1bf[((size_t)(kt * 8 + wv * 2 + 0) * 64 + lane) * 8];
        bf16x8 wb1 = *(const bf16x8*)&w1bf[((size_t)(kt * 8 + wv * 2 + 1) * 64 + lane) * 8];
        #pragma unroll
        for (int mt = 0; mt < 2; ++mt) {
            bf16x8 a = as_bf(*(const us8*)&xb[(size_t)iN[mt] * HID + kt * 32 + kq8]);
            aS[mt][0] = __builtin_amdgcn_mfma_f32_16x16x32_bf16(ws0, a, aS[mt][0], 0, 0, 0);
            aS[mt][1] = __builtin_amdgcn_mfma_f32_16x16x32_bf16(ws1, a, aS[mt][1], 0, 0, 0);
            aB[mt][0] = __builtin_amdgcn_mfma_f32_16x16x32_bf16(wb0, a, aB[mt][0], 0, 0, 0);
            aB[mt][1] = __builtin_amdgcn_mfma_f32_16x16x32_bf16(wb1, a, aB[mt][1], 0, 0, 0);
        }
    }
    #pragma unroll
    for (int mt = 0; mt < 2; ++mt) {
        int node = i0 + mt * 16 + lrow;
        if (node < n) {
            #pragma unroll
            for (int nt = 0; nt < 2; ++nt) {
                uint2 sv, bv;
                sv.x = pack_bf2(aS[mt][nt][0], aS[mt][nt][1]);
                sv.y = pack_bf2(aS[mt][nt][2], aS[mt][nt][3]);
                bv.x = pack_bf2(aB[mt][nt][0], aB[mt][nt][1]);
                bv.y = pack_bf2(aB[mt][nt][2], aB[mt][nt][3]);
                *(uint2*)&Ys[(size_t)node * HID + (wv * 2 + nt) * 16 + kq * 4] = sv;
                *(uint2*)&Y [(size_t)node * HID + (wv * 2 + nt) * 16 + kq * 4] = bv;
            }
        }
    }
}

// ---------------- merged scatter + embed + layer-0 projections ---------------
// R28 merge + R29 (this round): AoS edge records. es[p] = {src, dst,
// pack(ea0,ea1), pack(ea2,ea3)} — ONE dwordx4 write per edge to ONE random
// line (was 3 writes to 3 lines across 3 arrays -> ~3x fewer dirty lines;
// scatter half was write-amplification-bound: WRITE 167MB, 150us, pipes idle).
__global__ __launch_bounds__(256) void scatter_embed_kernel(
        const int* __restrict__ src, const int* __restrict__ dst,
        const float* __restrict__ ea, const int* __restrict__ rowptr,
        int* __restrict__ cursor, int4* __restrict__ es,
        const int* __restrict__ z, const float* __restrict__ emb,
        u16* __restrict__ xb, float* __restrict__ agg,
        const int* __restrict__ batch, float* __restrict__ counts,
        const u16* __restrict__ w1sf, const u16* __restrict__ w1bf,
        const float* __restrict__ b1n,
        u16* __restrict__ Ys, u16* __restrict__ Y,
        int E, int n, int SB) {
    const int t = threadIdx.x;
    if ((int)blockIdx.x < SB) {
        // -------- scatter half (blocks [0, SB)) --------
        int e = blockIdx.x * 256 + t;
        if (e >= E) return;
        int d = dst[e];
        int p = rowptr[d] + atomicAdd(&cursor[d], 1);
        const float* q = &ea[(size_t)e * EDIM];
        int4 rec;
        rec.x = src[e];
        rec.y = d;
        rec.z = (int)((unsigned)f2bf(q[0]) | ((unsigned)f2bf(q[1]) << 16));
        rec.w = (int)((unsigned)f2bf(q[2]) | ((unsigned)f2bf(q[3]) << 16));
        es[p] = rec;
    } else {
        // -------- embed half (blocks [SB, SB+EB)) --------
        const int i0 = (blockIdx.x - SB) * 32;
        #pragma unroll
        for (int j = 0; j < 16; ++j) {
            int idx = j * 256 + t;             // 4096 slots = 32 nodes x 128
            int node = i0 + (idx >> 7), col = idx & 127;
            if (node < n) {
                xb[(size_t)node * HID + col] = f2bf(emb[(size_t)z[node] * HID + col]);
                agg[(size_t)node * HID + col] = 0.f;
            }
        }
        if (t < 32 && i0 + t < n)
            unsafeAtomicAdd(&counts[batch[i0 + t]], 1.0f);
        __syncthreads();   // xb stores drained -> visible block-wide
        dual_proj(xb, w1sf, w1bf, b1n, Ys, Y, i0, n, t);
    }
}

// ---------------- edge MLP: 64 dst-sorted edges/block, 8 waves --------------
// R12 core + R15 wave-local scan + R16 (8 waves, swapped MFMA operands) +
// R17 (dst-dedup) + R22 (src-hoist: GEMM1 attr-only K=32) + R26 (bf16 Ys/Y
// gathers, b1 pre-folded into Y) + R29 (AoS es records: one coalesced int4
// per edge in the stage, replacing 3 loads). Compute bodies byte-identical
// to R11/R13 (135.5-139.8 us measured).
// FAILED variants (do not reintroduce): R9 XOR-swizzle, R13 2x2 wave tiling,
// R16 occupancy 2x, R18 VGPR-persistent weights (spill), R19 node-centric
// fusion (L2 thrash), R5 LDS-transpose node tail, R6 H-split, R9 cooperative
// launch (dropped under graph capture), R10 persistent manual-barrier kernel
// (fence invalidate storm), R12 dataflow-fused edge+node (uncached agg
// coherence reads serialize the tail; occupancy 13%, 1135 us).
__global__ __launch_bounds__(512, 8) void edge_mfma(
        const int4* __restrict__ es,
        const u16* __restrict__ w1tf,
        const u16* __restrict__ w2f, const float* __restrict__ b2,
        const u16* __restrict__ Ys, const u16* __restrict__ Y,
        float* __restrict__ agg, int nE) {
    // A: u16 [64][40] = 5120 B (attr only; dead after GEMM1)
    // H: u16 [64][136] = 17408 B (aliases A; dead after GEMM2)
    // M: f32 [64][132] = 33792 B (aliases A/H; sized to M)
    __shared__ __align__(16) char smem[64 * 132 * 4];
    __shared__ __align__(16) int dsh[64];
    __shared__ __align__(16) int ssh[64];
    u16*   A = (u16*)smem;
    u16*   H = (u16*)smem;
    float* M = (float*)smem;

    const int t    = threadIdx.x;
    const int e0   = blockIdx.x * 64;
    const int wv   = t >> 6, lane = t & 63;
    const int lrow = lane & 15;
    const int kq   = lane >> 4;
    const int kq8  = kq * 8;
    const int rq   = kq * 4;
    const int h    = wv >> 2;     // edge-half this wave owns (0/1)
    const int p    = wv & 3;      // col-pair this wave owns (0..3)

    // ---- stage: dsh/ssh + attr rows from ONE int4/edge (rows padded to 40) ----
    if (t < 64) {
        int e = e0 + t;
        bool valid = e < nE; if (!valid) e = nE - 1;
        int4 rec = es[e];
        dsh[t] = valid ? rec.y : -1;
        ssh[t] = rec.x;
        int base = t * 40;
        us8 z8 = (us8){0, 0, 0, 0, 0, 0, 0, 0};
        *(us8*)&A[base + 8]  = z8;         // K-pad cols 8..31 zero
        *(us8*)&A[base + 16] = z8;
        *(us8*)&A[base + 24] = z8;
        A[base + 0] = (u16)((unsigned)rec.z & 0xffffu);
        A[base + 1] = (u16)((unsigned)rec.z >> 16);
        A[base + 2] = (u16)((unsigned)rec.w & 0xffffu);
        A[base + 3] = (u16)((unsigned)rec.w >> 16);
        A[base + 4] = 0;   A[base + 5] = 0;   A[base + 6] = 0;   A[base + 7] = 0;
    }
    __syncthreads();

    // ---- GEMM1: attr-only K=32. acc init = cvt(Ys[src]) + cvt(Y[dst])
    //      (b1 already folded into Y). Lane (lrow,kq) holds
    //      n = (p*2+nt)*16 + rq + r, edge = (h*2+mt)*16+lrow.
    f32x4 acc[2][2];
    #pragma unroll
    for (int mt = 0; mt < 2; ++mt) {
        int edge = (h * 2 + mt) * 16 + lrow;
        int d = dsh[edge]; if (d < 0) d = 0;   // tail-safe (unused result)
        int s = ssh[edge];
        #pragma unroll
        for (int nt = 0; nt < 2; ++nt) {
            ushort4 yv = *(const ushort4*)&Y [(size_t)d * HID + (p * 2 + nt) * 16 + rq];
            ushort4 sv = *(const ushort4*)&Ys[(size_t)s * HID + (p * 2 + nt) * 16 + rq];
            acc[mt][nt] = bf4f(yv) + bf4f(sv);
        }
    }
    {
        bf16x8 w0 = *(const bf16x8*)&w1tf[((size_t)(p * 2 + 0) * 64 + lane) * 8];
        bf16x8 w1 = *(const bf16x8*)&w1tf[((size_t)(p * 2 + 1) * 64 + lane) * 8];
        #pragma unroll
        for (int mt = 0; mt < 2; ++mt) {
            bf16x8 a = *(const bf16x8*)&A[((h * 2 + mt) * 16 + lrow) * 40 + kq8];
            acc[mt][0] = __builtin_amdgcn_mfma_f32_16x16x32_bf16(w0, a, acc[mt][0], 0, 0, 0);
            acc[mt][1] = __builtin_amdgcn_mfma_f32_16x16x32_bf16(w1, a, acc[mt][1], 0, 0, 0);
        }
    }
    __syncthreads();   // all A reads done; region reused as H

    // silu -> H: 4 consecutive n per lane -> one packed b64 per (mt,nt)
    #pragma unroll
    for (int mt = 0; mt < 2; ++mt)
        #pragma unroll
        for (int nt = 0; nt < 2; ++nt) {
            uint2 hv;
            hv.x = pack_bf2(silu_f(acc[mt][nt][0]), silu_f(acc[mt][nt][1]));
            hv.y = pack_bf2(silu_f(acc[mt][nt][2]), silu_f(acc[mt][nt][3]));
            int edge = (h * 2 + mt) * 16 + lrow;
            *(uint2*)&H[edge * 136 + (p * 2 + nt) * 16 + rq] = hv;
        }
    __syncthreads();

    // ---- GEMM2: [64 x 128] @ [128 x 128], swapped operands ----
    f32x4 acc2[2][2];
    #pragma unroll
    for (int nt = 0; nt < 2; ++nt) {
        f32x4 bv = *(const f32x4*)&b2[(p * 2 + nt) * 16 + rq];
        acc2[0][nt] = bv; acc2[1][nt] = bv;
    }
    #pragma unroll
    for (int kt = 0; kt < 4; ++kt) {
        bf16x8 w0 = *(const bf16x8*)&w2f[((size_t)(kt * 8 + p * 2 + 0) * 64 + lane) * 8];
        bf16x8 w1 = *(const bf16x8*)&w2f[((size_t)(kt * 8 + p * 2 + 1) * 64 + lane) * 8];
        #pragma unroll
        for (int mt = 0; mt < 2; ++mt) {
            bf16x8 a = *(const bf16x8*)&H[((h * 2 + mt) * 16 + lrow) * 136 + kt * 32 + kq8];
            acc2[mt][0] = __builtin_amdgcn_mfma_f32_16x16x32_bf16(w0, a, acc2[mt][0], 0, 0, 0);
            acc2[mt][1] = __builtin_amdgcn_mfma_f32_16x16x32_bf16(w1, a, acc2[mt][1], 0, 0, 0);
        }
    }
    __syncthreads();   // all H reads complete before M overwrites (aliased WAR)

    // silu -> M: fp32 messages, one float4 store per (mt,nt)
    #pragma unroll
    for (int mt = 0; mt < 2; ++mt)
        #pragma unroll
        for (int nt = 0; nt < 2; ++nt) {
            f32x4 mv;
            #pragma unroll
            for (int r = 0; r < 4; ++r) mv[r] = silu_f(acc2[mt][nt][r]);
            int edge = (h * 2 + mt) * 16 + lrow;
            *(f32x4*)&M[edge * 132 + (p * 2 + nt) * 16 + rq] = mv;
        }

    // ---- wave-local segmented reduction: wave (h,p) scans exactly the
    // 32-row x 32-col M region it wrote (NO barrier; intra-wave DS program
    // order + compiler lgkmcnt waits guarantee visibility). dsh preloaded
    // as 4x ds_read_b128.
    {
        int col = p * 32 + (lane & 31);
        int r0  = h * 32 + (lane >> 5) * 16;   // rows r0..r0+15
        int4 da = *(const int4*)&dsh[r0];
        int4 db = *(const int4*)&dsh[r0 + 4];
        int4 dc = *(const int4*)&dsh[r0 + 8];
        int4 dd = *(const int4*)&dsh[r0 + 12];
        int ds_[16] = {da.x, da.y, da.z, da.w, db.x, db.y, db.z, db.w,
                       dc.x, dc.y, dc.z, dc.w, dd.x, dd.y, dd.z, dd.w};
        float run = 0.f;
        int   cur = ds_[0];
        #pragma unroll
        for (int i = 0; i < 16; ++i) {
            run += M[(r0 + i) * 132 + col];
            int nxt = (i == 15) ? -2 : ds_[i + 1];
            if (cur != nxt) {             // uniform within 32-lane half
                if (cur >= 0)
                    unsafeAtomicAdd(&agg[(size_t)cur * HID + col], run);
                run = 0.f; cur = nxt;
            }
        }
    }
}

// ---------------- node MLP: 32 nodes/block + fused next-layer projections ---
// R2-exact core (non-swapped mfma, scalar xb stores). R23 tail (last==0):
// after xb stores + barrier (vmcnt drain -> L2 visibility), dual_proj on the
// block's own 32 fresh xb rows (bf16 out, b1_nxt folded). Proven R8 pattern.
__global__ __launch_bounds__(256) void node_mfma(
        u16* __restrict__ xb, float* __restrict__ agg,
        const u16* __restrict__ nwf, const float* __restrict__ nb,
        const int* __restrict__ batch, float* __restrict__ sums,
        const u16* __restrict__ w1sf_nxt, const u16* __restrict__ w1bf_nxt,
        const float* __restrict__ b1_nxt,
        u16* __restrict__ Ys, u16* __restrict__ Y,
        int last, int n) {
    const int t    = threadIdx.x;
    const int i0   = blockIdx.x * 32;
    const int wv   = t >> 6, lane = t & 63;
    const int lrow = lane & 15;
    const int kq   = lane >> 4;
    const int kq8  = kq * 8;
    const int rq   = kq * 4;

    int iN[2];
    #pragma unroll
    for (int mt = 0; mt < 2; ++mt) {
        int i = i0 + mt * 16 + lrow; if (i >= n) i = n - 1;
        iN[mt] = i;
    }

    f32x4 acc[2][2];
    {
        float bias0 = nb[wv * 32 + lrow], bias1 = nb[wv * 32 + 16 + lrow];
        #pragma unroll
        for (int mt = 0; mt < 2; ++mt)
            #pragma unroll
            for (int r = 0; r < 4; ++r) {
                acc[mt][0][r] = bias0; acc[mt][1][r] = bias1;
            }
    }
    #pragma unroll
    for (int kt = 0; kt < 4; ++kt) {     // x part (k 0..127)
        bf16x8 w0 = *(const bf16x8*)&nwf[((size_t)(kt * 8 + wv * 2 + 0) * 64 + lane) * 8];
        bf16x8 w1 = *(const bf16x8*)&nwf[((size_t)(kt * 8 + wv * 2 + 1) * 64 + lane) * 8];
        #pragma unroll
        for (int mt = 0; mt < 2; ++mt) {
            bf16x8 a = as_bf(*(const us8*)&xb[(size_t)iN[mt] * HID + kt * 32 + kq8]);
            acc[mt][0] = __builtin_amdgcn_mfma_f32_16x16x32_bf16(a, w0, acc[mt][0], 0, 0, 0);
            acc[mt][1] = __builtin_amdgcn_mfma_f32_16x16x32_bf16(a, w1, acc[mt][1], 0, 0, 0);
        }
    }
    #pragma unroll
    for (int kt = 4; kt < 8; ++kt) {     // agg part (k 128..255), fp32 -> bf16
        bf16x8 w0 = *(const bf16x8*)&nwf[((size_t)(kt * 8 + wv * 2 + 0) * 64 + lane) * 8];
        bf16x8 w1 = *(const bf16x8*)&nwf[((size_t)(kt * 8 + wv * 2 + 1) * 64 + lane) * 8];
        #pragma unroll
        for (int mt = 0; mt < 2; ++mt) {
            const float* pa = &agg[(size_t)iN[mt] * HID + (kt - 4) * 32 + kq8];
            float4 f0 = *(const float4*)pa;
            float4 f1 = *(const float4*)(pa + 4);
            us8 av;
            av[0] = f2bf_fast(f0.x); av[1] = f2bf_fast(f0.y);
            av[2] = f2bf_fast(f0.z); av[3] = f2bf_fast(f0.w);
            av[4] = f2bf_fast(f1.x); av[5] = f2bf_fast(f1.y);
            av[6] = f2bf_fast(f1.z); av[7] = f2bf_fast(f1.w);
            bf16x8 a = as_bf(av);
            acc[mt][0] = __builtin_amdgcn_mfma_f32_16x16x32_bf16(a, w0, acc[mt][0], 0, 0, 0);
            acc[mt][1] = __builtin_amdgcn_mfma_f32_16x16x32_bf16(a, w1, acc[mt][1], 0, 0, 0);
        }
    }

    if (!last) {
        __syncthreads();   // all xb/agg reads in block complete before overwrite
        const float4 z4 = make_float4(0.f, 0.f, 0.f, 0.f);
        #pragma unroll
        for (int kt = 0; kt < 4; ++kt)
            #pragma unroll
            for (int mt = 0; mt < 2; ++mt) {
                float* pa = &agg[(size_t)iN[mt] * HID + kt * 32 + kq8];
                *(float4*)pa = z4; *(float4*)(pa + 4) = z4;
            }
        #pragma unroll
        for (int mt = 0; mt < 2; ++mt)
            #pragma unroll
            for (int nt2 = 0; nt2 < 2; ++nt2)
                #pragma unroll
                for (int r = 0; r < 4; ++r) {
                    int i = i0 + mt * 16 + rq + r;
                    if (i < n)
                        xb[(size_t)i * HID + wv * 32 + nt2 * 16 + lrow] =
                            f2bf_fast(silu_f(acc[mt][nt2][r]));
                }
        __syncthreads();   // xb stores drained (vmcnt0 at barrier) -> visible
        dual_proj(xb, w1sf_nxt, w1bf_nxt, b1_nxt, Ys, Y, i0, n, t);
    } else {
        // final layer: scatter straight into per-graph sums
        #pragma unroll
        for (int mt = 0; mt < 2; ++mt)
            #pragma unroll
            for (int nt2 = 0; nt2 < 2; ++nt2)
                #pragma unroll
                for (int r = 0; r < 4; ++r) {
                    int i = i0 + mt * 16 + rq + r;
                    if (i < n) {
                        int b = batch[i];
                        unsafeAtomicAdd(&sums[(size_t)b * HID + wv * 32 + nt2 * 16 + lrow],
                                        silu_f(acc[mt][nt2][r]));
                    }
                }
    }
}

// ---------------- readout ---------------------------------------------------
__global__ __launch_bounds__(HID) void readout_kernel(
        const float* __restrict__ sums, const float* __restrict__ counts,
        const float* __restrict__ rw1, const float* __restrict__ rb1,
        const float* __restrict__ rw2, const float* __restrict__ rb2,
        float* __restrict__ pred) {
    __shared__ float gv[HID];
    __shared__ float hv[HID];
    const int g = blockIdx.x;
    const int t = threadIdx.x;
    float c = counts[g];
    if (c < 1.0f) c = 1.0f;
    gv[t] = sums[(size_t)g * HID + t] / c;   // cold path: keep exact division
    __syncthreads();
    float acc = rb1[t];
    for (int k4 = 0; k4 < 32; ++k4) {
        float4 mv = *(const float4*)&gv[k4 * 4];
        #pragma unroll
        for (int j = 0; j < 4; ++j)
            acc += ((const float*)&mv)[j] * rw1[(size_t)(k4 * 4 + j) * HID + t];
    }
    hv[t] = silu_f(acc) * rw2[t];
    __syncthreads();
    for (int s = HID / 2; s > 0; s >>= 1) {
        if (t < s) hv[t] += hv[t + s];
        __syncthreads();
    }
    if (t == 0) pred[g] = hv[0] + rb2[0];
}

extern "C" void kernel_launch(void* const* d_in, const int* in_sizes, int n_in,
                              void* d_out, int out_size, void* d_ws, size_t ws_size,
                              hipStream_t stream) {
    const int*   z          = (const int*)d_in[0];
    const int*   edge_index = (const int*)d_in[1];
    const float* edge_attr  = (const float*)d_in[2];
    const int*   batch      = (const int*)d_in[3];
    const float* emb        = (const float*)d_in[4];
    const float* ew1        = (const float*)d_in[5];
    const float* eb1        = (const float*)d_in[6];
    const float* ew2        = (const float*)d_in[7];
    const float* eb2        = (const float*)d_in[8];
    const float* nw         = (const float*)d_in[9];
    const float* nb         = (const float*)d_in[10];
    const float* rw1        = (const float*)d_in[11];
    const float* rb1        = (const float*)d_in[12];
    const float* rw2        = (const float*)d_in[13];
    const float* rb2        = (const float*)d_in[14];
    float* pred = (float*)d_out;

    const int N = in_sizes[0];
    const int E = in_sizes[1] / 2;
    const int G = out_size;
    const int* srcI = edge_index;
    const int* dstI = edge_index + E;

    char* base = (char*)d_ws;
    size_t off = 0;
    auto carve = [&](size_t bytes) -> char* {
        char* p = base + off;
        off = (off + bytes + 255) & ~(size_t)255;
        return p;
    };
    float* agg    = (float*)carve((size_t)N * HID * sizeof(float));
    float* sums   = (float*)carve((size_t)G * HID * sizeof(float));
    float* cnts_g = (float*)carve((size_t)G * sizeof(float));
    u16*   xb     = (u16*)carve((size_t)N * HID * sizeof(u16));
    u16*   Y      = (u16*)carve((size_t)N * HID * sizeof(u16));   // dst-proj (bf16, b1 folded)
    u16*   Ys     = (u16*)carve((size_t)N * HID * sizeof(u16));   // src-proj (bf16)
    int4*  es     = (int4*)carve((size_t)(E + 64) * sizeof(int4)); // AoS edge recs
    int*   rowptr = (int*)carve((size_t)(N + 1) * sizeof(int));
    int*   cursor = (int*)carve((size_t)N * sizeof(int));
    int*   cnt    = (int*)carve((size_t)N * sizeof(int));
    u16*   w1sf   = (u16*)carve((size_t)4 * 32 * 512 * sizeof(u16)); // KT=4 src
    u16*   w1tf   = (u16*)carve((size_t)4 * 8 * 512 * sizeof(u16));  // KT=1 attr
    u16*   w1bf   = (u16*)carve((size_t)4 * 32 * 512 * sizeof(u16)); // KT=4 dst
    u16*   w2f    = (u16*)carve((size_t)4 * 32 * 512 * sizeof(u16)); // KT=4
    u16*   nwf    = (u16*)carve((size_t)4 * 64 * 512 * sizeof(u16)); // KT=8

    // ---- fused setup: weight swizzle + zero cnt/cursor/sums/counts ----
    {
        long long total = (long long)T1S + T1T + T1B + T2 + T3
                        + 2LL * N + (long long)G * HID + G;
        int blocks = (int)((total + 255) / 256);
        setup_kernel<<<blocks, 256, 0, stream>>>(ew1, ew2, nw, w1sf, w1tf, w1bf,
                                                 w2f, nwf, cnt, cursor,
                                                 sums, cnts_g, N, G);
    }

    // ---- CSR build (dst-sorted edges) ----
    hist_kernel<<<(E + 255) / 256, 256, 0, stream>>>(dstI, cnt, E);
    scan_kernel<<<1, 1024, 0, stream>>>(cnt, rowptr, N);

    // ---- merged scatter + embed + layer-0 projections (independent halves) ----
    {
        const int SB = (E + 255) / 256;
        const int EB = (N + 31) / 32;
        scatter_embed_kernel<<<SB + EB, 256, 0, stream>>>(
            srcI, dstI, edge_attr, rowptr, cursor, es,
            z, emb, xb, agg, batch, cnts_g, w1sf, w1bf, eb1, Ys, Y, E, N, SB);
    }

    for (int l = 0; l < 4; ++l) {
        edge_mfma<<<(E + 63) / 64, 512, 0, stream>>>(
            es,
            w1tf + (size_t)l * 8 * 512,
            w2f + (size_t)l * 32 * 512, eb2 + (size_t)l * HID,
            Ys, Y, agg, E);
        int lnxt = (l + 1) & 3;   // l==3: tail skipped (last=1), args unused
        node_mfma<<<(N + 31) / 32, 256, 0, stream>>>(
            xb, agg, nwf + (size_t)l * 64 * 512, nb + (size_t)l * HID,
            batch, sums,
            w1sf + (size_t)lnxt * 32 * 512, w1bf + (size_t)lnxt * 32 * 512,
            eb1 + (size_t)lnxt * HID,
            Ys, Y, (l == 3) ? 1 : 0, N);
    }

    readout_kernel<<<G, HID, 0, stream>>>(sums, cnts_g, rw1, rb1, rw2, rb2, pred);
}

// Round 15
// 993.305 us; speedup vs baseline: 4.3853x; 1.0478x over previous
//
#include <hip/hip_runtime.h>
#include <hip/hip_bf16.h>
#include <math.h>

#define HID  128
#define EDIM 4

typedef unsigned short u16;
typedef u16    us8   __attribute__((ext_vector_type(8)));
typedef __bf16 bf16x8 __attribute__((ext_vector_type(8)));
typedef float  f32x4 __attribute__((ext_vector_type(4)));

// silu via hw rcp: v_rcp_f32 (~1 ulp) instead of IEEE div (10+ inst w/o fast-math)
__device__ __forceinline__ float silu_f(float v) {
    return v * __builtin_amdgcn_rcpf(1.0f + __expf(-v));
}
__device__ __forceinline__ u16 f2bf(float f) {   // RNE fp32->bf16 (cold paths)
    unsigned u = __float_as_uint(f);
    unsigned r = u + 0x7fffu + ((u >> 16) & 1u);
    return (u16)(r >> 16);
}
__device__ __forceinline__ u16 f2bf_fast(float f) {  // round-half-up, 2 ops (hot)
    return (u16)((__float_as_uint(f) + 0x8000u) >> 16);
}
// pack two fp32 -> one u32 of 2 bf16 (round-half-up)
__device__ __forceinline__ unsigned pack_bf2(float a, float b) {
    return ((__float_as_uint(a) + 0x8000u) >> 16) |
           ((__float_as_uint(b) + 0x8000u) & 0xffff0000u);
}
__device__ __forceinline__ float bf2f(u16 s) {
    return __uint_as_float(((unsigned)s) << 16);
}
__device__ __forceinline__ bf16x8 as_bf(us8 v) {
    return __builtin_bit_cast(bf16x8, v);
}
__device__ __forceinline__ f32x4 bf4f(ushort4 v) {
    f32x4 r;
    r[0] = bf2f(v.x); r[1] = bf2f(v.y); r[2] = bf2f(v.z); r[3] = bf2f(v.w);
    return r;
}

// ---------------- fused setup: weight swizzle + zero-fills ------------------
// Generalized fragment swizzler: logical k -> source row = k + (k>=split ?
// jump : 0); valid iff row < Kdata. Layer stride Kstride rows.
__device__ __forceinline__ void wfrag_gen(const float* __restrict__ w,
        u16* __restrict__ out, int KT, int Kdata, int Kstride,
        int split, int jump, int idx) {
    int lane = idx & 63;
    int f    = (idx >> 6) % (KT * 8);
    int l    = idx / (64 * KT * 8);
    int kt = f >> 3, nt = f & 7;
    int n  = nt * 16 + (lane & 15);
    int k0 = kt * 32 + ((lane >> 4) * 8);
    us8 v;
    #pragma unroll
    for (int j = 0; j < 8; ++j) {
        int k = k0 + j;
        int row = k + (k >= split ? jump : 0);
        v[j] = (row < Kdata) ? f2bf(w[((size_t)l * Kstride + row) * HID + n]) : (u16)0;
    }
    *(us8*)&out[((size_t)(l * KT * 8 + f) * 64 + lane) * 8] = v;
}

// R22 split of W1 [260x128]: w1s (src rows 0..127, KT=4), w1b (dst rows
// 128..255, KT=4), w1t (attr rows 256..259 zero-padded to K=32, KT=1).
#define T1S (4 * 4 * 8 * 64)
#define T1T (4 * 1 * 8 * 64)
#define T1B (4 * 4 * 8 * 64)
#define T2  (4 * 4 * 8 * 64)
#define T3  (4 * 8 * 8 * 64)

__global__ __launch_bounds__(256) void setup_kernel(
        const float* __restrict__ ew1, const float* __restrict__ ew2,
        const float* __restrict__ nw,
        u16* __restrict__ w1sf, u16* __restrict__ w1tf,
        u16* __restrict__ w1bf,
        u16* __restrict__ w2f, u16* __restrict__ nwf,
        int* __restrict__ cnt, int* __restrict__ cursor,
        float* __restrict__ sums, float* __restrict__ cnts_g, int N, int G) {
    const int BIG = 1 << 30;
    int idx = blockIdx.x * 256 + threadIdx.x;
    if (idx < T1S) { wfrag_gen(ew1, w1sf, 4, 128, 260, BIG, 0, idx); return; }
    idx -= T1S;
    if (idx < T1T) { wfrag_gen(ew1, w1tf, 1, 260, 260, 0, 256, idx); return; }
    idx -= T1T;
    if (idx < T1B) { wfrag_gen(ew1, w1bf, 4, 260, 260, 0, 128, idx); return; }
    idx -= T1B;
    if (idx < T2) { wfrag_gen(ew2, w2f, 4, 128, 128, BIG, 0, idx); return; }
    idx -= T2;
    if (idx < T3) { wfrag_gen(nw, nwf, 8, 256, 256, BIG, 0, idx); return; }
    idx -= T3;
    if (idx < N) { cnt[idx] = 0; return; }
    idx -= N;
    if (idx < N) { cursor[idx] = 0; return; }
    idx -= N;
    if (idx < G * HID) { sums[idx] = 0.f; return; }
    idx -= G * HID;
    if (idx < G) { cnts_g[idx] = 0.f; return; }
}

// ---------------- CSR build: hist -> scan ------------------------------------
__global__ __launch_bounds__(256) void hist_kernel(const int* __restrict__ dst,
        int* __restrict__ cnt, int E) {
    int e = blockIdx.x * 256 + threadIdx.x;
    if (e < E) atomicAdd(&cnt[dst[e]], 1);
}

__global__ __launch_bounds__(1024) void scan_kernel(const int* __restrict__ cnt,
        int* __restrict__ rowptr, int n) {
    __shared__ int s[1024];
    const int t = threadIdx.x;
    const int chunk = (n + 1023) >> 10;
    int lo = t * chunk, hi = lo + chunk;
    if (lo > n) lo = n;
    if (hi > n) hi = n;
    int sum = 0;
    for (int i = lo; i < hi; ++i) sum += cnt[i];
    s[t] = sum;
    __syncthreads();
    for (int off = 1; off < 1024; off <<= 1) {
        int v = (t >= off) ? s[t - off] : 0;
        __syncthreads();
        s[t] += v;
        __syncthreads();
    }
    int run = s[t] - sum;
    for (int i = lo; i < hi; ++i) { rowptr[i] = run; run += cnt[i]; }
    if (t == 1023) rowptr[n] = run;
}

// ---------------- shared dual-projection tail -------------------------------
// Ys = x@W1s, Y = b1 + x@W1b from the block's own 32 xb rows; OUTPUT bf16
// (halves edge gather traffic; b1 folded -> edge acc-init is cvt+cvt+add).
// Caller must __syncthreads() after writing those xb rows. 256-thread
// geometry (t in [0,256)).
__device__ __forceinline__ void dual_proj(
        const u16* __restrict__ xb,
        const u16* __restrict__ w1sf, const u16* __restrict__ w1bf,
        const float* __restrict__ b1n,
        u16* __restrict__ Ys, u16* __restrict__ Y,
        int i0, int n, int t) {
    const int wv   = t >> 6, lane = t & 63;
    const int lrow = lane & 15;
    const int kq   = lane >> 4;
    const int kq8  = kq * 8;

    int iN[2];
    #pragma unroll
    for (int mt = 0; mt < 2; ++mt) {
        int i = i0 + mt * 16 + lrow; if (i >= n) i = n - 1;
        iN[mt] = i;
    }
    f32x4 aS[2][2], aB[2][2];
    #pragma unroll
    for (int mt = 0; mt < 2; ++mt)
        #pragma unroll
        for (int nt = 0; nt < 2; ++nt) {
            aS[mt][nt] = (f32x4){0.f, 0.f, 0.f, 0.f};
            aB[mt][nt] = *(const f32x4*)&b1n[(wv * 2 + nt) * 16 + kq * 4];
        }

    #pragma unroll
    for (int kt = 0; kt < 4; ++kt) {
        bf16x8 ws0 = *(const bf16x8*)&w1sf[((size_t)(kt * 8 + wv * 2 + 0) * 64 + lane) * 8];
        bf16x8 ws1 = *(const bf16x8*)&w1sf[((size_t)(kt * 8 + wv * 2 + 1) * 64 + lane) * 8];
        bf16x8 wb0 = *(const bf16x8*)&w1bf[((size_t)(kt * 8 + wv * 2 + 0) * 64 + lane) * 8];
        bf16x8 wb1 = *(const bf16x8*)&w1bf[((size_t)(kt * 8 + wv * 2 + 1) * 64 + lane) * 8];
        #pragma unroll
        for (int mt = 0; mt < 2; ++mt) {
            bf16x8 a = as_bf(*(const us8*)&xb[(size_t)iN[mt] * HID + kt * 32 + kq8]);
            aS[mt][0] = __builtin_amdgcn_mfma_f32_16x16x32_bf16(ws0, a, aS[mt][0], 0, 0, 0);
            aS[mt][1] = __builtin_amdgcn_mfma_f32_16x16x32_bf16(ws1, a, aS[mt][1], 0, 0, 0);
            aB[mt][0] = __builtin_amdgcn_mfma_f32_16x16x32_bf16(wb0, a, aB[mt][0], 0, 0, 0);
            aB[mt][1] = __builtin_amdgcn_mfma_f32_16x16x32_bf16(wb1, a, aB[mt][1], 0, 0, 0);
        }
    }
    #pragma unroll
    for (int mt = 0; mt < 2; ++mt) {
        int node = i0 + mt * 16 + lrow;
        if (node < n) {
            #pragma unroll
            for (int nt = 0; nt < 2; ++nt) {
                uint2 sv, bv;
                sv.x = pack_bf2(aS[mt][nt][0], aS[mt][nt][1]);
                sv.y = pack_bf2(aS[mt][nt][2], aS[mt][nt][3]);
                bv.x = pack_bf2(aB[mt][nt][0], aB[mt][nt][1]);
                bv.y = pack_bf2(aB[mt][nt][2], aB[mt][nt][3]);
                *(uint2*)&Ys[(size_t)node * HID + (wv * 2 + nt) * 16 + kq * 4] = sv;
                *(uint2*)&Y [(size_t)node * HID + (wv * 2 + nt) * 16 + kq * 4] = bv;
            }
        }
    }
}

// ---------------- merged scatter + embed + layer-0 projections ---------------
// R28 merge + R29 AoS edge records (one dwordx4 write per edge).
// R30: agg is bf16 now -> embed zeroes u16 cells.
__global__ __launch_bounds__(256) void scatter_embed_kernel(
        const int* __restrict__ src, const int* __restrict__ dst,
        const float* __restrict__ ea, const int* __restrict__ rowptr,
        int* __restrict__ cursor, int4* __restrict__ es,
        const int* __restrict__ z, const float* __restrict__ emb,
        u16* __restrict__ xb, u16* __restrict__ agg,
        const int* __restrict__ batch, float* __restrict__ counts,
        const u16* __restrict__ w1sf, const u16* __restrict__ w1bf,
        const float* __restrict__ b1n,
        u16* __restrict__ Ys, u16* __restrict__ Y,
        int E, int n, int SB) {
    const int t = threadIdx.x;
    if ((int)blockIdx.x < SB) {
        // -------- scatter half (blocks [0, SB)) --------
        int e = blockIdx.x * 256 + t;
        if (e >= E) return;
        int d = dst[e];
        int p = rowptr[d] + atomicAdd(&cursor[d], 1);
        const float* q = &ea[(size_t)e * EDIM];
        int4 rec;
        rec.x = src[e];
        rec.y = d;
        rec.z = (int)((unsigned)f2bf(q[0]) | ((unsigned)f2bf(q[1]) << 16));
        rec.w = (int)((unsigned)f2bf(q[2]) | ((unsigned)f2bf(q[3]) << 16));
        es[p] = rec;
    } else {
        // -------- embed half (blocks [SB, SB+EB)) --------
        const int i0 = (blockIdx.x - SB) * 32;
        #pragma unroll
        for (int j = 0; j < 16; ++j) {
            int idx = j * 256 + t;             // 4096 slots = 32 nodes x 128
            int node = i0 + (idx >> 7), col = idx & 127;
            if (node < n) {
                xb[(size_t)node * HID + col] = f2bf(emb[(size_t)z[node] * HID + col]);
                agg[(size_t)node * HID + col] = 0;     // bf16 zero
            }
        }
        if (t < 32 && i0 + t < n)
            unsafeAtomicAdd(&counts[batch[i0 + t]], 1.0f);
        __syncthreads();   // xb stores drained -> visible block-wide
        dual_proj(xb, w1sf, w1bf, b1n, Ys, Y, i0, n, t);
    }
}

// ---------------- edge MLP: 64 dst-sorted edges/block, 8 waves --------------
// R12 core + R15 wave-local scan + R16 (8 waves, swapped MFMA operands) +
// R17 (dst-dedup) + R22 (src-hoist: GEMM1 attr-only K=32) + R26 (bf16 Ys/Y,
// b1 folded into Y) + R29 (AoS es records) + R30 (this round): agg is BF16;
// scan flushes via packed-bf16 atomics (global_atomic_pk_add_bf16): even
// lane shfl_xor's its odd neighbor's run and issues ONE pk atomic per col
// pair -> half the atomic count, rows dirty 2 lines not 4.
// FAILED variants (do not reintroduce): R9 XOR-swizzle, R13 2x2 wave tiling,
// R16 occupancy 2x, R18 VGPR-persistent weights (spill), R19 node-centric
// fusion (L2 thrash), R5 LDS-transpose node tail, R6 H-split, R9 cooperative
// launch (dropped under graph capture), R10 persistent manual-barrier kernel
// (fence invalidate storm), R12 dataflow-fused edge+node (uncached agg
// coherence reads; 1135 us).
__global__ __launch_bounds__(512, 8) void edge_mfma(
        const int4* __restrict__ es,
        const u16* __restrict__ w1tf,
        const u16* __restrict__ w2f, const float* __restrict__ b2,
        const u16* __restrict__ Ys, const u16* __restrict__ Y,
        u16* __restrict__ agg, int nE) {
    // A: u16 [64][40] = 5120 B (attr only; dead after GEMM1)
    // H: u16 [64][136] = 17408 B (aliases A; dead after GEMM2)
    // M: f32 [64][132] = 33792 B (aliases A/H; sized to M)
    __shared__ __align__(16) char smem[64 * 132 * 4];
    __shared__ __align__(16) int dsh[64];
    __shared__ __align__(16) int ssh[64];
    u16*   A = (u16*)smem;
    u16*   H = (u16*)smem;
    float* M = (float*)smem;

    const int t    = threadIdx.x;
    const int e0   = blockIdx.x * 64;
    const int wv   = t >> 6, lane = t & 63;
    const int lrow = lane & 15;
    const int kq   = lane >> 4;
    const int kq8  = kq * 8;
    const int rq   = kq * 4;
    const int h    = wv >> 2;     // edge-half this wave owns (0/1)
    const int p    = wv & 3;      // col-pair this wave owns (0..3)

    // ---- stage: dsh/ssh + attr rows from ONE int4/edge (rows padded to 40) ----
    if (t < 64) {
        int e = e0 + t;
        bool valid = e < nE; if (!valid) e = nE - 1;
        int4 rec = es[e];
        dsh[t] = valid ? rec.y : -1;
        ssh[t] = rec.x;
        int base = t * 40;
        us8 z8 = (us8){0, 0, 0, 0, 0, 0, 0, 0};
        *(us8*)&A[base + 8]  = z8;         // K-pad cols 8..31 zero
        *(us8*)&A[base + 16] = z8;
        *(us8*)&A[base + 24] = z8;
        A[base + 0] = (u16)((unsigned)rec.z & 0xffffu);
        A[base + 1] = (u16)((unsigned)rec.z >> 16);
        A[base + 2] = (u16)((unsigned)rec.w & 0xffffu);
        A[base + 3] = (u16)((unsigned)rec.w >> 16);
        A[base + 4] = 0;   A[base + 5] = 0;   A[base + 6] = 0;   A[base + 7] = 0;
    }
    __syncthreads();

    // ---- GEMM1: attr-only K=32. acc init = cvt(Ys[src]) + cvt(Y[dst])
    //      (b1 already folded into Y). Lane (lrow,kq) holds
    //      n = (p*2+nt)*16 + rq + r, edge = (h*2+mt)*16+lrow.
    f32x4 acc[2][2];
    #pragma unroll
    for (int mt = 0; mt < 2; ++mt) {
        int edge = (h * 2 + mt) * 16 + lrow;
        int d = dsh[edge]; if (d < 0) d = 0;   // tail-safe (unused result)
        int s = ssh[edge];
        #pragma unroll
        for (int nt = 0; nt < 2; ++nt) {
            ushort4 yv = *(const ushort4*)&Y [(size_t)d * HID + (p * 2 + nt) * 16 + rq];
            ushort4 sv = *(const ushort4*)&Ys[(size_t)s * HID + (p * 2 + nt) * 16 + rq];
            acc[mt][nt] = bf4f(yv) + bf4f(sv);
        }
    }
    {
        bf16x8 w0 = *(const bf16x8*)&w1tf[((size_t)(p * 2 + 0) * 64 + lane) * 8];
        bf16x8 w1 = *(const bf16x8*)&w1tf[((size_t)(p * 2 + 1) * 64 + lane) * 8];
        #pragma unroll
        for (int mt = 0; mt < 2; ++mt) {
            bf16x8 a = *(const bf16x8*)&A[((h * 2 + mt) * 16 + lrow) * 40 + kq8];
            acc[mt][0] = __builtin_amdgcn_mfma_f32_16x16x32_bf16(w0, a, acc[mt][0], 0, 0, 0);
            acc[mt][1] = __builtin_amdgcn_mfma_f32_16x16x32_bf16(w1, a, acc[mt][1], 0, 0, 0);
        }
    }
    __syncthreads();   // all A reads done; region reused as H

    // silu -> H: 4 consecutive n per lane -> one packed b64 per (mt,nt)
    #pragma unroll
    for (int mt = 0; mt < 2; ++mt)
        #pragma unroll
        for (int nt = 0; nt < 2; ++nt) {
            uint2 hv;
            hv.x = pack_bf2(silu_f(acc[mt][nt][0]), silu_f(acc[mt][nt][1]));
            hv.y = pack_bf2(silu_f(acc[mt][nt][2]), silu_f(acc[mt][nt][3]));
            int edge = (h * 2 + mt) * 16 + lrow;
            *(uint2*)&H[edge * 136 + (p * 2 + nt) * 16 + rq] = hv;
        }
    __syncthreads();

    // ---- GEMM2: [64 x 128] @ [128 x 128], swapped operands ----
    f32x4 acc2[2][2];
    #pragma unroll
    for (int nt = 0; nt < 2; ++nt) {
        f32x4 bv = *(const f32x4*)&b2[(p * 2 + nt) * 16 + rq];
        acc2[0][nt] = bv; acc2[1][nt] = bv;
    }
    #pragma unroll
    for (int kt = 0; kt < 4; ++kt) {
        bf16x8 w0 = *(const bf16x8*)&w2f[((size_t)(kt * 8 + p * 2 + 0) * 64 + lane) * 8];
        bf16x8 w1 = *(const bf16x8*)&w2f[((size_t)(kt * 8 + p * 2 + 1) * 64 + lane) * 8];
        #pragma unroll
        for (int mt = 0; mt < 2; ++mt) {
            bf16x8 a = *(const bf16x8*)&H[((h * 2 + mt) * 16 + lrow) * 136 + kt * 32 + kq8];
            acc2[mt][0] = __builtin_amdgcn_mfma_f32_16x16x32_bf16(w0, a, acc2[mt][0], 0, 0, 0);
            acc2[mt][1] = __builtin_amdgcn_mfma_f32_16x16x32_bf16(w1, a, acc2[mt][1], 0, 0, 0);
        }
    }
    __syncthreads();   // all H reads complete before M overwrites (aliased WAR)

    // silu -> M: fp32 messages, one float4 store per (mt,nt)
    #pragma unroll
    for (int mt = 0; mt < 2; ++mt)
        #pragma unroll
        for (int nt = 0; nt < 2; ++nt) {
            f32x4 mv;
            #pragma unroll
            for (int r = 0; r < 4; ++r) mv[r] = silu_f(acc2[mt][nt][r]);
            int edge = (h * 2 + mt) * 16 + lrow;
            *(f32x4*)&M[edge * 132 + (p * 2 + nt) * 16 + rq] = mv;
        }

    // ---- wave-local segmented reduction -> packed-bf16 atomics.
    // Wave (h,p) scans exactly the 32x32 M region it wrote (no barrier;
    // intra-wave DS program order). Run flushes are uniform within each
    // 32-lane half (run boundaries are row-based): even lane takes its odd
    // neighbor's run via shfl_xor and issues ONE pk_add_bf16 per col pair.
    {
        int col = p * 32 + (lane & 31);
        int r0  = h * 32 + (lane >> 5) * 16;   // rows r0..r0+15
        int4 da = *(const int4*)&dsh[r0];
        int4 db = *(const int4*)&dsh[r0 + 4];
        int4 dc = *(const int4*)&dsh[r0 + 8];
        int4 dd = *(const int4*)&dsh[r0 + 12];
        int ds_[16] = {da.x, da.y, da.z, da.w, db.x, db.y, db.z, db.w,
                       dc.x, dc.y, dc.z, dc.w, dd.x, dd.y, dd.z, dd.w};
        float run = 0.f;
        int   cur = ds_[0];
        #pragma unroll
        for (int i = 0; i < 16; ++i) {
            run += M[(r0 + i) * 132 + col];
            int nxt = (i == 15) ? -2 : ds_[i + 1];
            if (cur != nxt) {             // uniform within 32-lane half
                float nbr = __shfl_xor(run, 1);
                if (cur >= 0 && !(col & 1)) {
                    __hip_bfloat162 v;
                    v.x = __float2bfloat16(run);
                    v.y = __float2bfloat16(nbr);
                    unsafeAtomicAdd(
                        (__hip_bfloat162*)&agg[(size_t)cur * HID + col], v);
                }
                run = 0.f; cur = nxt;
            }
        }
    }
}

// ---------------- node MLP: 32 nodes/block + fused next-layer projections ---
// R2-exact core; R30: agg is bf16 -> one us8 (16B) load feeds the MFMA
// directly (was 2 float4 + 8 cvts), zeroing is one us8 store.
__global__ __launch_bounds__(256) void node_mfma(
        u16* __restrict__ xb, u16* __restrict__ agg,
        const u16* __restrict__ nwf, const float* __restrict__ nb,
        const int* __restrict__ batch, float* __restrict__ sums,
        const u16* __restrict__ w1sf_nxt, const u16* __restrict__ w1bf_nxt,
        const float* __restrict__ b1_nxt,
        u16* __restrict__ Ys, u16* __restrict__ Y,
        int last, int n) {
    const int t    = threadIdx.x;
    const int i0   = blockIdx.x * 32;
    const int wv   = t >> 6, lane = t & 63;
    const int lrow = lane & 15;
    const int kq   = lane >> 4;
    const int kq8  = kq * 8;
    const int rq   = kq * 4;

    int iN[2];
    #pragma unroll
    for (int mt = 0; mt < 2; ++mt) {
        int i = i0 + mt * 16 + lrow; if (i >= n) i = n - 1;
        iN[mt] = i;
    }

    f32x4 acc[2][2];
    {
        float bias0 = nb[wv * 32 + lrow], bias1 = nb[wv * 32 + 16 + lrow];
        #pragma unroll
        for (int mt = 0; mt < 2; ++mt)
            #pragma unroll
            for (int r = 0; r < 4; ++r) {
                acc[mt][0][r] = bias0; acc[mt][1][r] = bias1;
            }
    }
    #pragma unroll
    for (int kt = 0; kt < 4; ++kt) {     // x part (k 0..127)
        bf16x8 w0 = *(const bf16x8*)&nwf[((size_t)(kt * 8 + wv * 2 + 0) * 64 + lane) * 8];
        bf16x8 w1 = *(const bf16x8*)&nwf[((size_t)(kt * 8 + wv * 2 + 1) * 64 + lane) * 8];
        #pragma unroll
        for (int mt = 0; mt < 2; ++mt) {
            bf16x8 a = as_bf(*(const us8*)&xb[(size_t)iN[mt] * HID + kt * 32 + kq8]);
            acc[mt][0] = __builtin_amdgcn_mfma_f32_16x16x32_bf16(a, w0, acc[mt][0], 0, 0, 0);
            acc[mt][1] = __builtin_amdgcn_mfma_f32_16x16x32_bf16(a, w1, acc[mt][1], 0, 0, 0);
        }
    }
    #pragma unroll
    for (int kt = 4; kt < 8; ++kt) {     // agg part (k 128..255), bf16 direct
        bf16x8 w0 = *(const bf16x8*)&nwf[((size_t)(kt * 8 + wv * 2 + 0) * 64 + lane) * 8];
        bf16x8 w1 = *(const bf16x8*)&nwf[((size_t)(kt * 8 + wv * 2 + 1) * 64 + lane) * 8];
        #pragma unroll
        for (int mt = 0; mt < 2; ++mt) {
            bf16x8 a = as_bf(*(const us8*)&agg[(size_t)iN[mt] * HID + (kt - 4) * 32 + kq8]);
            acc[mt][0] = __builtin_amdgcn_mfma_f32_16x16x32_bf16(a, w0, acc[mt][0], 0, 0, 0);
            acc[mt][1] = __builtin_amdgcn_mfma_f32_16x16x32_bf16(a, w1, acc[mt][1], 0, 0, 0);
        }
    }

    if (!last) {
        __syncthreads();   // all xb/agg reads in block complete before overwrite
        const us8 z8 = (us8){0, 0, 0, 0, 0, 0, 0, 0};
        #pragma unroll
        for (int kt = 0; kt < 4; ++kt)
            #pragma unroll
            for (int mt = 0; mt < 2; ++mt)
                *(us8*)&agg[(size_t)iN[mt] * HID + kt * 32 + kq8] = z8;
        #pragma unroll
        for (int mt = 0; mt < 2; ++mt)
            #pragma unroll
            for (int nt2 = 0; nt2 < 2; ++nt2)
                #pragma unroll
                for (int r = 0; r < 4; ++r) {
                    int i = i0 + mt * 16 + rq + r;
                    if (i < n)
                        xb[(size_t)i * HID + wv * 32 + nt2 * 16 + lrow] =
                            f2bf_fast(silu_f(acc[mt][nt2][r]));
                }
        __syncthreads();   // xb stores drained (vmcnt0 at barrier) -> visible
        dual_proj(xb, w1sf_nxt, w1bf_nxt, b1_nxt, Ys, Y, i0, n, t);
    } else {
        // final layer: scatter straight into per-graph sums
        #pragma unroll
        for (int mt = 0; mt < 2; ++mt)
            #pragma unroll
            for (int nt2 = 0; nt2 < 2; ++nt2)
                #pragma unroll
                for (int r = 0; r < 4; ++r) {
                    int i = i0 + mt * 16 + rq + r;
                    if (i < n) {
                        int b = batch[i];
                        unsafeAtomicAdd(&sums[(size_t)b * HID + wv * 32 + nt2 * 16 + lrow],
                                        silu_f(acc[mt][nt2][r]));
                    }
                }
    }
}

// ---------------- readout ---------------------------------------------------
__global__ __launch_bounds__(HID) void readout_kernel(
        const float* __restrict__ sums, const float* __restrict__ counts,
        const float* __restrict__ rw1, const float* __restrict__ rb1,
        const float* __restrict__ rw2, const float* __restrict__ rb2,
        float* __restrict__ pred) {
    __shared__ float gv[HID];
    __shared__ float hv[HID];
    const int g = blockIdx.x;
    const int t = threadIdx.x;
    float c = counts[g];
    if (c < 1.0f) c = 1.0f;
    gv[t] = sums[(size_t)g * HID + t] / c;   // cold path: keep exact division
    __syncthreads();
    float acc = rb1[t];
    for (int k4 = 0; k4 < 32; ++k4) {
        float4 mv = *(const float4*)&gv[k4 * 4];
        #pragma unroll
        for (int j = 0; j < 4; ++j)
            acc += ((const float*)&mv)[j] * rw1[(size_t)(k4 * 4 + j) * HID + t];
    }
    hv[t] = silu_f(acc) * rw2[t];
    __syncthreads();
    for (int s = HID / 2; s > 0; s >>= 1) {
        if (t < s) hv[t] += hv[t + s];
        __syncthreads();
    }
    if (t == 0) pred[g] = hv[0] + rb2[0];
}

extern "C" void kernel_launch(void* const* d_in, const int* in_sizes, int n_in,
                              void* d_out, int out_size, void* d_ws, size_t ws_size,
                              hipStream_t stream) {
    const int*   z          = (const int*)d_in[0];
    const int*   edge_index = (const int*)d_in[1];
    const float* edge_attr  = (const float*)d_in[2];
    const int*   batch      = (const int*)d_in[3];
    const float* emb        = (const float*)d_in[4];
    const float* ew1        = (const float*)d_in[5];
    const float* eb1        = (const float*)d_in[6];
    const float* ew2        = (const float*)d_in[7];
    const float* eb2        = (const float*)d_in[8];
    const float* nw         = (const float*)d_in[9];
    const float* nb         = (const float*)d_in[10];
    const float* rw1        = (const float*)d_in[11];
    const float* rb1        = (const float*)d_in[12];
    const float* rw2        = (const float*)d_in[13];
    const float* rb2        = (const float*)d_in[14];
    float* pred = (float*)d_out;

    const int N = in_sizes[0];
    const int E = in_sizes[1] / 2;
    const int G = out_size;
    const int* srcI = edge_index;
    const int* dstI = edge_index + E;

    char* base = (char*)d_ws;
    size_t off = 0;
    auto carve = [&](size_t bytes) -> char* {
        char* p = base + off;
        off = (off + bytes + 255) & ~(size_t)255;
        return p;
    };
    u16*   agg    = (u16*)carve((size_t)N * HID * sizeof(u16));   // bf16 agg
    float* sums   = (float*)carve((size_t)G * HID * sizeof(float));
    float* cnts_g = (float*)carve((size_t)G * sizeof(float));
    u16*   xb     = (u16*)carve((size_t)N * HID * sizeof(u16));
    u16*   Y      = (u16*)carve((size_t)N * HID * sizeof(u16));   // dst-proj (bf16, b1 folded)
    u16*   Ys     = (u16*)carve((size_t)N * HID * sizeof(u16));   // src-proj (bf16)
    int4*  es     = (int4*)carve((size_t)(E + 64) * sizeof(int4)); // AoS edge recs
    int*   rowptr = (int*)carve((size_t)(N + 1) * sizeof(int));
    int*   cursor = (int*)carve((size_t)N * sizeof(int));
    int*   cnt    = (int*)carve((size_t)N * sizeof(int));
    u16*   w1sf   = (u16*)carve((size_t)4 * 32 * 512 * sizeof(u16)); // KT=4 src
    u16*   w1tf   = (u16*)carve((size_t)4 * 8 * 512 * sizeof(u16));  // KT=1 attr
    u16*   w1bf   = (u16*)carve((size_t)4 * 32 * 512 * sizeof(u16)); // KT=4 dst
    u16*   w2f    = (u16*)carve((size_t)4 * 32 * 512 * sizeof(u16)); // KT=4
    u16*   nwf    = (u16*)carve((size_t)4 * 64 * 512 * sizeof(u16)); // KT=8

    // ---- fused setup: weight swizzle + zero cnt/cursor/sums/counts ----
    {
        long long total = (long long)T1S + T1T + T1B + T2 + T3
                        + 2LL * N + (long long)G * HID + G;
        int blocks = (int)((total + 255) / 256);
        setup_kernel<<<blocks, 256, 0, stream>>>(ew1, ew2, nw, w1sf, w1tf, w1bf,
                                                 w2f, nwf, cnt, cursor,
                                                 sums, cnts_g, N, G);
    }

    // ---- CSR build (dst-sorted edges) ----
    hist_kernel<<<(E + 255) / 256, 256, 0, stream>>>(dstI, cnt, E);
    scan_kernel<<<1, 1024, 0, stream>>>(cnt, rowptr, N);

    // ---- merged scatter + embed + layer-0 projections (independent halves) ----
    {
        const int SB = (E + 255) / 256;
        const int EB = (N + 31) / 32;
        scatter_embed_kernel<<<SB + EB, 256, 0, stream>>>(
            srcI, dstI, edge_attr, rowptr, cursor, es,
            z, emb, xb, agg, batch, cnts_g, w1sf, w1bf, eb1, Ys, Y, E, N, SB);
    }

    for (int l = 0; l < 4; ++l) {
        edge_mfma<<<(E + 63) / 64, 512, 0, stream>>>(
            es,
            w1tf + (size_t)l * 8 * 512,
            w2f + (size_t)l * 32 * 512, eb2 + (size_t)l * HID,
            Ys, Y, agg, E);
        int lnxt = (l + 1) & 3;   // l==3: tail skipped (last=1), args unused
        node_mfma<<<(N + 31) / 32, 256, 0, stream>>>(
            xb, agg, nwf + (size_t)l * 64 * 512, nb + (size_t)l * HID,
            batch, sums,
            w1sf + (size_t)lnxt * 32 * 512, w1bf + (size_t)lnxt * 32 * 512,
            eb1 + (size_t)lnxt * HID,
            Ys, Y, (l == 3) ? 1 : 0, N);
    }

    readout_kernel<<<G, HID, 0, stream>>>(sums, cnts_g, rw1, rb1, rw2, rb2, pred);
}

// Round 17
// 984.258 us; speedup vs baseline: 4.4256x; 1.0092x over previous
//
#include <hip/hip_runtime.h>
#include <hip/hip_bf16.h>
#include <math.h>

#define HID  128
#define EDIM 4

typedef unsigned short u16;
typedef u16    us8   __attribute__((ext_vector_type(8)));
typedef __bf16 bf16x8 __attribute__((ext_vector_type(8)));
typedef float  f32x4 __attribute__((ext_vector_type(4)));

// silu via hw rcp: v_rcp_f32 (~1 ulp) instead of IEEE div (10+ inst w/o fast-math)
__device__ __forceinline__ float silu_f(float v) {
    return v * __builtin_amdgcn_rcpf(1.0f + __expf(-v));
}
__device__ __forceinline__ u16 f2bf(float f) {   // RNE fp32->bf16 (cold paths)
    unsigned u = __float_as_uint(f);
    unsigned r = u + 0x7fffu + ((u >> 16) & 1u);
    return (u16)(r >> 16);
}
__device__ __forceinline__ u16 f2bf_fast(float f) {  // round-half-up, 2 ops (hot)
    return (u16)((__float_as_uint(f) + 0x8000u) >> 16);
}
// pack two fp32 -> one u32 of 2 bf16 (round-half-up)
__device__ __forceinline__ unsigned pack_bf2(float a, float b) {
    return ((__float_as_uint(a) + 0x8000u) >> 16) |
           ((__float_as_uint(b) + 0x8000u) & 0xffff0000u);
}
__device__ __forceinline__ float bf2f(u16 s) {
    return __uint_as_float(((unsigned)s) << 16);
}
__device__ __forceinline__ bf16x8 as_bf(us8 v) {
    return __builtin_bit_cast(bf16x8, v);
}
__device__ __forceinline__ f32x4 bf4f(ushort4 v) {
    f32x4 r;
    r[0] = bf2f(v.x); r[1] = bf2f(v.y); r[2] = bf2f(v.z); r[3] = bf2f(v.w);
    return r;
}

// ---------------- fused setup: weight swizzle + histogram -------------------
// Generalized fragment swizzler: logical k -> source row = k + (k>=split ?
// jump : 0); valid iff row < Kdata. Layer stride Kstride rows.
__device__ __forceinline__ void wfrag_gen(const float* __restrict__ w,
        u16* __restrict__ out, int KT, int Kdata, int Kstride,
        int split, int jump, int idx) {
    int lane = idx & 63;
    int f    = (idx >> 6) % (KT * 8);
    int l    = idx / (64 * KT * 8);
    int kt = f >> 3, nt = f & 7;
    int n  = nt * 16 + (lane & 15);
    int k0 = kt * 32 + ((lane >> 4) * 8);
    us8 v;
    #pragma unroll
    for (int j = 0; j < 8; ++j) {
        int k = k0 + j;
        int row = k + (k >= split ? jump : 0);
        v[j] = (row < Kdata) ? f2bf(w[((size_t)l * Kstride + row) * HID + n]) : (u16)0;
    }
    *(us8*)&out[((size_t)(l * KT * 8 + f) * 64 + lane) * 8] = v;
}

// R22 split of W1 [260x128]: w1s (src rows 0..127, KT=4), w1b (dst rows
// 128..255, KT=4), w1t (attr rows 256..259 zero-padded to K=32, KT=1).
#define T1S (4 * 4 * 8 * 64)
#define T1T (4 * 1 * 8 * 64)
#define T1B (4 * 4 * 8 * 64)
#define T2  (4 * 4 * 8 * 64)
#define T3  (4 * 8 * 8 * 64)

// R31: cnt/cursor/sums/cnts_g zeroed by hipMemsetAsync before this dispatch
// -> the hist pass (needs cnt==0) merges in as trailing blocks; one launch
// boundary removed.
__global__ __launch_bounds__(256) void setup_kernel(
        const float* __restrict__ ew1, const float* __restrict__ ew2,
        const float* __restrict__ nw,
        u16* __restrict__ w1sf, u16* __restrict__ w1tf,
        u16* __restrict__ w1bf,
        u16* __restrict__ w2f, u16* __restrict__ nwf,
        const int* __restrict__ dstI, int* __restrict__ cnt, int E) {
    const int BIG = 1 << 30;
    int idx = blockIdx.x * 256 + threadIdx.x;
    if (idx < T1S) { wfrag_gen(ew1, w1sf, 4, 128, 260, BIG, 0, idx); return; }
    idx -= T1S;
    if (idx < T1T) { wfrag_gen(ew1, w1tf, 1, 260, 260, 0, 256, idx); return; }
    idx -= T1T;
    if (idx < T1B) { wfrag_gen(ew1, w1bf, 4, 260, 260, 0, 128, idx); return; }
    idx -= T1B;
    if (idx < T2) { wfrag_gen(ew2, w2f, 4, 128, 128, BIG, 0, idx); return; }
    idx -= T2;
    if (idx < T3) { wfrag_gen(nw, nwf, 8, 256, 256, BIG, 0, idx); return; }
    idx -= T3;
    if (idx < E) atomicAdd(&cnt[dstI[idx]], 1);
}

// ---------------- CSR scan ---------------------------------------------------
__global__ __launch_bounds__(1024) void scan_kernel(const int* __restrict__ cnt,
        int* __restrict__ rowptr, int n) {
    __shared__ int s[1024];
    const int t = threadIdx.x;
    const int chunk = (n + 1023) >> 10;
    int lo = t * chunk, hi = lo + chunk;
    if (lo > n) lo = n;
    if (hi > n) hi = n;
    int sum = 0;
    for (int i = lo; i < hi; ++i) sum += cnt[i];
    s[t] = sum;
    __syncthreads();
    for (int off = 1; off < 1024; off <<= 1) {
        int v = (t >= off) ? s[t - off] : 0;
        __syncthreads();
        s[t] += v;
        __syncthreads();
    }
    int run = s[t] - sum;
    for (int i = lo; i < hi; ++i) { rowptr[i] = run; run += cnt[i]; }
    if (t == 1023) rowptr[n] = run;
}

// ---------------- shared dual-projection tail -------------------------------
// Ys = x@W1s, Y = b1 + x@W1b from the block's own 32 xb rows; OUTPUT bf16
// (halves edge gather traffic; b1 folded -> edge acc-init is cvt+cvt+add).
// Caller must __syncthreads() after writing those xb rows. 256-thread
// geometry (t in [0,256)).
__device__ __forceinline__ void dual_proj(
        const u16* __restrict__ xb,
        const u16* __restrict__ w1sf, const u16* __restrict__ w1bf,
        const float* __restrict__ b1n,
        u16* __restrict__ Ys, u16* __restrict__ Y,
        int i0, int n, int t) {
    const int wv   = t >> 6, lane = t & 63;
    const int lrow = lane & 15;
    const int kq   = lane >> 4;
    const int kq8  = kq * 8;

    int iN[2];
    #pragma unroll
    for (int mt = 0; mt < 2; ++mt) {
        int i = i0 + mt * 16 + lrow; if (i >= n) i = n - 1;
        iN[mt] = i;
    }
    f32x4 aS[2][2], aB[2][2];
    #pragma unroll
    for (int mt = 0; mt < 2; ++mt)
        #pragma unroll
        for (int nt = 0; nt < 2; ++nt) {
            aS[mt][nt] = (f32x4){0.f, 0.f, 0.f, 0.f};
            aB[mt][nt] = *(const f32x4*)&b1n[(wv * 2 + nt) * 16 + kq * 4];
        }

    #pragma unroll
    for (int kt = 0; kt < 4; ++kt) {
        bf16x8 ws0 = *(const bf16x8*)&w1sf[((size_t)(kt * 8 + wv * 2 + 0) * 64 + lane) * 8];
        bf16x8 ws1 = *(const bf16x8*)&w1sf[((size_t)(kt * 8 + wv * 2 + 1) * 64 + lane) * 8];
        bf16x8 wb0 = *(const bf16x8*)&w1bf[((size_t)(kt * 8 + wv * 2 + 0) * 64 + lane) * 8];
        bf16x8 wb1 = *(const bf16x8*)&w1bf[((size_t)(kt * 8 + wv * 2 + 1) * 64 + lane) * 8];
        #pragma unroll
        for (int mt = 0; mt < 2; ++mt) {
            bf16x8 a = as_bf(*(const us8*)&xb[(size_t)iN[mt] * HID + kt * 32 + kq8]);
            aS[mt][0] = __builtin_amdgcn_mfma_f32_16x16x32_bf16(ws0, a, aS[mt][0], 0, 0, 0);
            aS[mt][1] = __builtin_amdgcn_mfma_f32_16x16x32_bf16(ws1, a, aS[mt][1], 0, 0, 0);
            aB[mt][0] = __builtin_amdgcn_mfma_f32_16x16x32_bf16(wb0, a, aB[mt][0], 0, 0, 0);
            aB[mt][1] = __builtin_amdgcn_mfma_f32_16x16x32_bf16(wb1, a, aB[mt][1], 0, 0, 0);
        }
    }
    #pragma unroll
    for (int mt = 0; mt < 2; ++mt) {
        int node = i0 + mt * 16 + lrow;
        if (node < n) {
            #pragma unroll
            for (int nt = 0; nt < 2; ++nt) {
                uint2 sv, bv;
                sv.x = pack_bf2(aS[mt][nt][0], aS[mt][nt][1]);
                sv.y = pack_bf2(aS[mt][nt][2], aS[mt][nt][3]);
                bv.x = pack_bf2(aB[mt][nt][0], aB[mt][nt][1]);
                bv.y = pack_bf2(aB[mt][nt][2], aB[mt][nt][3]);
                *(uint2*)&Ys[(size_t)node * HID + (wv * 2 + nt) * 16 + kq * 4] = sv;
                *(uint2*)&Y [(size_t)node * HID + (wv * 2 + nt) * 16 + kq * 4] = bv;
            }
        }
    }
}

// ---------------- merged scatter + embed + layer-0 projections ---------------
// R28 merge + R29 AoS edge records (one dwordx4 write per edge) + R30 bf16 agg.
__global__ __launch_bounds__(256) void scatter_embed_kernel(
        const int* __restrict__ src, const int* __restrict__ dst,
        const float* __restrict__ ea, const int* __restrict__ rowptr,
        int* __restrict__ cursor, int4* __restrict__ es,
        const int* __restrict__ z, const float* __restrict__ emb,
        u16* __restrict__ xb, u16* __restrict__ agg,
        const int* __restrict__ batch, float* __restrict__ counts,
        const u16* __restrict__ w1sf, const u16* __restrict__ w1bf,
        const float* __restrict__ b1n,
        u16* __restrict__ Ys, u16* __restrict__ Y,
        int E, int n, int SB) {
    const int t = threadIdx.x;
    if ((int)blockIdx.x < SB) {
        // -------- scatter half (blocks [0, SB)) --------
        int e = blockIdx.x * 256 + t;
        if (e >= E) return;
        int d = dst[e];
        int p = rowptr[d] + atomicAdd(&cursor[d], 1);
        const float* q = &ea[(size_t)e * EDIM];
        int4 rec;
        rec.x = src[e];
        rec.y = d;
        rec.z = (int)((unsigned)f2bf(q[0]) | ((unsigned)f2bf(q[1]) << 16));
        rec.w = (int)((unsigned)f2bf(q[2]) | ((unsigned)f2bf(q[3]) << 16));
        es[p] = rec;
    } else {
        // -------- embed half (blocks [SB, SB+EB)) --------
        const int i0 = (blockIdx.x - SB) * 32;
        #pragma unroll
        for (int j = 0; j < 16; ++j) {
            int idx = j * 256 + t;             // 4096 slots = 32 nodes x 128
            int node = i0 + (idx >> 7), col = idx & 127;
            if (node < n) {
                xb[(size_t)node * HID + col] = f2bf(emb[(size_t)z[node] * HID + col]);
                agg[(size_t)node * HID + col] = 0;     // bf16 zero
            }
        }
        if (t < 32 && i0 + t < n)
            unsafeAtomicAdd(&counts[batch[i0 + t]], 1.0f);
        __syncthreads();   // xb stores drained -> visible block-wide
        dual_proj(xb, w1sf, w1bf, b1n, Ys, Y, i0, n, t);
    }
}

// ---------------- edge MLP: 64 dst-sorted edges/block, 8 waves --------------
// R12 core + R15 wave-local scan + R16 (8 waves, swapped MFMA operands) +
// R17 (dst-dedup) + R22 (src-hoist: GEMM1 attr-only K=32) + R26 (bf16 Ys/Y,
// b1 folded into Y) + R29 (AoS es) + R30 (bf16 agg, pk atomics) + R31:
// acc-init's Ys/Y gathers issue BEFORE the staging barrier via direct
// per-lane es loads (16 consecutive records per 16-lane group, L2-hot) —
// breaks the stage->barrier->gather serial chain.
// FAILED variants (do not reintroduce): R9 XOR-swizzle, R13 2x2 wave tiling,
// R16 occupancy 2x, R18 VGPR-persistent weights (spill), R19 node-centric
// fusion (L2 thrash), R5 LDS-transpose node tail, R6 H-split, R9 cooperative
// launch (dropped under graph capture), R10 persistent manual-barrier kernel
// (fence invalidate storm), R12 dataflow-fused edge+node (uncached agg
// coherence reads; 1135 us).
__global__ __launch_bounds__(512, 8) void edge_mfma(
        const int4* __restrict__ es,
        const u16* __restrict__ w1tf,
        const u16* __restrict__ w2f, const float* __restrict__ b2,
        const u16* __restrict__ Ys, const u16* __restrict__ Y,
        u16* __restrict__ agg, int nE) {
    // A: u16 [64][40] = 5120 B (attr only; dead after GEMM1)
    // H: u16 [64][136] = 17408 B (aliases A; dead after GEMM2)
    // M: f32 [64][132] = 33792 B (aliases A/H; sized to M)
    __shared__ __align__(16) char smem[64 * 132 * 4];
    __shared__ __align__(16) int dsh[64];
    u16*   A = (u16*)smem;
    u16*   H = (u16*)smem;
    float* M = (float*)smem;

    const int t    = threadIdx.x;
    const int e0   = blockIdx.x * 64;
    const int wv   = t >> 6, lane = t & 63;
    const int lrow = lane & 15;
    const int kq   = lane >> 4;
    const int kq8  = kq * 8;
    const int rq   = kq * 4;
    const int h    = wv >> 2;     // edge-half this wave owns (0/1)
    const int p    = wv & 3;      // col-pair this wave owns (0..3)

    // ---- stage: dsh + attr rows from ONE int4/edge (rows padded to 40) ----
    if (t < 64) {
        int e = e0 + t;
        bool valid = e < nE; if (!valid) e = nE - 1;
        int4 rec = es[e];
        dsh[t] = valid ? rec.y : -1;
        int base = t * 40;
        us8 z8 = (us8){0, 0, 0, 0, 0, 0, 0, 0};
        *(us8*)&A[base + 8]  = z8;         // K-pad cols 8..31 zero
        *(us8*)&A[base + 16] = z8;
        *(us8*)&A[base + 24] = z8;
        A[base + 0] = (u16)((unsigned)rec.z & 0xffffu);
        A[base + 1] = (u16)((unsigned)rec.z >> 16);
        A[base + 2] = (u16)((unsigned)rec.w & 0xffffu);
        A[base + 3] = (u16)((unsigned)rec.w >> 16);
        A[base + 4] = 0;   A[base + 5] = 0;   A[base + 6] = 0;   A[base + 7] = 0;
    }

    // ---- acc-init gathers issued BEFORE the barrier (direct es reads;
    //      no LDS dependency). Values identical: invalid rows clamp to
    //      edge nE-1 -> unused garbage, scan skips them via dsh==-1.
    f32x4 acc[2][2];
    {
        int eA = e0 + (h * 2 + 0) * 16 + lrow; if (eA >= nE) eA = nE - 1;
        int eB = e0 + (h * 2 + 1) * 16 + lrow; if (eB >= nE) eB = nE - 1;
        int4 recA = es[eA];
        int4 recB = es[eB];
        int dA = recA.y, sA = recA.x;
        int dB = recB.y, sB = recB.x;
        #pragma unroll
        for (int nt = 0; nt < 2; ++nt) {
            int c = (p * 2 + nt) * 16 + rq;
            ushort4 yA = *(const ushort4*)&Y [(size_t)dA * HID + c];
            ushort4 sA4 = *(const ushort4*)&Ys[(size_t)sA * HID + c];
            ushort4 yB = *(const ushort4*)&Y [(size_t)dB * HID + c];
            ushort4 sB4 = *(const ushort4*)&Ys[(size_t)sB * HID + c];
            acc[0][nt] = bf4f(yA) + bf4f(sA4);
            acc[1][nt] = bf4f(yB) + bf4f(sB4);
        }
    }
    __syncthreads();

    // ---- GEMM1: attr-only K=32 on top of the pre-gathered acc ----
    {
        bf16x8 w0 = *(const bf16x8*)&w1tf[((size_t)(p * 2 + 0) * 64 + lane) * 8];
        bf16x8 w1 = *(const bf16x8*)&w1tf[((size_t)(p * 2 + 1) * 64 + lane) * 8];
        #pragma unroll
        for (int mt = 0; mt < 2; ++mt) {
            bf16x8 a = *(const bf16x8*)&A[((h * 2 + mt) * 16 + lrow) * 40 + kq8];
            acc[mt][0] = __builtin_amdgcn_mfma_f32_16x16x32_bf16(w0, a, acc[mt][0], 0, 0, 0);
            acc[mt][1] = __builtin_amdgcn_mfma_f32_16x16x32_bf16(w1, a, acc[mt][1], 0, 0, 0);
        }
    }
    __syncthreads();   // all A reads done; region reused as H

    // silu -> H: 4 consecutive n per lane -> one packed b64 per (mt,nt)
    #pragma unroll
    for (int mt = 0; mt < 2; ++mt)
        #pragma unroll
        for (int nt = 0; nt < 2; ++nt) {
            uint2 hv;
            hv.x = pack_bf2(silu_f(acc[mt][nt][0]), silu_f(acc[mt][nt][1]));
            hv.y = pack_bf2(silu_f(acc[mt][nt][2]), silu_f(acc[mt][nt][3]));
            int edge = (h * 2 + mt) * 16 + lrow;
            *(uint2*)&H[edge * 136 + (p * 2 + nt) * 16 + rq] = hv;
        }
    __syncthreads();

    // ---- GEMM2: [64 x 128] @ [128 x 128], swapped operands ----
    f32x4 acc2[2][2];
    #pragma unroll
    for (int nt = 0; nt < 2; ++nt) {
        f32x4 bv = *(const f32x4*)&b2[(p * 2 + nt) * 16 + rq];
        acc2[0][nt] = bv; acc2[1][nt] = bv;
    }
    #pragma unroll
    for (int kt = 0; kt < 4; ++kt) {
        bf16x8 w0 = *(const bf16x8*)&w2f[((size_t)(kt * 8 + p * 2 + 0) * 64 + lane) * 8];
        bf16x8 w1 = *(const bf16x8*)&w2f[((size_t)(kt * 8 + p * 2 + 1) * 64 + lane) * 8];
        #pragma unroll
        for (int mt = 0; mt < 2; ++mt) {
            bf16x8 a = *(const bf16x8*)&H[((h * 2 + mt) * 16 + lrow) * 136 + kt * 32 + kq8];
            acc2[mt][0] = __builtin_amdgcn_mfma_f32_16x16x32_bf16(w0, a, acc2[mt][0], 0, 0, 0);
            acc2[mt][1] = __builtin_amdgcn_mfma_f32_16x16x32_bf16(w1, a, acc2[mt][1], 0, 0, 0);
        }
    }
    __syncthreads();   // all H reads complete before M overwrites (aliased WAR)

    // silu -> M: fp32 messages, one float4 store per (mt,nt)
    #pragma unroll
    for (int mt = 0; mt < 2; ++mt)
        #pragma unroll
        for (int nt = 0; nt < 2; ++nt) {
            f32x4 mv;
            #pragma unroll
            for (int r = 0; r < 4; ++r) mv[r] = silu_f(acc2[mt][nt][r]);
            int edge = (h * 2 + mt) * 16 + lrow;
            *(f32x4*)&M[edge * 132 + (p * 2 + nt) * 16 + rq] = mv;
        }

    // ---- wave-local segmented reduction -> packed-bf16 atomics.
    // Wave (h,p) scans exactly the 32x32 M region it wrote (no barrier;
    // intra-wave DS program order). Run flushes are uniform within each
    // 32-lane half (row-based boundaries): even lane takes its odd
    // neighbor's run via shfl_xor and issues ONE pk_add_bf16 per col pair.
    {
        int col = p * 32 + (lane & 31);
        int r0  = h * 32 + (lane >> 5) * 16;   // rows r0..r0+15
        int4 da = *(const int4*)&dsh[r0];
        int4 db = *(const int4*)&dsh[r0 + 4];
        int4 dc = *(const int4*)&dsh[r0 + 8];
        int4 dd = *(const int4*)&dsh[r0 + 12];
        int ds_[16] = {da.x, da.y, da.z, da.w, db.x, db.y, db.z, db.w,
                       dc.x, dc.y, dc.z, dc.w, dd.x, dd.y, dd.z, dd.w};
        float run = 0.f;
        int   cur = ds_[0];
        #pragma unroll
        for (int i = 0; i < 16; ++i) {
            run += M[(r0 + i) * 132 + col];
            int nxt = (i == 15) ? -2 : ds_[i + 1];
            if (cur != nxt) {             // uniform within 32-lane half
                float nbr = __shfl_xor(run, 1);
                if (cur >= 0 && !(col & 1)) {
                    __hip_bfloat162 v;
                    v.x = __float2bfloat16(run);
                    v.y = __float2bfloat16(nbr);
                    unsafeAtomicAdd(
                        (__hip_bfloat162*)&agg[(size_t)cur * HID + col], v);
                }
                run = 0.f; cur = nxt;
            }
        }
    }
}

// ---------------- node MLP: 32 nodes/block + fused next-layer projections ---
// R2-exact core; R30: bf16 agg -> one us8 load feeds MFMA directly.
__global__ __launch_bounds__(256) void node_mfma(
        u16* __restrict__ xb, u16* __restrict__ agg,
        const u16* __restrict__ nwf, const float* __restrict__ nb,
        const int* __restrict__ batch, float* __restrict__ sums,
        const u16* __restrict__ w1sf_nxt, const u16* __restrict__ w1bf_nxt,
        const float* __restrict__ b1_nxt,
        u16* __restrict__ Ys, u16* __restrict__ Y,
        int last, int n) {
    const int t    = threadIdx.x;
    const int i0   = blockIdx.x * 32;
    const int wv   = t >> 6, lane = t & 63;
    const int lrow = lane & 15;
    const int kq   = lane >> 4;
    const int kq8  = kq * 8;
    const int rq   = kq * 4;

    int iN[2];
    #pragma unroll
    for (int mt = 0; mt < 2; ++mt) {
        int i = i0 + mt * 16 + lrow; if (i >= n) i = n - 1;
        iN[mt] = i;
    }

    f32x4 acc[2][2];
    {
        float bias0 = nb[wv * 32 + lrow], bias1 = nb[wv * 32 + 16 + lrow];
        #pragma unroll
        for (int mt = 0; mt < 2; ++mt)
            #pragma unroll
            for (int r = 0; r < 4; ++r) {
                acc[mt][0][r] = bias0; acc[mt][1][r] = bias1;
            }
    }
    #pragma unroll
    for (int kt = 0; kt < 4; ++kt) {     // x part (k 0..127)
        bf16x8 w0 = *(const bf16x8*)&nwf[((size_t)(kt * 8 + wv * 2 + 0) * 64 + lane) * 8];
        bf16x8 w1 = *(const bf16x8*)&nwf[((size_t)(kt * 8 + wv * 2 + 1) * 64 + lane) * 8];
        #pragma unroll
        for (int mt = 0; mt < 2; ++mt) {
            bf16x8 a = as_bf(*(const us8*)&xb[(size_t)iN[mt] * HID + kt * 32 + kq8]);
            acc[mt][0] = __builtin_amdgcn_mfma_f32_16x16x32_bf16(a, w0, acc[mt][0], 0, 0, 0);
            acc[mt][1] = __builtin_amdgcn_mfma_f32_16x16x32_bf16(a, w1, acc[mt][1], 0, 0, 0);
        }
    }
    #pragma unroll
    for (int kt = 4; kt < 8; ++kt) {     // agg part (k 128..255), bf16 direct
        bf16x8 w0 = *(const bf16x8*)&nwf[((size_t)(kt * 8 + wv * 2 + 0) * 64 + lane) * 8];
        bf16x8 w1 = *(const bf16x8*)&nwf[((size_t)(kt * 8 + wv * 2 + 1) * 64 + lane) * 8];
        #pragma unroll
        for (int mt = 0; mt < 2; ++mt) {
            bf16x8 a = as_bf(*(const us8*)&agg[(size_t)iN[mt] * HID + (kt - 4) * 32 + kq8]);
            acc[mt][0] = __builtin_amdgcn_mfma_f32_16x16x32_bf16(a, w0, acc[mt][0], 0, 0, 0);
            acc[mt][1] = __builtin_amdgcn_mfma_f32_16x16x32_bf16(a, w1, acc[mt][1], 0, 0, 0);
        }
    }

    if (!last) {
        __syncthreads();   // all xb/agg reads in block complete before overwrite
        const us8 z8 = (us8){0, 0, 0, 0, 0, 0, 0, 0};
        #pragma unroll
        for (int kt = 0; kt < 4; ++kt)
            #pragma unroll
            for (int mt = 0; mt < 2; ++mt)
                *(us8*)&agg[(size_t)iN[mt] * HID + kt * 32 + kq8] = z8;
        #pragma unroll
        for (int mt = 0; mt < 2; ++mt)
            #pragma unroll
            for (int nt2 = 0; nt2 < 2; ++nt2)
                #pragma unroll
                for (int r = 0; r < 4; ++r) {
                    int i = i0 + mt * 16 + rq + r;
                    if (i < n)
                        xb[(size_t)i * HID + wv * 32 + nt2 * 16 + lrow] =
                            f2bf_fast(silu_f(acc[mt][nt2][r]));
                }
        __syncthreads();   // xb stores drained (vmcnt0 at barrier) -> visible
        dual_proj(xb, w1sf_nxt, w1bf_nxt, b1_nxt, Ys, Y, i0, n, t);
    } else {
        // final layer: scatter straight into per-graph sums
        #pragma unroll
        for (int mt = 0; mt < 2; ++mt)
            #pragma unroll
            for (int nt2 = 0; nt2 < 2; ++nt2)
                #pragma unroll
                for (int r = 0; r < 4; ++r) {
                    int i = i0 + mt * 16 + rq + r;
                    if (i < n) {
                        int b = batch[i];
                        unsafeAtomicAdd(&sums[(size_t)b * HID + wv * 32 + nt2 * 16 + lrow],
                                        silu_f(acc[mt][nt2][r]));
                    }
                }
    }
}

// ---------------- readout ---------------------------------------------------
__global__ __launch_bounds__(HID) void readout_kernel(
        const float* __restrict__ sums, const float* __restrict__ counts,
        const float* __restrict__ rw1, const float* __restrict__ rb1,
        const float* __restrict__ rw2, const float* __restrict__ rb2,
        float* __restrict__ pred) {
    __shared__ float gv[HID];
    __shared__ float hv[HID];
    const int g = blockIdx.x;
    const int t = threadIdx.x;
    float c = counts[g];
    if (c < 1.0f) c = 1.0f;
    gv[t] = sums[(size_t)g * HID + t] / c;   // cold path: keep exact division
    __syncthreads();
    float acc = rb1[t];
    for (int k4 = 0; k4 < 32; ++k4) {
        float4 mv = *(const float4*)&gv[k4 * 4];
        #pragma unroll
        for (int j = 0; j < 4; ++j)
            acc += ((const float*)&mv)[j] * rw1[(size_t)(k4 * 4 + j) * HID + t];
    }
    hv[t] = silu_f(acc) * rw2[t];
    __syncthreads();
    for (int s = HID / 2; s > 0; s >>= 1) {
        if (t < s) hv[t] += hv[t + s];
        __syncthreads();
    }
    if (t == 0) pred[g] = hv[0] + rb2[0];
}

extern "C" void kernel_launch(void* const* d_in, const int* in_sizes, int n_in,
                              void* d_out, int out_size, void* d_ws, size_t ws_size,
                              hipStream_t stream) {
    const int*   z          = (const int*)d_in[0];
    const int*   edge_index = (const int*)d_in[1];
    const float* edge_attr  = (const float*)d_in[2];
    const int*   batch      = (const int*)d_in[3];
    const float* emb        = (const float*)d_in[4];
    const float* ew1        = (const float*)d_in[5];
    const float* eb1        = (const float*)d_in[6];
    const float* ew2        = (const float*)d_in[7];
    const float* eb2        = (const float*)d_in[8];
    const float* nw         = (const float*)d_in[9];
    const float* nb         = (const float*)d_in[10];
    const float* rw1        = (const float*)d_in[11];
    const float* rb1        = (const float*)d_in[12];
    const float* rw2        = (const float*)d_in[13];
    const float* rb2        = (const float*)d_in[14];
    float* pred = (float*)d_out;

    const int N = in_sizes[0];
    const int E = in_sizes[1] / 2;
    const int G = out_size;
    const int* srcI = edge_index;
    const int* dstI = edge_index + E;

    char* base = (char*)d_ws;
    size_t off = 0;
    auto carve = [&](size_t bytes) -> char* {
        char* p = base + off;
        off = (off + bytes + 255) & ~(size_t)255;
        return p;
    };
    u16*   agg    = (u16*)carve((size_t)N * HID * sizeof(u16));   // bf16 agg
    float* sums   = (float*)carve((size_t)G * HID * sizeof(float));
    float* cnts_g = (float*)carve((size_t)G * sizeof(float));     // adjacent to sums
    u16*   xb     = (u16*)carve((size_t)N * HID * sizeof(u16));
    u16*   Y      = (u16*)carve((size_t)N * HID * sizeof(u16));   // dst-proj (bf16, b1 folded)
    u16*   Ys     = (u16*)carve((size_t)N * HID * sizeof(u16));   // src-proj (bf16)
    int4*  es     = (int4*)carve((size_t)(E + 64) * sizeof(int4)); // AoS edge recs
    int*   rowptr = (int*)carve((size_t)(N + 1) * sizeof(int));
    int*   cursor = (int*)carve((size_t)N * sizeof(int));
    int*   cnt    = (int*)carve((size_t)N * sizeof(int));          // adjacent to cursor
    u16*   w1sf   = (u16*)carve((size_t)4 * 32 * 512 * sizeof(u16)); // KT=4 src
    u16*   w1tf   = (u16*)carve((size_t)4 * 8 * 512 * sizeof(u16));  // KT=1 attr
    u16*   w1bf   = (u16*)carve((size_t)4 * 32 * 512 * sizeof(u16)); // KT=4 dst
    u16*   w2f    = (u16*)carve((size_t)4 * 32 * 512 * sizeof(u16)); // KT=4
    u16*   nwf    = (u16*)carve((size_t)4 * 64 * 512 * sizeof(u16)); // KT=8

    // ---- R31: async pre-zeroing (stream-ordered, graph-capture-safe) ----
    // cursor..cnt span and sums..cnts_g span are contiguous carves.
    hipMemsetAsync(cursor, 0, (size_t)((char*)(cnt + N) - (char*)cursor), stream);
    hipMemsetAsync(sums, 0, (size_t)((char*)(cnts_g + G) - (char*)sums), stream);

    // ---- fused setup: weight swizzle + histogram (cnt pre-zeroed) ----
    {
        long long total = (long long)T1S + T1T + T1B + T2 + T3 + E;
        int blocks = (int)((total + 255) / 256);
        setup_kernel<<<blocks, 256, 0, stream>>>(ew1, ew2, nw, w1sf, w1tf, w1bf,
                                                 w2f, nwf, dstI, cnt, E);
    }

    // ---- CSR scan ----
    scan_kernel<<<1, 1024, 0, stream>>>(cnt, rowptr, N);

    // ---- merged scatter + embed + layer-0 projections (independent halves) ----
    {
        const int SB = (E + 255) / 256;
        const int EB = (N + 31) / 32;
        scatter_embed_kernel<<<SB + EB, 256, 0, stream>>>(
            srcI, dstI, edge_attr, rowptr, cursor, es,
            z, emb, xb, agg, batch, cnts_g, w1sf, w1bf, eb1, Ys, Y, E, N, SB);
    }

    for (int l = 0; l < 4; ++l) {
        edge_mfma<<<(E + 63) / 64, 512, 0, stream>>>(
            es,
            w1tf + (size_t)l * 8 * 512,
            w2f + (size_t)l * 32 * 512, eb2 + (size_t)l * HID,
            Ys, Y, agg, E);
        int lnxt = (l + 1) & 3;   // l==3: tail skipped (last=1), args unused
        node_mfma<<<(N + 31) / 32, 256, 0, stream>>>(
            xb, agg, nwf + (size_t)l * 64 * 512, nb + (size_t)l * HID,
            batch, sums,
            w1sf + (size_t)lnxt * 32 * 512, w1bf + (size_t)lnxt * 32 * 512,
            eb1 + (size_t)lnxt * HID,
            Ys, Y, (l == 3) ? 1 : 0, N);
    }

    readout_kernel<<<G, HID, 0, stream>>>(sums, cnts_g, rw1, rb1, rw2, rb2, pred);
}

// Round 18
// 974.257 us; speedup vs baseline: 4.4711x; 1.0103x over previous
//
#include <hip/hip_runtime.h>
#include <hip/hip_bf16.h>
#include <math.h>

#define HID  128
#define EDIM 4

typedef unsigned short u16;
typedef u16    us8   __attribute__((ext_vector_type(8)));
typedef __bf16 bf16x8 __attribute__((ext_vector_type(8)));
typedef float  f32x4 __attribute__((ext_vector_type(4)));

// silu via hw rcp: v_rcp_f32 (~1 ulp) instead of IEEE div (10+ inst w/o fast-math)
__device__ __forceinline__ float silu_f(float v) {
    return v * __builtin_amdgcn_rcpf(1.0f + __expf(-v));
}
__device__ __forceinline__ u16 f2bf(float f) {   // RNE fp32->bf16 (cold paths)
    unsigned u = __float_as_uint(f);
    unsigned r = u + 0x7fffu + ((u >> 16) & 1u);
    return (u16)(r >> 16);
}
__device__ __forceinline__ u16 f2bf_fast(float f) {  // round-half-up, 2 ops (hot)
    return (u16)((__float_as_uint(f) + 0x8000u) >> 16);
}
// pack two fp32 -> one u32 of 2 bf16 (round-half-up)
__device__ __forceinline__ unsigned pack_bf2(float a, float b) {
    return ((__float_as_uint(a) + 0x8000u) >> 16) |
           ((__float_as_uint(b) + 0x8000u) & 0xffff0000u);
}
__device__ __forceinline__ float bf2f(u16 s) {
    return __uint_as_float(((unsigned)s) << 16);
}
__device__ __forceinline__ bf16x8 as_bf(us8 v) {
    return __builtin_bit_cast(bf16x8, v);
}
__device__ __forceinline__ f32x4 bf4f(ushort4 v) {
    f32x4 r;
    r[0] = bf2f(v.x); r[1] = bf2f(v.y); r[2] = bf2f(v.z); r[3] = bf2f(v.w);
    return r;
}

// ---------------- fused setup: weight swizzle + histogram -------------------
// Generalized fragment swizzler: logical k -> source row = k + (k>=split ?
// jump : 0); valid iff row < Kdata. Layer stride Kstride rows.
__device__ __forceinline__ void wfrag_gen(const float* __restrict__ w,
        u16* __restrict__ out, int KT, int Kdata, int Kstride,
        int split, int jump, int idx) {
    int lane = idx & 63;
    int f    = (idx >> 6) % (KT * 8);
    int l    = idx / (64 * KT * 8);
    int kt = f >> 3, nt = f & 7;
    int n  = nt * 16 + (lane & 15);
    int k0 = kt * 32 + ((lane >> 4) * 8);
    us8 v;
    #pragma unroll
    for (int j = 0; j < 8; ++j) {
        int k = k0 + j;
        int row = k + (k >= split ? jump : 0);
        v[j] = (row < Kdata) ? f2bf(w[((size_t)l * Kstride + row) * HID + n]) : (u16)0;
    }
    *(us8*)&out[((size_t)(l * KT * 8 + f) * 64 + lane) * 8] = v;
}

// R22 split of W1 [260x128]: w1s (src rows 0..127, KT=4), w1b (dst rows
// 128..255, KT=4), w1t (attr rows 256..259 zero-padded to K=32, KT=1).
#define T1S (4 * 4 * 8 * 64)
#define T1T (4 * 1 * 8 * 64)
#define T1B (4 * 4 * 8 * 64)
#define T2  (4 * 4 * 8 * 64)
#define T3  (4 * 8 * 8 * 64)

// R31: cnt/cursor/sums/cnts_g zeroed by hipMemsetAsync before this dispatch
// -> the hist pass (needs cnt==0) merges in as trailing blocks.
__global__ __launch_bounds__(256) void setup_kernel(
        const float* __restrict__ ew1, const float* __restrict__ ew2,
        const float* __restrict__ nw,
        u16* __restrict__ w1sf, u16* __restrict__ w1tf,
        u16* __restrict__ w1bf,
        u16* __restrict__ w2f, u16* __restrict__ nwf,
        const int* __restrict__ dstI, int* __restrict__ cnt, int E) {
    const int BIG = 1 << 30;
    int idx = blockIdx.x * 256 + threadIdx.x;
    if (idx < T1S) { wfrag_gen(ew1, w1sf, 4, 128, 260, BIG, 0, idx); return; }
    idx -= T1S;
    if (idx < T1T) { wfrag_gen(ew1, w1tf, 1, 260, 260, 0, 256, idx); return; }
    idx -= T1T;
    if (idx < T1B) { wfrag_gen(ew1, w1bf, 4, 260, 260, 0, 128, idx); return; }
    idx -= T1B;
    if (idx < T2) { wfrag_gen(ew2, w2f, 4, 128, 128, BIG, 0, idx); return; }
    idx -= T2;
    if (idx < T3) { wfrag_gen(nw, nwf, 8, 256, 256, BIG, 0, idx); return; }
    idx -= T3;
    if (idx < E) atomicAdd(&cnt[dstI[idx]], 1);
}

// ---------------- CSR scan ---------------------------------------------------
__global__ __launch_bounds__(1024) void scan_kernel(const int* __restrict__ cnt,
        int* __restrict__ rowptr, int n) {
    __shared__ int s[1024];
    const int t = threadIdx.x;
    const int chunk = (n + 1023) >> 10;
    int lo = t * chunk, hi = lo + chunk;
    if (lo > n) lo = n;
    if (hi > n) hi = n;
    int sum = 0;
    for (int i = lo; i < hi; ++i) sum += cnt[i];
    s[t] = sum;
    __syncthreads();
    for (int off = 1; off < 1024; off <<= 1) {
        int v = (t >= off) ? s[t - off] : 0;
        __syncthreads();
        s[t] += v;
        __syncthreads();
    }
    int run = s[t] - sum;
    for (int i = lo; i < hi; ++i) { rowptr[i] = run; run += cnt[i]; }
    if (t == 1023) rowptr[n] = run;
}

// ---------------- shared dual-projection tail -------------------------------
// Ys = x@W1s, Y = b1 + x@W1b from the block's own 32 xb rows; OUTPUT bf16
// (halves edge gather traffic; b1 folded -> edge acc-init is cvt+cvt+add).
// Caller must __syncthreads() after writing those xb rows. 256-thread
// geometry (t in [0,256)).
__device__ __forceinline__ void dual_proj(
        const u16* __restrict__ xb,
        const u16* __restrict__ w1sf, const u16* __restrict__ w1bf,
        const float* __restrict__ b1n,
        u16* __restrict__ Ys, u16* __restrict__ Y,
        int i0, int n, int t) {
    const int wv   = t >> 6, lane = t & 63;
    const int lrow = lane & 15;
    const int kq   = lane >> 4;
    const int kq8  = kq * 8;

    int iN[2];
    #pragma unroll
    for (int mt = 0; mt < 2; ++mt) {
        int i = i0 + mt * 16 + lrow; if (i >= n) i = n - 1;
        iN[mt] = i;
    }
    f32x4 aS[2][2], aB[2][2];
    #pragma unroll
    for (int mt = 0; mt < 2; ++mt)
        #pragma unroll
        for (int nt = 0; nt < 2; ++nt) {
            aS[mt][nt] = (f32x4){0.f, 0.f, 0.f, 0.f};
            aB[mt][nt] = *(const f32x4*)&b1n[(wv * 2 + nt) * 16 + kq * 4];
        }

    #pragma unroll
    for (int kt = 0; kt < 4; ++kt) {
        bf16x8 ws0 = *(const bf16x8*)&w1sf[((size_t)(kt * 8 + wv * 2 + 0) * 64 + lane) * 8];
        bf16x8 ws1 = *(const bf16x8*)&w1sf[((size_t)(kt * 8 + wv * 2 + 1) * 64 + lane) * 8];
        bf16x8 wb0 = *(const bf16x8*)&w1bf[((size_t)(kt * 8 + wv * 2 + 0) * 64 + lane) * 8];
        bf16x8 wb1 = *(const bf16x8*)&w1bf[((size_t)(kt * 8 + wv * 2 + 1) * 64 + lane) * 8];
        #pragma unroll
        for (int mt = 0; mt < 2; ++mt) {
            bf16x8 a = as_bf(*(const us8*)&xb[(size_t)iN[mt] * HID + kt * 32 + kq8]);
            aS[mt][0] = __builtin_amdgcn_mfma_f32_16x16x32_bf16(ws0, a, aS[mt][0], 0, 0, 0);
            aS[mt][1] = __builtin_amdgcn_mfma_f32_16x16x32_bf16(ws1, a, aS[mt][1], 0, 0, 0);
            aB[mt][0] = __builtin_amdgcn_mfma_f32_16x16x32_bf16(wb0, a, aB[mt][0], 0, 0, 0);
            aB[mt][1] = __builtin_amdgcn_mfma_f32_16x16x32_bf16(wb1, a, aB[mt][1], 0, 0, 0);
        }
    }
    #pragma unroll
    for (int mt = 0; mt < 2; ++mt) {
        int node = i0 + mt * 16 + lrow;
        if (node < n) {
            #pragma unroll
            for (int nt = 0; nt < 2; ++nt) {
                uint2 sv, bv;
                sv.x = pack_bf2(aS[mt][nt][0], aS[mt][nt][1]);
                sv.y = pack_bf2(aS[mt][nt][2], aS[mt][nt][3]);
                bv.x = pack_bf2(aB[mt][nt][0], aB[mt][nt][1]);
                bv.y = pack_bf2(aB[mt][nt][2], aB[mt][nt][3]);
                *(uint2*)&Ys[(size_t)node * HID + (wv * 2 + nt) * 16 + kq * 4] = sv;
                *(uint2*)&Y [(size_t)node * HID + (wv * 2 + nt) * 16 + kq * 4] = bv;
            }
        }
    }
}

// ---------------- merged scatter + embed + layer-0 projections ---------------
// R28 merge + R29 AoS + R30 bf16 agg + R32 (this round): scatter half is
// 4x thread-coarsened — each thread owns 4 edges (block covers 1024; loads
// stay coalesced per unrolled step) -> 4 independent atomic+store latency
// chains per thread (half was a single serial chain: 34% occupancy, <4%
// pipe busy).
__global__ __launch_bounds__(256) void scatter_embed_kernel(
        const int* __restrict__ src, const int* __restrict__ dst,
        const float* __restrict__ ea, const int* __restrict__ rowptr,
        int* __restrict__ cursor, int4* __restrict__ es,
        const int* __restrict__ z, const float* __restrict__ emb,
        u16* __restrict__ xb, u16* __restrict__ agg,
        const int* __restrict__ batch, float* __restrict__ counts,
        const u16* __restrict__ w1sf, const u16* __restrict__ w1bf,
        const float* __restrict__ b1n,
        u16* __restrict__ Ys, u16* __restrict__ Y,
        int E, int n, int SB) {
    const int t = threadIdx.x;
    if ((int)blockIdx.x < SB) {
        // -------- scatter half (blocks [0, SB)), 4 edges/thread --------
        const int e0 = blockIdx.x * 1024 + t;
        #pragma unroll
        for (int j = 0; j < 4; ++j) {
            int e = e0 + j * 256;
            if (e < E) {
                int d = dst[e];
                int p = rowptr[d] + atomicAdd(&cursor[d], 1);
                const float* q = &ea[(size_t)e * EDIM];
                int4 rec;
                rec.x = src[e];
                rec.y = d;
                rec.z = (int)((unsigned)f2bf(q[0]) | ((unsigned)f2bf(q[1]) << 16));
                rec.w = (int)((unsigned)f2bf(q[2]) | ((unsigned)f2bf(q[3]) << 16));
                es[p] = rec;
            }
        }
    } else {
        // -------- embed half (blocks [SB, SB+EB)) --------
        const int i0 = (blockIdx.x - SB) * 32;
        #pragma unroll
        for (int j = 0; j < 16; ++j) {
            int idx = j * 256 + t;             // 4096 slots = 32 nodes x 128
            int node = i0 + (idx >> 7), col = idx & 127;
            if (node < n) {
                xb[(size_t)node * HID + col] = f2bf(emb[(size_t)z[node] * HID + col]);
                agg[(size_t)node * HID + col] = 0;     // bf16 zero
            }
        }
        if (t < 32 && i0 + t < n)
            unsafeAtomicAdd(&counts[batch[i0 + t]], 1.0f);
        __syncthreads();   // xb stores drained -> visible block-wide
        dual_proj(xb, w1sf, w1bf, b1n, Ys, Y, i0, n, t);
    }
}

// ---------------- edge MLP: 64 dst-sorted edges/block, 8 waves --------------
// R12 core + R15 wave-local scan + R16 (8 waves, swapped MFMA operands) +
// R17 (dst-dedup) + R22 (src-hoist: GEMM1 attr-only K=32) + R26 (bf16 Ys/Y,
// b1 folded into Y) + R29 (AoS es) + R30 (bf16 agg, pk atomics) + R31
// (acc-init gathers hoisted before the staging barrier via direct es loads).
// FAILED variants (do not reintroduce): R9 XOR-swizzle, R13 2x2 wave tiling,
// R16 occupancy 2x, R18 VGPR-persistent weights (spill), R19 node-centric
// fusion (L2 thrash), R5 LDS-transpose node tail, R6 H-split, R9 cooperative
// launch (dropped under graph capture), R10 persistent manual-barrier kernel
// (fence invalidate storm), R12 dataflow-fused edge+node (uncached agg
// coherence reads; 1135 us).
__global__ __launch_bounds__(512, 8) void edge_mfma(
        const int4* __restrict__ es,
        const u16* __restrict__ w1tf,
        const u16* __restrict__ w2f, const float* __restrict__ b2,
        const u16* __restrict__ Ys, const u16* __restrict__ Y,
        u16* __restrict__ agg, int nE) {
    // A: u16 [64][40] = 5120 B (attr only; dead after GEMM1)
    // H: u16 [64][136] = 17408 B (aliases A; dead after GEMM2)
    // M: f32 [64][132] = 33792 B (aliases A/H; sized to M)
    __shared__ __align__(16) char smem[64 * 132 * 4];
    __shared__ __align__(16) int dsh[64];
    u16*   A = (u16*)smem;
    u16*   H = (u16*)smem;
    float* M = (float*)smem;

    const int t    = threadIdx.x;
    const int e0   = blockIdx.x * 64;
    const int wv   = t >> 6, lane = t & 63;
    const int lrow = lane & 15;
    const int kq   = lane >> 4;
    const int kq8  = kq * 8;
    const int rq   = kq * 4;
    const int h    = wv >> 2;     // edge-half this wave owns (0/1)
    const int p    = wv & 3;      // col-pair this wave owns (0..3)

    // ---- stage: dsh + attr rows from ONE int4/edge (rows padded to 40) ----
    if (t < 64) {
        int e = e0 + t;
        bool valid = e < nE; if (!valid) e = nE - 1;
        int4 rec = es[e];
        dsh[t] = valid ? rec.y : -1;
        int base = t * 40;
        us8 z8 = (us8){0, 0, 0, 0, 0, 0, 0, 0};
        *(us8*)&A[base + 8]  = z8;         // K-pad cols 8..31 zero
        *(us8*)&A[base + 16] = z8;
        *(us8*)&A[base + 24] = z8;
        A[base + 0] = (u16)((unsigned)rec.z & 0xffffu);
        A[base + 1] = (u16)((unsigned)rec.z >> 16);
        A[base + 2] = (u16)((unsigned)rec.w & 0xffffu);
        A[base + 3] = (u16)((unsigned)rec.w >> 16);
        A[base + 4] = 0;   A[base + 5] = 0;   A[base + 6] = 0;   A[base + 7] = 0;
    }

    // ---- acc-init gathers issued BEFORE the barrier (direct es reads;
    //      no LDS dependency). Values identical: invalid rows clamp to
    //      edge nE-1 -> unused garbage, scan skips them via dsh==-1.
    f32x4 acc[2][2];
    {
        int eA = e0 + (h * 2 + 0) * 16 + lrow; if (eA >= nE) eA = nE - 1;
        int eB = e0 + (h * 2 + 1) * 16 + lrow; if (eB >= nE) eB = nE - 1;
        int4 recA = es[eA];
        int4 recB = es[eB];
        int dA = recA.y, sA = recA.x;
        int dB = recB.y, sB = recB.x;
        #pragma unroll
        for (int nt = 0; nt < 2; ++nt) {
            int c = (p * 2 + nt) * 16 + rq;
            ushort4 yA = *(const ushort4*)&Y [(size_t)dA * HID + c];
            ushort4 sA4 = *(const ushort4*)&Ys[(size_t)sA * HID + c];
            ushort4 yB = *(const ushort4*)&Y [(size_t)dB * HID + c];
            ushort4 sB4 = *(const ushort4*)&Ys[(size_t)sB * HID + c];
            acc[0][nt] = bf4f(yA) + bf4f(sA4);
            acc[1][nt] = bf4f(yB) + bf4f(sB4);
        }
    }
    __syncthreads();

    // ---- GEMM1: attr-only K=32 on top of the pre-gathered acc ----
    {
        bf16x8 w0 = *(const bf16x8*)&w1tf[((size_t)(p * 2 + 0) * 64 + lane) * 8];
        bf16x8 w1 = *(const bf16x8*)&w1tf[((size_t)(p * 2 + 1) * 64 + lane) * 8];
        #pragma unroll
        for (int mt = 0; mt < 2; ++mt) {
            bf16x8 a = *(const bf16x8*)&A[((h * 2 + mt) * 16 + lrow) * 40 + kq8];
            acc[mt][0] = __builtin_amdgcn_mfma_f32_16x16x32_bf16(w0, a, acc[mt][0], 0, 0, 0);
            acc[mt][1] = __builtin_amdgcn_mfma_f32_16x16x32_bf16(w1, a, acc[mt][1], 0, 0, 0);
        }
    }
    __syncthreads();   // all A reads done; region reused as H

    // silu -> H: 4 consecutive n per lane -> one packed b64 per (mt,nt)
    #pragma unroll
    for (int mt = 0; mt < 2; ++mt)
        #pragma unroll
        for (int nt = 0; nt < 2; ++nt) {
            uint2 hv;
            hv.x = pack_bf2(silu_f(acc[mt][nt][0]), silu_f(acc[mt][nt][1]));
            hv.y = pack_bf2(silu_f(acc[mt][nt][2]), silu_f(acc[mt][nt][3]));
            int edge = (h * 2 + mt) * 16 + lrow;
            *(uint2*)&H[edge * 136 + (p * 2 + nt) * 16 + rq] = hv;
        }
    __syncthreads();

    // ---- GEMM2: [64 x 128] @ [128 x 128], swapped operands ----
    f32x4 acc2[2][2];
    #pragma unroll
    for (int nt = 0; nt < 2; ++nt) {
        f32x4 bv = *(const f32x4*)&b2[(p * 2 + nt) * 16 + rq];
        acc2[0][nt] = bv; acc2[1][nt] = bv;
    }
    #pragma unroll
    for (int kt = 0; kt < 4; ++kt) {
        bf16x8 w0 = *(const bf16x8*)&w2f[((size_t)(kt * 8 + p * 2 + 0) * 64 + lane) * 8];
        bf16x8 w1 = *(const bf16x8*)&w2f[((size_t)(kt * 8 + p * 2 + 1) * 64 + lane) * 8];
        #pragma unroll
        for (int mt = 0; mt < 2; ++mt) {
            bf16x8 a = *(const bf16x8*)&H[((h * 2 + mt) * 16 + lrow) * 136 + kt * 32 + kq8];
            acc2[mt][0] = __builtin_amdgcn_mfma_f32_16x16x32_bf16(w0, a, acc2[mt][0], 0, 0, 0);
            acc2[mt][1] = __builtin_amdgcn_mfma_f32_16x16x32_bf16(w1, a, acc2[mt][1], 0, 0, 0);
        }
    }
    __syncthreads();   // all H reads complete before M overwrites (aliased WAR)

    // silu -> M: fp32 messages, one float4 store per (mt,nt)
    #pragma unroll
    for (int mt = 0; mt < 2; ++mt)
        #pragma unroll
        for (int nt = 0; nt < 2; ++nt) {
            f32x4 mv;
            #pragma unroll
            for (int r = 0; r < 4; ++r) mv[r] = silu_f(acc2[mt][nt][r]);
            int edge = (h * 2 + mt) * 16 + lrow;
            *(f32x4*)&M[edge * 132 + (p * 2 + nt) * 16 + rq] = mv;
        }

    // ---- wave-local segmented reduction -> packed-bf16 atomics.
    // Wave (h,p) scans exactly the 32x32 M region it wrote (no barrier;
    // intra-wave DS program order). Run flushes are uniform within each
    // 32-lane half (row-based boundaries): even lane takes its odd
    // neighbor's run via shfl_xor and issues ONE pk_add_bf16 per col pair.
    {
        int col = p * 32 + (lane & 31);
        int r0  = h * 32 + (lane >> 5) * 16;   // rows r0..r0+15
        int4 da = *(const int4*)&dsh[r0];
        int4 db = *(const int4*)&dsh[r0 + 4];
        int4 dc = *(const int4*)&dsh[r0 + 8];
        int4 dd = *(const int4*)&dsh[r0 + 12];
        int ds_[16] = {da.x, da.y, da.z, da.w, db.x, db.y, db.z, db.w,
                       dc.x, dc.y, dc.z, dc.w, dd.x, dd.y, dd.z, dd.w};
        float run = 0.f;
        int   cur = ds_[0];
        #pragma unroll
        for (int i = 0; i < 16; ++i) {
            run += M[(r0 + i) * 132 + col];
            int nxt = (i == 15) ? -2 : ds_[i + 1];
            if (cur != nxt) {             // uniform within 32-lane half
                float nbr = __shfl_xor(run, 1);
                if (cur >= 0 && !(col & 1)) {
                    __hip_bfloat162 v;
                    v.x = __float2bfloat16(run);
                    v.y = __float2bfloat16(nbr);
                    unsafeAtomicAdd(
                        (__hip_bfloat162*)&agg[(size_t)cur * HID + col], v);
                }
                run = 0.f; cur = nxt;
            }
        }
    }
}

// ---------------- node MLP: 32 nodes/block + fused next-layer projections ---
// R2-exact core; R30: bf16 agg -> one us8 load feeds MFMA directly.
__global__ __launch_bounds__(256) void node_mfma(
        u16* __restrict__ xb, u16* __restrict__ agg,
        const u16* __restrict__ nwf, const float* __restrict__ nb,
        const int* __restrict__ batch, float* __restrict__ sums,
        const u16* __restrict__ w1sf_nxt, const u16* __restrict__ w1bf_nxt,
        const float* __restrict__ b1_nxt,
        u16* __restrict__ Ys, u16* __restrict__ Y,
        int last, int n) {
    const int t    = threadIdx.x;
    const int i0   = blockIdx.x * 32;
    const int wv   = t >> 6, lane = t & 63;
    const int lrow = lane & 15;
    const int kq   = lane >> 4;
    const int kq8  = kq * 8;
    const int rq   = kq * 4;

    int iN[2];
    #pragma unroll
    for (int mt = 0; mt < 2; ++mt) {
        int i = i0 + mt * 16 + lrow; if (i >= n) i = n - 1;
        iN[mt] = i;
    }

    f32x4 acc[2][2];
    {
        float bias0 = nb[wv * 32 + lrow], bias1 = nb[wv * 32 + 16 + lrow];
        #pragma unroll
        for (int mt = 0; mt < 2; ++mt)
            #pragma unroll
            for (int r = 0; r < 4; ++r) {
                acc[mt][0][r] = bias0; acc[mt][1][r] = bias1;
            }
    }
    #pragma unroll
    for (int kt = 0; kt < 4; ++kt) {     // x part (k 0..127)
        bf16x8 w0 = *(const bf16x8*)&nwf[((size_t)(kt * 8 + wv * 2 + 0) * 64 + lane) * 8];
        bf16x8 w1 = *(const bf16x8*)&nwf[((size_t)(kt * 8 + wv * 2 + 1) * 64 + lane) * 8];
        #pragma unroll
        for (int mt = 0; mt < 2; ++mt) {
            bf16x8 a = as_bf(*(const us8*)&xb[(size_t)iN[mt] * HID + kt * 32 + kq8]);
            acc[mt][0] = __builtin_amdgcn_mfma_f32_16x16x32_bf16(a, w0, acc[mt][0], 0, 0, 0);
            acc[mt][1] = __builtin_amdgcn_mfma_f32_16x16x32_bf16(a, w1, acc[mt][1], 0, 0, 0);
        }
    }
    #pragma unroll
    for (int kt = 4; kt < 8; ++kt) {     // agg part (k 128..255), bf16 direct
        bf16x8 w0 = *(const bf16x8*)&nwf[((size_t)(kt * 8 + wv * 2 + 0) * 64 + lane) * 8];
        bf16x8 w1 = *(const bf16x8*)&nwf[((size_t)(kt * 8 + wv * 2 + 1) * 64 + lane) * 8];
        #pragma unroll
        for (int mt = 0; mt < 2; ++mt) {
            bf16x8 a = as_bf(*(const us8*)&agg[(size_t)iN[mt] * HID + (kt - 4) * 32 + kq8]);
            acc[mt][0] = __builtin_amdgcn_mfma_f32_16x16x32_bf16(a, w0, acc[mt][0], 0, 0, 0);
            acc[mt][1] = __builtin_amdgcn_mfma_f32_16x16x32_bf16(a, w1, acc[mt][1], 0, 0, 0);
        }
    }

    if (!last) {
        __syncthreads();   // all xb/agg reads in block complete before overwrite
        const us8 z8 = (us8){0, 0, 0, 0, 0, 0, 0, 0};
        #pragma unroll
        for (int kt = 0; kt < 4; ++kt)
            #pragma unroll
            for (int mt = 0; mt < 2; ++mt)
                *(us8*)&agg[(size_t)iN[mt] * HID + kt * 32 + kq8] = z8;
        #pragma unroll
        for (int mt = 0; mt < 2; ++mt)
            #pragma unroll
            for (int nt2 = 0; nt2 < 2; ++nt2)
                #pragma unroll
                for (int r = 0; r < 4; ++r) {
                    int i = i0 + mt * 16 + rq + r;
                    if (i < n)
                        xb[(size_t)i * HID + wv * 32 + nt2 * 16 + lrow] =
                            f2bf_fast(silu_f(acc[mt][nt2][r]));
                }
        __syncthreads();   // xb stores drained (vmcnt0 at barrier) -> visible
        dual_proj(xb, w1sf_nxt, w1bf_nxt, b1_nxt, Ys, Y, i0, n, t);
    } else {
        // final layer: scatter straight into per-graph sums
        #pragma unroll
        for (int mt = 0; mt < 2; ++mt)
            #pragma unroll
            for (int nt2 = 0; nt2 < 2; ++nt2)
                #pragma unroll
                for (int r = 0; r < 4; ++r) {
                    int i = i0 + mt * 16 + rq + r;
                    if (i < n) {
                        int b = batch[i];
                        unsafeAtomicAdd(&sums[(size_t)b * HID + wv * 32 + nt2 * 16 + lrow],
                                        silu_f(acc[mt][nt2][r]));
                    }
                }
    }
}

// ---------------- readout ---------------------------------------------------
__global__ __launch_bounds__(HID) void readout_kernel(
        const float* __restrict__ sums, const float* __restrict__ counts,
        const float* __restrict__ rw1, const float* __restrict__ rb1,
        const float* __restrict__ rw2, const float* __restrict__ rb2,
        float* __restrict__ pred) {
    __shared__ float gv[HID];
    __shared__ float hv[HID];
    const int g = blockIdx.x;
    const int t = threadIdx.x;
    float c = counts[g];
    if (c < 1.0f) c = 1.0f;
    gv[t] = sums[(size_t)g * HID + t] / c;   // cold path: keep exact division
    __syncthreads();
    float acc = rb1[t];
    for (int k4 = 0; k4 < 32; ++k4) {
        float4 mv = *(const float4*)&gv[k4 * 4];
        #pragma unroll
        for (int j = 0; j < 4; ++j)
            acc += ((const float*)&mv)[j] * rw1[(size_t)(k4 * 4 + j) * HID + t];
    }
    hv[t] = silu_f(acc) * rw2[t];
    __syncthreads();
    for (int s = HID / 2; s > 0; s >>= 1) {
        if (t < s) hv[t] += hv[t + s];
        __syncthreads();
    }
    if (t == 0) pred[g] = hv[0] + rb2[0];
}

extern "C" void kernel_launch(void* const* d_in, const int* in_sizes, int n_in,
                              void* d_out, int out_size, void* d_ws, size_t ws_size,
                              hipStream_t stream) {
    const int*   z          = (const int*)d_in[0];
    const int*   edge_index = (const int*)d_in[1];
    const float* edge_attr  = (const float*)d_in[2];
    const int*   batch      = (const int*)d_in[3];
    const float* emb        = (const float*)d_in[4];
    const float* ew1        = (const float*)d_in[5];
    const float* eb1        = (const float*)d_in[6];
    const float* ew2        = (const float*)d_in[7];
    const float* eb2        = (const float*)d_in[8];
    const float* nw         = (const float*)d_in[9];
    const float* nb         = (const float*)d_in[10];
    const float* rw1        = (const float*)d_in[11];
    const float* rb1        = (const float*)d_in[12];
    const float* rw2        = (const float*)d_in[13];
    const float* rb2        = (const float*)d_in[14];
    float* pred = (float*)d_out;

    const int N = in_sizes[0];
    const int E = in_sizes[1] / 2;
    const int G = out_size;
    const int* srcI = edge_index;
    const int* dstI = edge_index + E;

    char* base = (char*)d_ws;
    size_t off = 0;
    auto carve = [&](size_t bytes) -> char* {
        char* p = base + off;
        off = (off + bytes + 255) & ~(size_t)255;
        return p;
    };
    u16*   agg    = (u16*)carve((size_t)N * HID * sizeof(u16));   // bf16 agg
    float* sums   = (float*)carve((size_t)G * HID * sizeof(float));
    float* cnts_g = (float*)carve((size_t)G * sizeof(float));     // adjacent to sums
    u16*   xb     = (u16*)carve((size_t)N * HID * sizeof(u16));
    u16*   Y      = (u16*)carve((size_t)N * HID * sizeof(u16));   // dst-proj (bf16, b1 folded)
    u16*   Ys     = (u16*)carve((size_t)N * HID * sizeof(u16));   // src-proj (bf16)
    int4*  es     = (int4*)carve((size_t)(E + 64) * sizeof(int4)); // AoS edge recs
    int*   rowptr = (int*)carve((size_t)(N + 1) * sizeof(int));
    int*   cursor = (int*)carve((size_t)N * sizeof(int));
    int*   cnt    = (int*)carve((size_t)N * sizeof(int));          // adjacent to cursor
    u16*   w1sf   = (u16*)carve((size_t)4 * 32 * 512 * sizeof(u16)); // KT=4 src
    u16*   w1tf   = (u16*)carve((size_t)4 * 8 * 512 * sizeof(u16));  // KT=1 attr
    u16*   w1bf   = (u16*)carve((size_t)4 * 32 * 512 * sizeof(u16)); // KT=4 dst
    u16*   w2f    = (u16*)carve((size_t)4 * 32 * 512 * sizeof(u16)); // KT=4
    u16*   nwf    = (u16*)carve((size_t)4 * 64 * 512 * sizeof(u16)); // KT=8

    // ---- R31: async pre-zeroing (stream-ordered, graph-capture-safe) ----
    // cursor..cnt span and sums..cnts_g span are contiguous carves.
    hipMemsetAsync(cursor, 0, (size_t)((char*)(cnt + N) - (char*)cursor), stream);
    hipMemsetAsync(sums, 0, (size_t)((char*)(cnts_g + G) - (char*)sums), stream);

    // ---- fused setup: weight swizzle + histogram (cnt pre-zeroed) ----
    {
        long long total = (long long)T1S + T1T + T1B + T2 + T3 + E;
        int blocks = (int)((total + 255) / 256);
        setup_kernel<<<blocks, 256, 0, stream>>>(ew1, ew2, nw, w1sf, w1tf, w1bf,
                                                 w2f, nwf, dstI, cnt, E);
    }

    // ---- CSR scan ----
    scan_kernel<<<1, 1024, 0, stream>>>(cnt, rowptr, N);

    // ---- merged scatter + embed + layer-0 projections (independent halves) ----
    {
        const int SB = (E + 1023) / 1024;   // 4 edges/thread
        const int EB = (N + 31) / 32;
        scatter_embed_kernel<<<SB + EB, 256, 0, stream>>>(
            srcI, dstI, edge_attr, rowptr, cursor, es,
            z, emb, xb, agg, batch, cnts_g, w1sf, w1bf, eb1, Ys, Y, E, N, SB);
    }

    for (int l = 0; l < 4; ++l) {
        edge_mfma<<<(E + 63) / 64, 512, 0, stream>>>(
            es,
            w1tf + (size_t)l * 8 * 512,
            w2f + (size_t)l * 32 * 512, eb2 + (size_t)l * HID,
            Ys, Y, agg, E);
        int lnxt = (l + 1) & 3;   // l==3: tail skipped (last=1), args unused
        node_mfma<<<(N + 31) / 32, 256, 0, stream>>>(
            xb, agg, nwf + (size_t)l * 64 * 512, nb + (size_t)l * HID,
            batch, sums,
            w1sf + (size_t)lnxt * 32 * 512, w1bf + (size_t)lnxt * 32 * 512,
            eb1 + (size_t)lnxt * HID,
            Ys, Y, (l == 3) ? 1 : 0, N);
    }

    readout_kernel<<<G, HID, 0, stream>>>(sums, cnts_g, rw1, rb1, rw2, rb2, pred);
}